// Round 3
// baseline (669.977 us; speedup 1.0000x reference)
//
#include <hip/hip_runtime.h>
#include <cstdint>
#include <cstddef>

// DinoDecoderBlock on MI355X (gfx950).
// B=4 NQ=NK=1024 C=768 H=12 DH=64, scale=1/8, eps=1e-5.
// bf16 MFMA GEMMs + two-pass in-LDS attention. fp32 residual stream.
// R3: sim/smean/mask path replaced by fused bf16 bias precompute (per-batch loop)
//     + coalesced LDS staging in cross-attn. simmean_k removed.

typedef __bf16 bf16;
typedef __attribute__((ext_vector_type(8))) __bf16 bf16x8;
typedef __attribute__((ext_vector_type(4))) __bf16 bf16x4;
typedef __attribute__((ext_vector_type(4))) float f32x4;

typedef __attribute__((address_space(1))) void gvoid;
typedef __attribute__((address_space(3))) void lvoid;

#define DEVI static __device__ __forceinline__

DEVI void gload16(const void* g, void* l) {
  __builtin_amdgcn_global_load_lds((gvoid*)(uintptr_t)g, (lvoid*)(uintptr_t)l, 16, 0, 0);
}

DEVI f32x4 mfma_bf16(bf16x8 a, bf16x8 b, f32x4 c) {
  return __builtin_amdgcn_mfma_f32_16x16x32_bf16(a, b, c, 0, 0, 0);
}

// ---------------- mask dtype detection ----------------
// jax bool mask may arrive as 1-byte bools (shift=0) or int32 0/1 words (shift=2).
__global__ __launch_bounds__(256)
void detect_mask_k(const unsigned char* __restrict__ mask, int* __restrict__ shift)
{
  __shared__ int acc[256];
  const int t = threadIdx.x;
  int s = 0;
  for (int i = t; i < 16384; i += 256) {
    const int base = i * 4;
    s += mask[base + 1] + mask[base + 2] + mask[base + 3];
  }
  acc[t] = s;
  __syncthreads();
  #pragma unroll
  for (int o = 128; o; o >>= 1) {
    if (t < o) acc[t] += acc[t + o];
    __syncthreads();
  }
  if (t == 0) *shift = (acc[0] == 0) ? 2 : 0;
}

// ---------------- fused bias precompute (one batch b) ----------------
// biasOut[h][q][k] = sim[b,h,q,k] - mean_h(sim[b,:,q,k]) + (mask[q,k] ? 0 : -1e30)
// block = q row (1024 blocks), 256 threads x f32x4 over k.
__global__ __launch_bounds__(256)
void bias_k(const float* __restrict__ sim,          // sim + b*12*2^20
            const unsigned char* __restrict__ mask,
            const int* __restrict__ mshift,
            bf16* __restrict__ biasOut)             // [12][1024][1024]
{
  const int q = blockIdx.x, t = threadIdx.x;
  const int k4 = t * 4;
  const int msh = *mshift;

  f32x4 sv[12];
  f32x4 acc = {0.f, 0.f, 0.f, 0.f};
  #pragma unroll
  for (int h = 0; h < 12; ++h) {
    sv[h] = *(const f32x4*)(sim + ((size_t)h * 1024 + q) * 1024 + k4);
    acc += sv[h];
  }
  const f32x4 mean = acc * (1.0f / 12.0f);

  float mb[4];
  if (msh == 0) {
    const uchar4 mv = *(const uchar4*)(mask + (size_t)q * 1024 + k4);
    mb[0] = mv.x ? 0.f : -1e30f;
    mb[1] = mv.y ? 0.f : -1e30f;
    mb[2] = mv.z ? 0.f : -1e30f;
    mb[3] = mv.w ? 0.f : -1e30f;
  } else {
    const int4 mv = *(const int4*)((const int*)mask + (size_t)q * 1024 + k4);
    mb[0] = mv.x ? 0.f : -1e30f;
    mb[1] = mv.y ? 0.f : -1e30f;
    mb[2] = mv.z ? 0.f : -1e30f;
    mb[3] = mv.w ? 0.f : -1e30f;
  }

  #pragma unroll
  for (int h = 0; h < 12; ++h) {
    bf16x4 o;
    #pragma unroll
    for (int j = 0; j < 4; ++j)
      o[j] = (bf16)(sv[h][j] - mean[j] + mb[j]);
    *(bf16x4*)(biasOut + ((size_t)h * 1024 + q) * 1024 + k4) = o;
  }
}

// ---------------- fp32 -> bf16 convert ----------------
__global__ __launch_bounds__(256)
void cvt_k(const float* __restrict__ s, bf16* __restrict__ d, int n4)
{
  const int i = blockIdx.x * 256 + threadIdx.x;
  if (i >= n4) return;
  const f32x4 v = *((const f32x4*)s + i);
  bf16* o = d + (size_t)i * 4;
  o[0] = (bf16)v[0]; o[1] = (bf16)v[1]; o[2] = (bf16)v[2]; o[3] = (bf16)v[3];
}

// ---------------- float4 copy ----------------
__global__ __launch_bounds__(256)
void copy4_k(const float* __restrict__ s, float* __restrict__ d, int n4)
{
  const int i = blockIdx.x * 256 + threadIdx.x;
  if (i < n4) ((f32x4*)d)[i] = ((const f32x4*)s)[i];
}

// ---------------- LayerNorm over 768, fp32 in -> bf16 out ----------------
__global__ __launch_bounds__(256)
void ln_k(const float* __restrict__ xin, const float* __restrict__ g,
          const float* __restrict__ be, bf16* __restrict__ out)
{
  const int row = blockIdx.x, tid = threadIdx.x;
  const int lane = tid & 63, w = tid >> 6;
  const float* xr = xin + (size_t)row * 768;
  const float v0 = xr[tid], v1 = xr[tid + 256], v2 = xr[tid + 512];
  float s = v0 + v1 + v2;
  #pragma unroll
  for (int o = 32; o; o >>= 1) s += __shfl_xor(s, o);
  __shared__ float r1[4], r2[4];
  if (lane == 0) r1[w] = s;
  __syncthreads();
  const float mean = (r1[0] + r1[1] + r1[2] + r1[3]) * (1.0f / 768.0f);
  const float d0 = v0 - mean, d1 = v1 - mean, d2 = v2 - mean;
  float q = d0 * d0 + d1 * d1 + d2 * d2;
  #pragma unroll
  for (int o = 32; o; o >>= 1) q += __shfl_xor(q, o);
  if (lane == 0) r2[w] = q;
  __syncthreads();
  const float inv = rsqrtf((r2[0] + r2[1] + r2[2] + r2[3]) * (1.0f / 768.0f) + 1e-5f);
  bf16* orow = out + (size_t)row * 768;
  orow[tid]       = (bf16)(d0 * inv * g[tid]       + be[tid]);
  orow[tid + 256] = (bf16)(d1 * inv * g[tid + 256] + be[tid + 256]);
  orow[tid + 512] = (bf16)(d2 * inv * g[tid + 512] + be[tid + 512]);
}

// ---------------- V transpose: src[(b*1024+n)*ld + h*64 + d] -> vt[(bh*64+d)*1024 + n] ----------------
__global__ __launch_bounds__(256)
void build_vt(const bf16* __restrict__ src, int ld, bf16* __restrict__ vt)
{
  __shared__ unsigned short t[64][72];
  const int bh = blockIdx.x, nt = blockIdx.y;
  const int b = bh / 12, hh = bh % 12;
  const int tid = threadIdx.x;
  {
    const int nl = tid >> 2, d0 = (tid & 3) * 16;
    const unsigned short* srow = (const unsigned short*)src
        + (size_t)(b * 1024 + nt * 64 + nl) * ld + hh * 64 + d0;
    #pragma unroll
    for (int j = 0; j < 4; ++j)
      *(ushort4*)(&t[nl][d0 + j * 4]) = *(const ushort4*)(srow + j * 4);
  }
  __syncthreads();
  {
    const int dl = tid >> 2, n0 = (tid & 3) * 16;
    unsigned short* drow = (unsigned short*)vt + ((size_t)bh * 64 + dl) * 1024 + nt * 64 + n0;
    #pragma unroll
    for (int j = 0; j < 4; ++j) {
      ushort4 o;
      o.x = t[n0 + j * 4 + 0][dl];
      o.y = t[n0 + j * 4 + 1][dl];
      o.z = t[n0 + j * 4 + 2][dl];
      o.w = t[n0 + j * 4 + 3][dl];
      *(ushort4*)(drow + j * 4) = o;
    }
  }
}

// ---------------- GEMM: C[M,N] = A[M,K] * Bt[N,K]^T  (bf16 in, fp32 acc) ----------------
template<bool BIAS, bool GELU, bool RES, bool OBF>
__global__ __launch_bounds__(256)
void gemm_bt(const bf16* __restrict__ A, const bf16* __restrict__ Bt,
             const float* __restrict__ bias, const float* __restrict__ res,
             bf16* __restrict__ Cb, float* __restrict__ Cf,
             int M, int N, int K)
{
  __shared__ bf16 As[128 * 64];
  __shared__ bf16 Bs[128 * 64];
  const int tid = threadIdx.x;
  const int lane = tid & 63;
  const int wv = tid >> 6;
  const int wr = wv >> 1, wc = wv & 1;
  const int l15 = lane & 15, lg = lane >> 4;
  const int bm = blockIdx.y * 128, bn = blockIdx.x * 128;
  (void)M;

  f32x4 acc[4][4];
  const f32x4 z = {0.f, 0.f, 0.f, 0.f};
  #pragma unroll
  for (int i = 0; i < 4; ++i)
    #pragma unroll
    for (int j = 0; j < 4; ++j) acc[i][j] = z;

  for (int k0 = 0; k0 < K; k0 += 64) {
    __syncthreads();
    #pragma unroll
    for (int i = 0; i < 4; ++i) {
      const int c = wv * 256 + i * 64 + lane;
      const int row = c >> 3;
      const int colb = (c & 7) << 4;
      gload16((const char*)A  + ((size_t)(bm + row) * K + k0) * 2 + colb,
              (char*)As + (size_t)c * 16);
      gload16((const char*)Bt + ((size_t)(bn + row) * K + k0) * 2 + colb,
              (char*)Bs + (size_t)c * 16);
    }
    __syncthreads();
    #pragma unroll
    for (int kk = 0; kk < 64; kk += 32) {
      bf16x8 af[4], bfr[4];
      #pragma unroll
      for (int mi = 0; mi < 4; ++mi)
        af[mi] = *(const bf16x8*)(As + (size_t)(wr * 64 + mi * 16 + l15) * 64 + kk + lg * 8);
      #pragma unroll
      for (int ni = 0; ni < 4; ++ni)
        bfr[ni] = *(const bf16x8*)(Bs + (size_t)(wc * 64 + ni * 16 + l15) * 64 + kk + lg * 8);
      #pragma unroll
      for (int mi = 0; mi < 4; ++mi)
        #pragma unroll
        for (int ni = 0; ni < 4; ++ni)
          acc[mi][ni] = mfma_bf16(af[mi], bfr[ni], acc[mi][ni]);
    }
  }

  #pragma unroll
  for (int mi = 0; mi < 4; ++mi) {
    const int row0 = bm + wr * 64 + mi * 16 + lg * 4;
    #pragma unroll
    for (int ni = 0; ni < 4; ++ni) {
      const int col = bn + wc * 64 + ni * 16 + l15;
      #pragma unroll
      for (int r = 0; r < 4; ++r) {
        float v = acc[mi][ni][r];
        if constexpr (BIAS) v += bias[col];
        if constexpr (GELU) v = 0.5f * v * (1.0f + erff(v * 0.70710678118654752f));
        if constexpr (RES)  v += res[(size_t)(row0 + r) * N + col];
        if constexpr (OBF)  Cb[(size_t)(row0 + r) * N + col] = (bf16)v;
        else                Cf[(size_t)(row0 + r) * N + col] = v;
      }
    }
  }
}

// ---------------- attention: one (b, h, 32 q-rows) per block, 8 waves ----------------
// CROSS: bias tile (bf16, precomputed sim-mean+mask) staged coalesced into S first;
// phase1 S = QK^T/8 (+S), phase2 softmax (P bf16 in place), phase3 P·V via Vt.
template<int CROSS>
__global__ __launch_bounds__(512)
void attn_k(const bf16* __restrict__ Qp, int ldq,
            const bf16* __restrict__ Kp, int ldk,
            const bf16* __restrict__ Vt,
            const bf16* __restrict__ bias,   // per-batch [12][1024][1024], CROSS only
            int bsel,
            bf16* __restrict__ Out)
{
  __shared__ float S[32][1028];
  __shared__ bf16 Qs[32][72];
  const int hh = blockIdx.x, qt = blockIdx.y;
  const int b = CROSS ? bsel : blockIdx.z;
  const int tid = threadIdx.x, lane = tid & 63, w = tid >> 6;
  const int l15 = lane & 15, lg = lane >> 4;

  { // stage Q tile [32 x 64]
    const int r = tid >> 4, c4 = (tid & 15) << 2;
    const bf16* srcp = Qp + (size_t)(b * 1024 + qt * 32 + r) * ldq + hh * 64 + c4;
    *(ushort4*)(&Qs[r][c4]) = *(const ushort4*)srcp;
  }
  if constexpr (CROSS) { // stage bias tile into S (coalesced bf16x8 loads)
    const bf16* brow = bias + ((size_t)hh * 1024 + qt * 32) * 1024;
    #pragma unroll
    for (int j = 0; j < 8; ++j) {
      const int chunk = j * 512 + tid;      // 0..4095
      const int row = chunk >> 7;
      const int c8 = (chunk & 127) << 3;
      const bf16x8 v = *(const bf16x8*)(brow + (size_t)row * 1024 + c8);
      #pragma unroll
      for (int e = 0; e < 8; ++e) S[row][c8 + e] = (float)v[e];
    }
  }
  __syncthreads();

  { // phase 1: wave w owns cols [w*128, w*128+128)
    f32x4 sacc[2][8];
    const f32x4 z = {0.f, 0.f, 0.f, 0.f};
    #pragma unroll
    for (int i = 0; i < 2; ++i)
      #pragma unroll
      for (int j = 0; j < 8; ++j) sacc[i][j] = z;
    const bf16* Kb = Kp + (size_t)b * 1024 * ldk + hh * 64;
    #pragma unroll
    for (int kk = 0; kk < 64; kk += 32) {
      const bf16x8 aq0 = *(const bf16x8*)(&Qs[l15][kk + lg * 8]);
      const bf16x8 aq1 = *(const bf16x8*)(&Qs[16 + l15][kk + lg * 8]);
      #pragma unroll
      for (int ni = 0; ni < 8; ++ni) {
        const bf16x8 bk = *(const bf16x8*)(Kb + (size_t)(w * 128 + ni * 16 + l15) * ldk + kk + lg * 8);
        sacc[0][ni] = mfma_bf16(aq0, bk, sacc[0][ni]);
        sacc[1][ni] = mfma_bf16(aq1, bk, sacc[1][ni]);
      }
    }
    #pragma unroll
    for (int mi = 0; mi < 2; ++mi) {
      const int rq = mi * 16 + lg * 4;
      #pragma unroll
      for (int ni = 0; ni < 8; ++ni) {
        const int col = w * 128 + ni * 16 + l15;
        #pragma unroll
        for (int r = 0; r < 4; ++r) {
          float v = sacc[mi][ni][r] * 0.125f;
          if constexpr (CROSS) v += S[rq + r][col];
          S[rq + r][col] = v;
        }
      }
    }
  }
  __syncthreads();

  { // phase 2: softmax rows [w*4, w*4+4), column-strided (bank-conflict-free)
    #pragma unroll
    for (int rr = 0; rr < 4; ++rr) {
      const int row = w * 4 + rr;
      float vv[16];
      #pragma unroll
      for (int j = 0; j < 16; ++j) vv[j] = S[row][lane + 64 * j];
      float m = vv[0];
      #pragma unroll
      for (int j = 1; j < 16; ++j) m = fmaxf(m, vv[j]);
      #pragma unroll
      for (int o = 32; o; o >>= 1) m = fmaxf(m, __shfl_xor(m, o));
      float s = 0.f;
      #pragma unroll
      for (int j = 0; j < 16; ++j) { vv[j] = __expf(vv[j] - m); s += vv[j]; }
      #pragma unroll
      for (int o = 32; o; o >>= 1) s += __shfl_xor(s, o);
      const float inv = 1.0f / s;
      bf16* prow = (bf16*)(&S[row][0]);
      #pragma unroll
      for (int j = 0; j < 16; ++j) prow[lane + 64 * j] = (bf16)(vv[j] * inv);
    }
  }
  __syncthreads();

  { // phase 3: wave w -> q-half (w>>2), d-tile (w&3)
    const int q2 = (w >> 2) * 16, dt = (w & 3) * 16;
    f32x4 oacc = {0.f, 0.f, 0.f, 0.f};
    const bf16* vb = Vt + ((size_t)(b * 12 + hh) * 64 + dt + l15) * 1024 + lg * 8;
    const bf16* pr = (const bf16*)(&S[q2 + l15][0]) + lg * 8;
    #pragma unroll 4
    for (int k0 = 0; k0 < 1024; k0 += 32) {
      const bf16x8 ap = *(const bf16x8*)(pr + k0);
      const bf16x8 bv = *(const bf16x8*)(vb + k0);
      oacc = mfma_bf16(ap, bv, oacc);
    }
    const int dcol = dt + l15;
    const int rq = q2 + lg * 4;
    #pragma unroll
    for (int r = 0; r < 4; ++r)
      Out[((size_t)(b * 1024 + qt * 32 + rq + r)) * 768 + hh * 64 + dcol] = (bf16)oacc[r];
  }
}

// ---------------- launcher ----------------
extern "C" void kernel_launch(void* const* d_in, const int* in_sizes, int n_in,
                              void* d_out, int out_size, void* d_ws, size_t ws_size,
                              hipStream_t stream)
{
  (void)in_sizes; (void)n_in; (void)out_size; (void)ws_size;
  const float* x    = (const float*)d_in[0];
  const float* y    = (const float*)d_in[1];
  const unsigned char* mask = (const unsigned char*)d_in[4];
  const float* sim  = (const float*)d_in[5];
  const float* ln1g = (const float*)d_in[6];
  const float* ln1b = (const float*)d_in[7];
  const float* ln2g = (const float*)d_in[8];
  const float* ln2b = (const float*)d_in[9];
  const float* ln3g = (const float*)d_in[10];
  const float* ln3b = (const float*)d_in[11];
  const float* lnyg = (const float*)d_in[12];
  const float* lnyb = (const float*)d_in[13];
  const float* qkvw = (const float*)d_in[14];
  const float* apw  = (const float*)d_in[15];
  const float* apb  = (const float*)d_in[16];
  const float* pqw  = (const float*)d_in[17];
  const float* pkw  = (const float*)d_in[18];
  const float* pvw  = (const float*)d_in[19];
  const float* cpw  = (const float*)d_in[20];
  const float* cpb  = (const float*)d_in[21];
  const float* f1w  = (const float*)d_in[22];
  const float* f1b  = (const float*)d_in[23];
  const float* f2w  = (const float*)d_in[24];
  const float* f2b  = (const float*)d_in[25];

  char* ws = (char*)d_ws;
  size_t off = 0;
  auto alloc = [&](size_t bytes) -> void* {
    off = (off + 255) & ~(size_t)255;
    void* p = ws + off;
    off += bytes;
    return p;
  };
  const size_t T = 4096;  // B*NQ
  bf16* w_qkv = (bf16*)alloc((size_t)2304 * 768 * 2);
  bf16* w_ap  = (bf16*)alloc((size_t)768 * 768 * 2);
  bf16* w_pq  = (bf16*)alloc((size_t)768 * 768 * 2);
  bf16* w_pk  = (bf16*)alloc((size_t)768 * 768 * 2);
  bf16* w_pv  = (bf16*)alloc((size_t)768 * 768 * 2);
  bf16* w_cp  = (bf16*)alloc((size_t)768 * 768 * 2);
  bf16* w_f1  = (bf16*)alloc((size_t)3072 * 768 * 2);
  bf16* w_f2  = (bf16*)alloc((size_t)768 * 3072 * 2);
  bf16* xn    = (bf16*)alloc(T * 768 * 2);
  bf16* qkvo  = (bf16*)alloc(T * 2304 * 2);
  bf16* vt    = (bf16*)alloc((size_t)48 * 64 * 1024 * 2);
  bf16* sa    = (bf16*)alloc(T * 768 * 2);
  float* x1   = (float*)alloc(T * 768 * 4);
  bf16* yln   = (bf16*)alloc(T * 768 * 2);
  bf16* xn2   = (bf16*)alloc(T * 768 * 2);
  bf16* cqf   = (bf16*)alloc(T * 768 * 2);
  bf16* ckf   = (bf16*)alloc(T * 768 * 2);
  bf16* cvf   = (bf16*)alloc(T * 768 * 2);
  bf16* cvtT  = (bf16*)alloc((size_t)48 * 64 * 1024 * 2);
  bf16* biasb = (bf16*)alloc((size_t)12 * 1024 * 1024 * 2);  // one batch of bias
  bf16* ca    = (bf16*)alloc(T * 768 * 2);
  float* x2   = (float*)alloc(T * 768 * 4);
  bf16* xn3   = (bf16*)alloc(T * 768 * 2);
  bf16* hbuf  = (bf16*)alloc(T * 3072 * 2);
  int* mshift = (int*)alloc(256);

  detect_mask_k<<<1, 256, 0, stream>>>(mask, mshift);

  auto cvt = [&](const float* s, bf16* d, int n) {
    const int n4 = n / 4;
    cvt_k<<<(n4 + 255) / 256, 256, 0, stream>>>(s, d, n4);
  };
  cvt(qkvw, w_qkv, 2304 * 768);
  cvt(apw,  w_ap,  768 * 768);
  cvt(pqw,  w_pq,  768 * 768);
  cvt(pkw,  w_pk,  768 * 768);
  cvt(pvw,  w_pv,  768 * 768);
  cvt(cpw,  w_cp,  768 * 768);
  cvt(f1w,  w_f1,  3072 * 768);
  cvt(f2w,  w_f2,  768 * 3072);

  // ---- self-attention ----
  ln_k<<<4096, 256, 0, stream>>>(x, ln1g, ln1b, xn);
  gemm_bt<false,false,false,true><<<dim3(18, 32), 256, 0, stream>>>(
      xn, w_qkv, nullptr, nullptr, qkvo, nullptr, 4096, 2304, 768);
  build_vt<<<dim3(48, 16), 256, 0, stream>>>(qkvo + 1536, 2304, vt);
  attn_k<0><<<dim3(12, 32, 4), 512, 0, stream>>>(
      qkvo, 2304, qkvo + 768, 2304, vt, nullptr, 0, sa);
  gemm_bt<true,false,true,false><<<dim3(6, 32), 256, 0, stream>>>(
      sa, w_ap, apb, x, nullptr, x1, 4096, 768, 768);

  // ---- cross-attention ----
  ln_k<<<4096, 256, 0, stream>>>(y, lnyg, lnyb, yln);
  ln_k<<<4096, 256, 0, stream>>>(x1, ln2g, ln2b, xn2);
  gemm_bt<false,false,false,true><<<dim3(6, 32), 256, 0, stream>>>(
      xn2, w_pq, nullptr, nullptr, cqf, nullptr, 4096, 768, 768);
  gemm_bt<false,false,false,true><<<dim3(6, 32), 256, 0, stream>>>(
      yln, w_pk, nullptr, nullptr, ckf, nullptr, 4096, 768, 768);
  gemm_bt<false,false,false,true><<<dim3(6, 32), 256, 0, stream>>>(
      yln, w_pv, nullptr, nullptr, cvf, nullptr, 4096, 768, 768);
  build_vt<<<dim3(48, 16), 256, 0, stream>>>(cvf, 768, cvtT);
  for (int b = 0; b < 4; ++b) {
    bias_k<<<1024, 256, 0, stream>>>(
        sim + (size_t)b * 12 * 1024 * 1024, mask, mshift, biasb);
    attn_k<1><<<dim3(12, 32, 1), 512, 0, stream>>>(
        cqf, 768, ckf, 768, cvtT, biasb, b, ca);
  }
  gemm_bt<true,false,true,false><<<dim3(6, 32), 256, 0, stream>>>(
      ca, w_cp, cpb, x1, nullptr, x2, 4096, 768, 768);

  // ---- MLP ----
  ln_k<<<4096, 256, 0, stream>>>(x2, ln3g, ln3b, xn3);
  gemm_bt<true,true,false,true><<<dim3(24, 32), 256, 0, stream>>>(
      xn3, w_f1, f1b, nullptr, hbuf, nullptr, 4096, 3072, 768);
  gemm_bt<true,false,true,false><<<dim3(6, 32), 256, 0, stream>>>(
      hbuf, w_f2, f2b, x2, nullptr, (float*)d_out, 4096, 768, 3072);

  // ---- y passthrough ----
  copy4_k<<<3072, 256, 0, stream>>>(y, (float*)d_out + 3145728, 786432);
}

// Round 4
// 599.483 us; speedup vs baseline: 1.1176x; 1.1176x over previous
//
#include <hip/hip_runtime.h>
#include <cstdint>
#include <cstddef>

// DinoDecoderBlock on MI355X (gfx950).
// B=4 NQ=NK=1024 C=768 H=12 DH=64, scale=1/8, eps=1e-5.
// bf16 MFMA GEMMs + two-pass in-LDS attention. fp32 residual stream.
// R4: attn -> 16 q-rows/block (72.5 KB LDS, 2 blocks/CU), single-dispatch bias
//     (full 100 MB) + single-dispatch cross-attn, fused weight cvt, pk+pv merged.

typedef __bf16 bf16;
typedef __attribute__((ext_vector_type(8))) __bf16 bf16x8;
typedef __attribute__((ext_vector_type(4))) __bf16 bf16x4;
typedef __attribute__((ext_vector_type(4))) float f32x4;

typedef __attribute__((address_space(1))) void gvoid;
typedef __attribute__((address_space(3))) void lvoid;

#define DEVI static __device__ __forceinline__

DEVI void gload16(const void* g, void* l) {
  __builtin_amdgcn_global_load_lds((gvoid*)(uintptr_t)g, (lvoid*)(uintptr_t)l, 16, 0, 0);
}

DEVI f32x4 mfma_bf16(bf16x8 a, bf16x8 b, f32x4 c) {
  return __builtin_amdgcn_mfma_f32_16x16x32_bf16(a, b, c, 0, 0, 0);
}

// ---------------- mask dtype detection ----------------
__global__ __launch_bounds__(256)
void detect_mask_k(const unsigned char* __restrict__ mask, int* __restrict__ shift)
{
  __shared__ int acc[256];
  const int t = threadIdx.x;
  int s = 0;
  for (int i = t; i < 16384; i += 256) {
    const int base = i * 4;
    s += mask[base + 1] + mask[base + 2] + mask[base + 3];
  }
  acc[t] = s;
  __syncthreads();
  #pragma unroll
  for (int o = 128; o; o >>= 1) {
    if (t < o) acc[t] += acc[t + o];
    __syncthreads();
  }
  if (t == 0) *shift = (acc[0] == 0) ? 2 : 0;
}

// ---------------- fused bias precompute, ALL batches ----------------
// biasOut[b][h][q][k] = sim[b,h,q,k] - mean_h(sim[b,:,q,k]) + (mask[q,k]?0:-1e30)
__global__ __launch_bounds__(256)
void bias_k(const float* __restrict__ sim,
            const unsigned char* __restrict__ mask,
            const int* __restrict__ mshift,
            bf16* __restrict__ biasOut)
{
  const int blk = blockIdx.x;                 // 4096 = b*1024 + q
  const int b = blk >> 10, q = blk & 1023;
  const int t = threadIdx.x;
  const int k4 = t * 4;
  const int msh = *mshift;
  const float* sb = sim + (size_t)b * 12 * 1024 * 1024;
  bf16* ob = biasOut + (size_t)b * 12 * 1024 * 1024;

  f32x4 sv[12];
  f32x4 acc = {0.f, 0.f, 0.f, 0.f};
  #pragma unroll
  for (int h = 0; h < 12; ++h) {
    sv[h] = *(const f32x4*)(sb + ((size_t)h * 1024 + q) * 1024 + k4);
    acc += sv[h];
  }
  const f32x4 mean = acc * (1.0f / 12.0f);

  float mb[4];
  if (msh == 0) {
    const uchar4 mv = *(const uchar4*)(mask + (size_t)q * 1024 + k4);
    mb[0] = mv.x ? 0.f : -1e30f; mb[1] = mv.y ? 0.f : -1e30f;
    mb[2] = mv.z ? 0.f : -1e30f; mb[3] = mv.w ? 0.f : -1e30f;
  } else {
    const int4 mv = *(const int4*)((const int*)mask + (size_t)q * 1024 + k4);
    mb[0] = mv.x ? 0.f : -1e30f; mb[1] = mv.y ? 0.f : -1e30f;
    mb[2] = mv.z ? 0.f : -1e30f; mb[3] = mv.w ? 0.f : -1e30f;
  }

  #pragma unroll
  for (int h = 0; h < 12; ++h) {
    bf16x4 o;
    #pragma unroll
    for (int j = 0; j < 4; ++j)
      o[j] = (bf16)(sv[h][j] - mean[j] + mb[j]);
    *(bf16x4*)(ob + ((size_t)h * 1024 + q) * 1024 + k4) = o;
  }
}

// ---------------- fused fp32 -> bf16 convert for all 8 weights ----------------
struct CvtArgs {
  const float* src[8];
  bf16* dst[8];
  int end[8];     // cumulative f32x4 counts
};
__global__ __launch_bounds__(256)
void cvt_all_k(CvtArgs a)
{
  const int i = blockIdx.x * 256 + threadIdx.x;
  int s = 0;
  #pragma unroll
  for (int j = 0; j < 7; ++j) s += (i >= a.end[j]) ? 1 : 0;
  const int base = s ? a.end[s - 1] : 0;
  const int off = i - base;
  const f32x4 v = *((const f32x4*)a.src[s] + off);
  bf16x4 o;
  o[0] = (bf16)v[0]; o[1] = (bf16)v[1]; o[2] = (bf16)v[2]; o[3] = (bf16)v[3];
  *(bf16x4*)(a.dst[s] + (size_t)off * 4) = o;
}

// ---------------- float4 copy ----------------
__global__ __launch_bounds__(256)
void copy4_k(const float* __restrict__ s, float* __restrict__ d, int n4)
{
  const int i = blockIdx.x * 256 + threadIdx.x;
  if (i < n4) ((f32x4*)d)[i] = ((const f32x4*)s)[i];
}

// ---------------- LayerNorm over 768, fp32 in -> bf16 out ----------------
__global__ __launch_bounds__(256)
void ln_k(const float* __restrict__ xin, const float* __restrict__ g,
          const float* __restrict__ be, bf16* __restrict__ out)
{
  const int row = blockIdx.x, tid = threadIdx.x;
  const int lane = tid & 63, w = tid >> 6;
  const float* xr = xin + (size_t)row * 768;
  const float v0 = xr[tid], v1 = xr[tid + 256], v2 = xr[tid + 512];
  float s = v0 + v1 + v2;
  #pragma unroll
  for (int o = 32; o; o >>= 1) s += __shfl_xor(s, o);
  __shared__ float r1[4], r2[4];
  if (lane == 0) r1[w] = s;
  __syncthreads();
  const float mean = (r1[0] + r1[1] + r1[2] + r1[3]) * (1.0f / 768.0f);
  const float d0 = v0 - mean, d1 = v1 - mean, d2 = v2 - mean;
  float q = d0 * d0 + d1 * d1 + d2 * d2;
  #pragma unroll
  for (int o = 32; o; o >>= 1) q += __shfl_xor(q, o);
  if (lane == 0) r2[w] = q;
  __syncthreads();
  const float inv = rsqrtf((r2[0] + r2[1] + r2[2] + r2[3]) * (1.0f / 768.0f) + 1e-5f);
  bf16* orow = out + (size_t)row * 768;
  orow[tid]       = (bf16)(d0 * inv * g[tid]       + be[tid]);
  orow[tid + 256] = (bf16)(d1 * inv * g[tid + 256] + be[tid + 256]);
  orow[tid + 512] = (bf16)(d2 * inv * g[tid + 512] + be[tid + 512]);
}

// ---------------- V transpose ----------------
__global__ __launch_bounds__(256)
void build_vt(const bf16* __restrict__ src, int ld, bf16* __restrict__ vt)
{
  __shared__ unsigned short t[64][72];
  const int bh = blockIdx.x, nt = blockIdx.y;
  const int b = bh / 12, hh = bh % 12;
  const int tid = threadIdx.x;
  {
    const int nl = tid >> 2, d0 = (tid & 3) * 16;
    const unsigned short* srow = (const unsigned short*)src
        + (size_t)(b * 1024 + nt * 64 + nl) * ld + hh * 64 + d0;
    #pragma unroll
    for (int j = 0; j < 4; ++j)
      *(ushort4*)(&t[nl][d0 + j * 4]) = *(const ushort4*)(srow + j * 4);
  }
  __syncthreads();
  {
    const int dl = tid >> 2, n0 = (tid & 3) * 16;
    unsigned short* drow = (unsigned short*)vt + ((size_t)bh * 64 + dl) * 1024 + nt * 64 + n0;
    #pragma unroll
    for (int j = 0; j < 4; ++j) {
      ushort4 o;
      o.x = t[n0 + j * 4 + 0][dl];
      o.y = t[n0 + j * 4 + 1][dl];
      o.z = t[n0 + j * 4 + 2][dl];
      o.w = t[n0 + j * 4 + 3][dl];
      *(ushort4*)(drow + j * 4) = o;
    }
  }
}

// ---------------- GEMM: C[M,N] = A[M,K] * Bt[N,K]^T ----------------
template<bool BIAS, bool GELU, bool RES, bool OBF>
__global__ __launch_bounds__(256)
void gemm_bt(const bf16* __restrict__ A, const bf16* __restrict__ Bt,
             const float* __restrict__ bias, const float* __restrict__ res,
             bf16* __restrict__ Cb, float* __restrict__ Cf,
             int M, int N, int K)
{
  __shared__ bf16 As[128 * 64];
  __shared__ bf16 Bs[128 * 64];
  const int tid = threadIdx.x;
  const int lane = tid & 63;
  const int wv = tid >> 6;
  const int wr = wv >> 1, wc = wv & 1;
  const int l15 = lane & 15, lg = lane >> 4;
  const int bm = blockIdx.y * 128, bn = blockIdx.x * 128;
  (void)M;

  f32x4 acc[4][4];
  const f32x4 z = {0.f, 0.f, 0.f, 0.f};
  #pragma unroll
  for (int i = 0; i < 4; ++i)
    #pragma unroll
    for (int j = 0; j < 4; ++j) acc[i][j] = z;

  for (int k0 = 0; k0 < K; k0 += 64) {
    __syncthreads();
    #pragma unroll
    for (int i = 0; i < 4; ++i) {
      const int c = wv * 256 + i * 64 + lane;
      const int row = c >> 3;
      const int colb = (c & 7) << 4;
      gload16((const char*)A  + ((size_t)(bm + row) * K + k0) * 2 + colb,
              (char*)As + (size_t)c * 16);
      gload16((const char*)Bt + ((size_t)(bn + row) * K + k0) * 2 + colb,
              (char*)Bs + (size_t)c * 16);
    }
    __syncthreads();
    #pragma unroll
    for (int kk = 0; kk < 64; kk += 32) {
      bf16x8 af[4], bfr[4];
      #pragma unroll
      for (int mi = 0; mi < 4; ++mi)
        af[mi] = *(const bf16x8*)(As + (size_t)(wr * 64 + mi * 16 + l15) * 64 + kk + lg * 8);
      #pragma unroll
      for (int ni = 0; ni < 4; ++ni)
        bfr[ni] = *(const bf16x8*)(Bs + (size_t)(wc * 64 + ni * 16 + l15) * 64 + kk + lg * 8);
      #pragma unroll
      for (int mi = 0; mi < 4; ++mi)
        #pragma unroll
        for (int ni = 0; ni < 4; ++ni)
          acc[mi][ni] = mfma_bf16(af[mi], bfr[ni], acc[mi][ni]);
    }
  }

  #pragma unroll
  for (int mi = 0; mi < 4; ++mi) {
    const int row0 = bm + wr * 64 + mi * 16 + lg * 4;
    #pragma unroll
    for (int ni = 0; ni < 4; ++ni) {
      const int col = bn + wc * 64 + ni * 16 + l15;
      #pragma unroll
      for (int r = 0; r < 4; ++r) {
        float v = acc[mi][ni][r];
        if constexpr (BIAS) v += bias[col];
        if constexpr (GELU) v = 0.5f * v * (1.0f + erff(v * 0.70710678118654752f));
        if constexpr (RES)  v += res[(size_t)(row0 + r) * N + col];
        if constexpr (OBF)  Cb[(size_t)(row0 + r) * N + col] = (bf16)v;
        else                Cf[(size_t)(row0 + r) * N + col] = v;
      }
    }
  }
}

// ---------------- attention: one (qt=16 rows, h, b) per block, 8 waves ----------------
// 72.5 KB LDS -> 2 blocks/CU. Grid (qt, h, b) so consecutive blocks share K/V panels.
// phase1: S = QK^T/8 (+bias) fp32 [16][1028]; phase2: softmax -> P bf16 in place;
// phase3: P*V, K-dim split across wave pairs, LDS partial combine.
template<int CROSS>
__global__ __launch_bounds__(512)
void attn_k(const bf16* __restrict__ Qp, int ldq,
            const bf16* __restrict__ Kp, int ldk,
            const bf16* __restrict__ Vt,
            const bf16* __restrict__ bias,   // [4][12][1024][1024], CROSS only
            bf16* __restrict__ Out)
{
  __shared__ float S[16][1028];
  __shared__ bf16 Qs[16][72];
  __shared__ float Obuf[16][68];
  const int qt = blockIdx.x, hh = blockIdx.y, b = blockIdx.z;
  const int tid = threadIdx.x, lane = tid & 63, w = tid >> 6;
  const int l15 = lane & 15, lg = lane >> 4;

  if (tid < 256) { // stage Q tile [16 x 64]
    const int r = tid >> 4, c4 = (tid & 15) << 2;
    const bf16* srcp = Qp + (size_t)(b * 1024 + qt * 16 + r) * ldq + hh * 64 + c4;
    *(ushort4*)(&Qs[r][c4]) = *(const ushort4*)srcp;
  }
  if constexpr (CROSS) { // stage bias tile into S, contiguous f32x4 writes
    const bf16* brow = bias + (((size_t)(b * 12 + hh)) * 1024 + qt * 16) * 1024;
    #pragma unroll
    for (int j = 0; j < 8; ++j) {
      const int idx = j * 512 + tid;       // f32x4 chunk, 0..4095
      const int row = idx >> 8;            // 256 chunks per row
      const int c4 = (idx & 255) << 2;
      const bf16x4 v = *(const bf16x4*)(brow + (size_t)row * 1024 + c4);
      f32x4 o;
      o[0] = (float)v[0]; o[1] = (float)v[1]; o[2] = (float)v[2]; o[3] = (float)v[3];
      *(f32x4*)(&S[row][c4]) = o;
    }
  }
  __syncthreads();

  { // phase 1: wave w owns kv cols [w*128, w*128+128)
    f32x4 sacc[8];
    const f32x4 z = {0.f, 0.f, 0.f, 0.f};
    #pragma unroll
    for (int j = 0; j < 8; ++j) sacc[j] = z;
    const bf16* Kb = Kp + (size_t)b * 1024 * ldk + hh * 64;
    #pragma unroll
    for (int kk = 0; kk < 64; kk += 32) {
      const bf16x8 aq = *(const bf16x8*)(&Qs[l15][kk + lg * 8]);
      #pragma unroll
      for (int ni = 0; ni < 8; ++ni) {
        const bf16x8 bk = *(const bf16x8*)(Kb + (size_t)(w * 128 + ni * 16 + l15) * ldk + kk + lg * 8);
        sacc[ni] = mfma_bf16(aq, bk, sacc[ni]);
      }
    }
    const int rq = lg * 4;
    #pragma unroll
    for (int ni = 0; ni < 8; ++ni) {
      const int col = w * 128 + ni * 16 + l15;
      #pragma unroll
      for (int r = 0; r < 4; ++r) {
        float v = sacc[ni][r] * 0.125f;
        if constexpr (CROSS) v += S[rq + r][col];
        S[rq + r][col] = v;
      }
    }
  }
  __syncthreads();

  { // phase 2: softmax rows [w*2, w*2+2)
    #pragma unroll
    for (int rr = 0; rr < 2; ++rr) {
      const int row = w * 2 + rr;
      float vv[16];
      #pragma unroll
      for (int j = 0; j < 16; ++j) vv[j] = S[row][lane + 64 * j];
      float m = vv[0];
      #pragma unroll
      for (int j = 1; j < 16; ++j) m = fmaxf(m, vv[j]);
      #pragma unroll
      for (int o = 32; o; o >>= 1) m = fmaxf(m, __shfl_xor(m, o));
      float s = 0.f;
      #pragma unroll
      for (int j = 0; j < 16; ++j) { vv[j] = __expf(vv[j] - m); s += vv[j]; }
      #pragma unroll
      for (int o = 32; o; o >>= 1) s += __shfl_xor(s, o);
      const float inv = 1.0f / s;
      bf16* prow = (bf16*)(&S[row][0]);
      #pragma unroll
      for (int j = 0; j < 16; ++j) prow[lane + 64 * j] = (bf16)(vv[j] * inv);
    }
  }
  __syncthreads();

  { // phase 3: wave w -> d-tile (w&3), k-half (w>>2); dual accumulators
    const int dt = (w & 3) * 16, kh = (w >> 2) * 512;
    f32x4 oa = {0.f, 0.f, 0.f, 0.f}, ob = {0.f, 0.f, 0.f, 0.f};
    const bf16* vb = Vt + ((size_t)(b * 12 + hh) * 64 + dt + l15) * 1024 + kh + lg * 8;
    const bf16* pr = (const bf16*)(&S[l15][0]) + kh + lg * 8;
    #pragma unroll 4
    for (int k0 = 0; k0 < 512; k0 += 64) {
      oa = mfma_bf16(*(const bf16x8*)(pr + k0),      *(const bf16x8*)(vb + k0),      oa);
      ob = mfma_bf16(*(const bf16x8*)(pr + k0 + 32), *(const bf16x8*)(vb + k0 + 32), ob);
    }
    oa += ob;
    if (w >= 4) {
      #pragma unroll
      for (int r = 0; r < 4; ++r) Obuf[lg * 4 + r][dt + l15] = oa[r];
    }
    __syncthreads();
    if (w < 4) {
      #pragma unroll
      for (int r = 0; r < 4; ++r) {
        const float v = oa[r] + Obuf[lg * 4 + r][dt + l15];
        Out[((size_t)(b * 1024 + qt * 16 + lg * 4 + r)) * 768 + hh * 64 + dt + l15] = (bf16)v;
      }
    }
  }
}

// ---------------- launcher ----------------
extern "C" void kernel_launch(void* const* d_in, const int* in_sizes, int n_in,
                              void* d_out, int out_size, void* d_ws, size_t ws_size,
                              hipStream_t stream)
{
  (void)in_sizes; (void)n_in; (void)out_size; (void)ws_size;
  const float* x    = (const float*)d_in[0];
  const float* y    = (const float*)d_in[1];
  const unsigned char* mask = (const unsigned char*)d_in[4];
  const float* sim  = (const float*)d_in[5];
  const float* ln1g = (const float*)d_in[6];
  const float* ln1b = (const float*)d_in[7];
  const float* ln2g = (const float*)d_in[8];
  const float* ln2b = (const float*)d_in[9];
  const float* ln3g = (const float*)d_in[10];
  const float* ln3b = (const float*)d_in[11];
  const float* lnyg = (const float*)d_in[12];
  const float* lnyb = (const float*)d_in[13];
  const float* qkvw = (const float*)d_in[14];
  const float* apw  = (const float*)d_in[15];
  const float* apb  = (const float*)d_in[16];
  const float* pqw  = (const float*)d_in[17];
  const float* pkw  = (const float*)d_in[18];
  const float* pvw  = (const float*)d_in[19];
  const float* cpw  = (const float*)d_in[20];
  const float* cpb  = (const float*)d_in[21];
  const float* f1w  = (const float*)d_in[22];
  const float* f1b  = (const float*)d_in[23];
  const float* f2w  = (const float*)d_in[24];
  const float* f2b  = (const float*)d_in[25];

  char* ws = (char*)d_ws;
  size_t off = 0;
  auto alloc = [&](size_t bytes) -> void* {
    off = (off + 255) & ~(size_t)255;
    void* p = ws + off;
    off += bytes;
    return p;
  };
  const size_t T = 4096;  // B*NQ
  bf16* w_qkv = (bf16*)alloc((size_t)2304 * 768 * 2);
  bf16* w_ap  = (bf16*)alloc((size_t)768 * 768 * 2);
  bf16* w_pq  = (bf16*)alloc((size_t)768 * 768 * 2);
  bf16* w_pkv = (bf16*)alloc((size_t)1536 * 768 * 2);
  bf16* w_cp  = (bf16*)alloc((size_t)768 * 768 * 2);
  bf16* w_f1  = (bf16*)alloc((size_t)3072 * 768 * 2);
  bf16* w_f2  = (bf16*)alloc((size_t)768 * 3072 * 2);
  bf16* xn    = (bf16*)alloc(T * 768 * 2);
  bf16* qkvo  = (bf16*)alloc(T * 2304 * 2);
  bf16* vt    = (bf16*)alloc((size_t)48 * 64 * 1024 * 2);
  bf16* sa    = (bf16*)alloc(T * 768 * 2);
  float* x1   = (float*)alloc(T * 768 * 4);
  bf16* yln   = (bf16*)alloc(T * 768 * 2);
  bf16* xn2   = (bf16*)alloc(T * 768 * 2);
  bf16* cqf   = (bf16*)alloc(T * 768 * 2);
  bf16* ckv   = (bf16*)alloc(T * 1536 * 2);
  bf16* cvtT  = (bf16*)alloc((size_t)48 * 64 * 1024 * 2);
  bf16* biasA = (bf16*)alloc((size_t)4 * 12 * 1024 * 1024 * 2);  // 100.7 MB
  bf16* ca    = (bf16*)alloc(T * 768 * 2);
  float* x2   = (float*)alloc(T * 768 * 4);
  bf16* xn3   = (bf16*)alloc(T * 768 * 2);
  bf16* hbuf  = (bf16*)alloc(T * 3072 * 2);
  int* mshift = (int*)alloc(256);

  detect_mask_k<<<1, 256, 0, stream>>>(mask, mshift);

  { // fused weight conversion (pk,pv land adjacent in w_pkv)
    CvtArgs a;
    const float* srcs[8] = {qkvw, apw, pqw, pkw, pvw, cpw, f1w, f2w};
    bf16* dsts[8] = {w_qkv, w_ap, w_pq, w_pkv, w_pkv + 768 * 768, w_cp, w_f1, w_f2};
    const int n4s[8] = {442368, 147456, 147456, 147456, 147456, 147456, 589824, 589824};
    int cum = 0;
    for (int j = 0; j < 8; ++j) {
      a.src[j] = srcs[j]; a.dst[j] = dsts[j];
      cum += n4s[j]; a.end[j] = cum;
    }
    cvt_all_k<<<cum / 256, 256, 0, stream>>>(a);   // 9216 blocks
  }

  // bias precompute (independent of everything but sim/mask)
  bias_k<<<4096, 256, 0, stream>>>(sim, mask, mshift, biasA);

  // ---- self-attention ----
  ln_k<<<4096, 256, 0, stream>>>(x, ln1g, ln1b, xn);
  gemm_bt<false,false,false,true><<<dim3(18, 32), 256, 0, stream>>>(
      xn, w_qkv, nullptr, nullptr, qkvo, nullptr, 4096, 2304, 768);
  build_vt<<<dim3(48, 16), 256, 0, stream>>>(qkvo + 1536, 2304, vt);
  attn_k<0><<<dim3(64, 12, 4), 512, 0, stream>>>(
      qkvo, 2304, qkvo + 768, 2304, vt, nullptr, sa);
  gemm_bt<true,false,true,false><<<dim3(6, 32), 256, 0, stream>>>(
      sa, w_ap, apb, x, nullptr, x1, 4096, 768, 768);

  // ---- cross-attention ----
  ln_k<<<4096, 256, 0, stream>>>(y, lnyg, lnyb, yln);
  ln_k<<<4096, 256, 0, stream>>>(x1, ln2g, ln2b, xn2);
  gemm_bt<false,false,false,true><<<dim3(6, 32), 256, 0, stream>>>(
      xn2, w_pq, nullptr, nullptr, cqf, nullptr, 4096, 768, 768);
  gemm_bt<false,false,false,true><<<dim3(12, 32), 256, 0, stream>>>(
      yln, w_pkv, nullptr, nullptr, ckv, nullptr, 4096, 1536, 768);
  build_vt<<<dim3(48, 16), 256, 0, stream>>>(ckv + 768, 1536, cvtT);
  attn_k<1><<<dim3(64, 12, 4), 512, 0, stream>>>(
      cqf, 768, ckv, 1536, cvtT, biasA, ca);
  gemm_bt<true,false,true,false><<<dim3(6, 32), 256, 0, stream>>>(
      ca, w_cp, cpb, x1, nullptr, x2, 4096, 768, 768);

  // ---- MLP ----
  ln_k<<<4096, 256, 0, stream>>>(x2, ln3g, ln3b, xn3);
  gemm_bt<true,true,false,true><<<dim3(24, 32), 256, 0, stream>>>(
      xn3, w_f1, f1b, nullptr, hbuf, nullptr, 4096, 3072, 768);
  gemm_bt<true,false,true,false><<<dim3(6, 32), 256, 0, stream>>>(
      hbuf, w_f2, f2b, x2, nullptr, (float*)d_out, 4096, 768, 3072);

  // ---- y passthrough ----
  copy4_k<<<3072, 256, 0, stream>>>(y, (float*)d_out + 3145728, 786432);
}

// Round 5
// 541.852 us; speedup vs baseline: 1.2365x; 1.1064x over previous
//
#include <hip/hip_runtime.h>
#include <cstdint>
#include <cstddef>

// DinoDecoderBlock on MI355X (gfx950).
// B=4 NQ=NK=1024 C=768 H=12 DH=64, scale=1/8, eps=1e-5.
// R5: XCD-clustered attention grid (one XCD per (h,b) K/V panel -> L2 hits),
//     GEMM templated BM/BN (64x128 for N=768 GEMMs -> 384 blocks, 4+ blocks/CU),
//     bf16x8 bias staging.

typedef __bf16 bf16;
typedef __attribute__((ext_vector_type(8))) __bf16 bf16x8;
typedef __attribute__((ext_vector_type(4))) __bf16 bf16x4;
typedef __attribute__((ext_vector_type(4))) float f32x4;

typedef __attribute__((address_space(1))) void gvoid;
typedef __attribute__((address_space(3))) void lvoid;

#define DEVI static __device__ __forceinline__

DEVI void gload16(const void* g, void* l) {
  __builtin_amdgcn_global_load_lds((gvoid*)(uintptr_t)g, (lvoid*)(uintptr_t)l, 16, 0, 0);
}

DEVI f32x4 mfma_bf16(bf16x8 a, bf16x8 b, f32x4 c) {
  return __builtin_amdgcn_mfma_f32_16x16x32_bf16(a, b, c, 0, 0, 0);
}

// ---------------- mask dtype detection ----------------
__global__ __launch_bounds__(256)
void detect_mask_k(const unsigned char* __restrict__ mask, int* __restrict__ shift)
{
  __shared__ int acc[256];
  const int t = threadIdx.x;
  int s = 0;
  for (int i = t; i < 16384; i += 256) {
    const int base = i * 4;
    s += mask[base + 1] + mask[base + 2] + mask[base + 3];
  }
  acc[t] = s;
  __syncthreads();
  #pragma unroll
  for (int o = 128; o; o >>= 1) {
    if (t < o) acc[t] += acc[t + o];
    __syncthreads();
  }
  if (t == 0) *shift = (acc[0] == 0) ? 2 : 0;
}

// ---------------- fused bias precompute, ALL batches ----------------
__global__ __launch_bounds__(256)
void bias_k(const float* __restrict__ sim,
            const unsigned char* __restrict__ mask,
            const int* __restrict__ mshift,
            bf16* __restrict__ biasOut)
{
  const int blk = blockIdx.x;                 // 4096 = b*1024 + q
  const int b = blk >> 10, q = blk & 1023;
  const int t = threadIdx.x;
  const int k4 = t * 4;
  const int msh = *mshift;
  const float* sb = sim + (size_t)b * 12 * 1024 * 1024;
  bf16* ob = biasOut + (size_t)b * 12 * 1024 * 1024;

  f32x4 sv[12];
  f32x4 acc = {0.f, 0.f, 0.f, 0.f};
  #pragma unroll
  for (int h = 0; h < 12; ++h) {
    sv[h] = *(const f32x4*)(sb + ((size_t)h * 1024 + q) * 1024 + k4);
    acc += sv[h];
  }
  const f32x4 mean = acc * (1.0f / 12.0f);

  float mb[4];
  if (msh == 0) {
    const uchar4 mv = *(const uchar4*)(mask + (size_t)q * 1024 + k4);
    mb[0] = mv.x ? 0.f : -1e30f; mb[1] = mv.y ? 0.f : -1e30f;
    mb[2] = mv.z ? 0.f : -1e30f; mb[3] = mv.w ? 0.f : -1e30f;
  } else {
    const int4 mv = *(const int4*)((const int*)mask + (size_t)q * 1024 + k4);
    mb[0] = mv.x ? 0.f : -1e30f; mb[1] = mv.y ? 0.f : -1e30f;
    mb[2] = mv.z ? 0.f : -1e30f; mb[3] = mv.w ? 0.f : -1e30f;
  }

  #pragma unroll
  for (int h = 0; h < 12; ++h) {
    bf16x4 o;
    #pragma unroll
    for (int j = 0; j < 4; ++j)
      o[j] = (bf16)(sv[h][j] - mean[j] + mb[j]);
    *(bf16x4*)(ob + ((size_t)h * 1024 + q) * 1024 + k4) = o;
  }
}

// ---------------- fused fp32 -> bf16 convert for all 8 weights ----------------
struct CvtArgs {
  const float* src[8];
  bf16* dst[8];
  int end[8];
};
__global__ __launch_bounds__(256)
void cvt_all_k(CvtArgs a)
{
  const int i = blockIdx.x * 256 + threadIdx.x;
  int s = 0;
  #pragma unroll
  for (int j = 0; j < 7; ++j) s += (i >= a.end[j]) ? 1 : 0;
  const int base = s ? a.end[s - 1] : 0;
  const int off = i - base;
  const f32x4 v = *((const f32x4*)a.src[s] + off);
  bf16x4 o;
  o[0] = (bf16)v[0]; o[1] = (bf16)v[1]; o[2] = (bf16)v[2]; o[3] = (bf16)v[3];
  *(bf16x4*)(a.dst[s] + (size_t)off * 4) = o;
}

// ---------------- float4 copy ----------------
__global__ __launch_bounds__(256)
void copy4_k(const float* __restrict__ s, float* __restrict__ d, int n4)
{
  const int i = blockIdx.x * 256 + threadIdx.x;
  if (i < n4) ((f32x4*)d)[i] = ((const f32x4*)s)[i];
}

// ---------------- LayerNorm over 768, fp32 in -> bf16 out ----------------
__global__ __launch_bounds__(256)
void ln_k(const float* __restrict__ xin, const float* __restrict__ g,
          const float* __restrict__ be, bf16* __restrict__ out)
{
  const int row = blockIdx.x, tid = threadIdx.x;
  const int lane = tid & 63, w = tid >> 6;
  const float* xr = xin + (size_t)row * 768;
  const float v0 = xr[tid], v1 = xr[tid + 256], v2 = xr[tid + 512];
  float s = v0 + v1 + v2;
  #pragma unroll
  for (int o = 32; o; o >>= 1) s += __shfl_xor(s, o);
  __shared__ float r1[4], r2[4];
  if (lane == 0) r1[w] = s;
  __syncthreads();
  const float mean = (r1[0] + r1[1] + r1[2] + r1[3]) * (1.0f / 768.0f);
  const float d0 = v0 - mean, d1 = v1 - mean, d2 = v2 - mean;
  float q = d0 * d0 + d1 * d1 + d2 * d2;
  #pragma unroll
  for (int o = 32; o; o >>= 1) q += __shfl_xor(q, o);
  if (lane == 0) r2[w] = q;
  __syncthreads();
  const float inv = rsqrtf((r2[0] + r2[1] + r2[2] + r2[3]) * (1.0f / 768.0f) + 1e-5f);
  bf16* orow = out + (size_t)row * 768;
  orow[tid]       = (bf16)(d0 * inv * g[tid]       + be[tid]);
  orow[tid + 256] = (bf16)(d1 * inv * g[tid + 256] + be[tid + 256]);
  orow[tid + 512] = (bf16)(d2 * inv * g[tid + 512] + be[tid + 512]);
}

// ---------------- V transpose ----------------
__global__ __launch_bounds__(256)
void build_vt(const bf16* __restrict__ src, int ld, bf16* __restrict__ vt)
{
  __shared__ unsigned short t[64][72];
  const int bh = blockIdx.x, nt = blockIdx.y;
  const int b = bh / 12, hh = bh % 12;
  const int tid = threadIdx.x;
  {
    const int nl = tid >> 2, d0 = (tid & 3) * 16;
    const unsigned short* srow = (const unsigned short*)src
        + (size_t)(b * 1024 + nt * 64 + nl) * ld + hh * 64 + d0;
    #pragma unroll
    for (int j = 0; j < 4; ++j)
      *(ushort4*)(&t[nl][d0 + j * 4]) = *(const ushort4*)(srow + j * 4);
  }
  __syncthreads();
  {
    const int dl = tid >> 2, n0 = (tid & 3) * 16;
    unsigned short* drow = (unsigned short*)vt + ((size_t)bh * 64 + dl) * 1024 + nt * 64 + n0;
    #pragma unroll
    for (int j = 0; j < 4; ++j) {
      ushort4 o;
      o.x = t[n0 + j * 4 + 0][dl];
      o.y = t[n0 + j * 4 + 1][dl];
      o.z = t[n0 + j * 4 + 2][dl];
      o.w = t[n0 + j * 4 + 3][dl];
      *(ushort4*)(drow + j * 4) = o;
    }
  }
}

// ---------------- GEMM: C[M,N] = A[M,K] * Bt[N,K]^T, tile BM x BN ----------------
// 4 waves (2x2); wave tile (BM/2)x(BN/2); fragments (BM/32)x(BN/32).
template<int BM, int BN, bool BIAS, bool GELU, bool RES, bool OBF>
__global__ __launch_bounds__(256)
void gemm_bt(const bf16* __restrict__ A, const bf16* __restrict__ Bt,
             const float* __restrict__ bias, const float* __restrict__ res,
             bf16* __restrict__ Cb, float* __restrict__ Cf,
             int M, int N, int K)
{
  constexpr int WM = BM / 2, WN = BN / 2;
  constexpr int FM = WM / 16, FN = WN / 16;
  __shared__ bf16 As[BM * 64];
  __shared__ bf16 Bs[BN * 64];
  const int tid = threadIdx.x;
  const int lane = tid & 63;
  const int wv = tid >> 6;
  const int wr = wv >> 1, wc = wv & 1;
  const int l15 = lane & 15, lg = lane >> 4;
  const int bm = blockIdx.y * BM, bn = blockIdx.x * BN;
  (void)M;

  f32x4 acc[FM][FN];
  const f32x4 z = {0.f, 0.f, 0.f, 0.f};
  #pragma unroll
  for (int i = 0; i < FM; ++i)
    #pragma unroll
    for (int j = 0; j < FN; ++j) acc[i][j] = z;

  for (int k0 = 0; k0 < K; k0 += 64) {
    __syncthreads();
    #pragma unroll
    for (int c = tid; c < BM * 8; c += 256) {
      const int row = c >> 3, colb = (c & 7) << 4;
      gload16((const char*)A + ((size_t)(bm + row) * K + k0) * 2 + colb,
              (char*)As + (size_t)c * 16);
    }
    #pragma unroll
    for (int c = tid; c < BN * 8; c += 256) {
      const int row = c >> 3, colb = (c & 7) << 4;
      gload16((const char*)Bt + ((size_t)(bn + row) * K + k0) * 2 + colb,
              (char*)Bs + (size_t)c * 16);
    }
    __syncthreads();
    #pragma unroll
    for (int kk = 0; kk < 64; kk += 32) {
      bf16x8 af[FM], bfr[FN];
      #pragma unroll
      for (int mi = 0; mi < FM; ++mi)
        af[mi] = *(const bf16x8*)(As + (size_t)(wr * WM + mi * 16 + l15) * 64 + kk + lg * 8);
      #pragma unroll
      for (int ni = 0; ni < FN; ++ni)
        bfr[ni] = *(const bf16x8*)(Bs + (size_t)(wc * WN + ni * 16 + l15) * 64 + kk + lg * 8);
      #pragma unroll
      for (int mi = 0; mi < FM; ++mi)
        #pragma unroll
        for (int ni = 0; ni < FN; ++ni)
          acc[mi][ni] = mfma_bf16(af[mi], bfr[ni], acc[mi][ni]);
    }
  }

  #pragma unroll
  for (int mi = 0; mi < FM; ++mi) {
    const int row0 = bm + wr * WM + mi * 16 + lg * 4;
    #pragma unroll
    for (int ni = 0; ni < FN; ++ni) {
      const int col = bn + wc * WN + ni * 16 + l15;
      #pragma unroll
      for (int r = 0; r < 4; ++r) {
        float v = acc[mi][ni][r];
        if constexpr (BIAS) v += bias[col];
        if constexpr (GELU) v = 0.5f * v * (1.0f + erff(v * 0.70710678118654752f));
        if constexpr (RES)  v += res[(size_t)(row0 + r) * N + col];
        if constexpr (OBF)  Cb[(size_t)(row0 + r) * N + col] = (bf16)v;
        else                Cf[(size_t)(row0 + r) * N + col] = v;
      }
    }
  }
}

// ---------------- attention: XCD-clustered grid, 16 q-rows/block, 8 waves ----------------
// Linear grid 3072. Decode so all 64 qt-blocks of pair p=(h+12b) get ids == p (mod 8):
// assuming wgid%8 -> XCD, each (h,b)'s 256 KB K/V panel lives in ONE XCD's L2.
template<int CROSS>
__global__ __launch_bounds__(512)
void attn_k(const bf16* __restrict__ Qp, int ldq,
            const bf16* __restrict__ Kp, int ldk,
            const bf16* __restrict__ Vt,
            const bf16* __restrict__ bias,   // [4][12][1024][1024], CROSS only
            bf16* __restrict__ Out)
{
  __shared__ float S[16][1028];
  __shared__ bf16 Qs[16][72];
  __shared__ float Obuf[16][68];
  const int f = blockIdx.x;
  const int r8 = f & 7, kix = f >> 3;
  const int c6 = kix >> 6, qt = kix & 63;
  const int p = r8 + 8 * c6;                 // 0..47
  const int b = p / 12, hh = p % 12;
  const int tid = threadIdx.x, lane = tid & 63, w = tid >> 6;
  const int l15 = lane & 15, lg = lane >> 4;

  if (tid < 256) { // stage Q tile [16 x 64]
    const int r = tid >> 4, c4 = (tid & 15) << 2;
    const bf16* srcp = Qp + (size_t)(b * 1024 + qt * 16 + r) * ldq + hh * 64 + c4;
    *(ushort4*)(&Qs[r][c4]) = *(const ushort4*)srcp;
  }
  if constexpr (CROSS) { // stage bias tile into S, bf16x8 loads
    const bf16* brow = bias + (((size_t)(b * 12 + hh)) * 1024 + qt * 16) * 1024;
    #pragma unroll
    for (int j = 0; j < 4; ++j) {
      const int idx = j * 512 + tid;       // bf16x8 chunk, 0..2047
      const int row = idx >> 7;            // 128 chunks per row
      const int c8 = (idx & 127) << 3;
      const bf16x8 v = *(const bf16x8*)(brow + (size_t)row * 1024 + c8);
      f32x4 o0, o1;
      o0[0] = (float)v[0]; o0[1] = (float)v[1]; o0[2] = (float)v[2]; o0[3] = (float)v[3];
      o1[0] = (float)v[4]; o1[1] = (float)v[5]; o1[2] = (float)v[6]; o1[3] = (float)v[7];
      *(f32x4*)(&S[row][c8]) = o0;
      *(f32x4*)(&S[row][c8 + 4]) = o1;
    }
  }
  __syncthreads();

  { // phase 1: wave w owns kv cols [w*128, w*128+128)
    f32x4 sacc[8];
    const f32x4 z = {0.f, 0.f, 0.f, 0.f};
    #pragma unroll
    for (int j = 0; j < 8; ++j) sacc[j] = z;
    const bf16* Kb = Kp + (size_t)b * 1024 * ldk + hh * 64;
    #pragma unroll
    for (int kk = 0; kk < 64; kk += 32) {
      const bf16x8 aq = *(const bf16x8*)(&Qs[l15][kk + lg * 8]);
      #pragma unroll
      for (int ni = 0; ni < 8; ++ni) {
        const bf16x8 bk = *(const bf16x8*)(Kb + (size_t)(w * 128 + ni * 16 + l15) * ldk + kk + lg * 8);
        sacc[ni] = mfma_bf16(aq, bk, sacc[ni]);
      }
    }
    const int rq = lg * 4;
    #pragma unroll
    for (int ni = 0; ni < 8; ++ni) {
      const int col = w * 128 + ni * 16 + l15;
      #pragma unroll
      for (int r = 0; r < 4; ++r) {
        float v = sacc[ni][r] * 0.125f;
        if constexpr (CROSS) v += S[rq + r][col];
        S[rq + r][col] = v;
      }
    }
  }
  __syncthreads();

  { // phase 2: softmax rows [w*2, w*2+2)
    #pragma unroll
    for (int rr = 0; rr < 2; ++rr) {
      const int row = w * 2 + rr;
      float vv[16];
      #pragma unroll
      for (int j = 0; j < 16; ++j) vv[j] = S[row][lane + 64 * j];
      float m = vv[0];
      #pragma unroll
      for (int j = 1; j < 16; ++j) m = fmaxf(m, vv[j]);
      #pragma unroll
      for (int o = 32; o; o >>= 1) m = fmaxf(m, __shfl_xor(m, o));
      float s = 0.f;
      #pragma unroll
      for (int j = 0; j < 16; ++j) { vv[j] = __expf(vv[j] - m); s += vv[j]; }
      #pragma unroll
      for (int o = 32; o; o >>= 1) s += __shfl_xor(s, o);
      const float inv = 1.0f / s;
      bf16* prow = (bf16*)(&S[row][0]);
      #pragma unroll
      for (int j = 0; j < 16; ++j) prow[lane + 64 * j] = (bf16)(vv[j] * inv);
    }
  }
  __syncthreads();

  { // phase 3: wave w -> d-tile (w&3), k-half (w>>2); dual accumulators
    const int dt = (w & 3) * 16, kh = (w >> 2) * 512;
    f32x4 oa = {0.f, 0.f, 0.f, 0.f}, ob = {0.f, 0.f, 0.f, 0.f};
    const bf16* vb = Vt + ((size_t)(b * 12 + hh) * 64 + dt + l15) * 1024 + kh + lg * 8;
    const bf16* pr = (const bf16*)(&S[l15][0]) + kh + lg * 8;
    #pragma unroll 4
    for (int k0 = 0; k0 < 512; k0 += 64) {
      oa = mfma_bf16(*(const bf16x8*)(pr + k0),      *(const bf16x8*)(vb + k0),      oa);
      ob = mfma_bf16(*(const bf16x8*)(pr + k0 + 32), *(const bf16x8*)(vb + k0 + 32), ob);
    }
    oa += ob;
    if (w >= 4) {
      #pragma unroll
      for (int r = 0; r < 4; ++r) Obuf[lg * 4 + r][dt + l15] = oa[r];
    }
    __syncthreads();
    if (w < 4) {
      #pragma unroll
      for (int r = 0; r < 4; ++r) {
        const float v = oa[r] + Obuf[lg * 4 + r][dt + l15];
        Out[((size_t)(b * 1024 + qt * 16 + lg * 4 + r)) * 768 + hh * 64 + dt + l15] = (bf16)v;
      }
    }
  }
}

// ---------------- launcher ----------------
extern "C" void kernel_launch(void* const* d_in, const int* in_sizes, int n_in,
                              void* d_out, int out_size, void* d_ws, size_t ws_size,
                              hipStream_t stream)
{
  (void)in_sizes; (void)n_in; (void)out_size; (void)ws_size;
  const float* x    = (const float*)d_in[0];
  const float* y    = (const float*)d_in[1];
  const unsigned char* mask = (const unsigned char*)d_in[4];
  const float* sim  = (const float*)d_in[5];
  const float* ln1g = (const float*)d_in[6];
  const float* ln1b = (const float*)d_in[7];
  const float* ln2g = (const float*)d_in[8];
  const float* ln2b = (const float*)d_in[9];
  const float* ln3g = (const float*)d_in[10];
  const float* ln3b = (const float*)d_in[11];
  const float* lnyg = (const float*)d_in[12];
  const float* lnyb = (const float*)d_in[13];
  const float* qkvw = (const float*)d_in[14];
  const float* apw  = (const float*)d_in[15];
  const float* apb  = (const float*)d_in[16];
  const float* pqw  = (const float*)d_in[17];
  const float* pkw  = (const float*)d_in[18];
  const float* pvw  = (const float*)d_in[19];
  const float* cpw  = (const float*)d_in[20];
  const float* cpb  = (const float*)d_in[21];
  const float* f1w  = (const float*)d_in[22];
  const float* f1b  = (const float*)d_in[23];
  const float* f2w  = (const float*)d_in[24];
  const float* f2b  = (const float*)d_in[25];

  char* ws = (char*)d_ws;
  size_t off = 0;
  auto alloc = [&](size_t bytes) -> void* {
    off = (off + 255) & ~(size_t)255;
    void* p = ws + off;
    off += bytes;
    return p;
  };
  const size_t T = 4096;  // B*NQ
  bf16* w_qkv = (bf16*)alloc((size_t)2304 * 768 * 2);
  bf16* w_ap  = (bf16*)alloc((size_t)768 * 768 * 2);
  bf16* w_pq  = (bf16*)alloc((size_t)768 * 768 * 2);
  bf16* w_pkv = (bf16*)alloc((size_t)1536 * 768 * 2);
  bf16* w_cp  = (bf16*)alloc((size_t)768 * 768 * 2);
  bf16* w_f1  = (bf16*)alloc((size_t)3072 * 768 * 2);
  bf16* w_f2  = (bf16*)alloc((size_t)768 * 3072 * 2);
  bf16* xn    = (bf16*)alloc(T * 768 * 2);
  bf16* qkvo  = (bf16*)alloc(T * 2304 * 2);
  bf16* vt    = (bf16*)alloc((size_t)48 * 64 * 1024 * 2);
  bf16* sa    = (bf16*)alloc(T * 768 * 2);
  float* x1   = (float*)alloc(T * 768 * 4);
  bf16* yln   = (bf16*)alloc(T * 768 * 2);
  bf16* xn2   = (bf16*)alloc(T * 768 * 2);
  bf16* cqf   = (bf16*)alloc(T * 768 * 2);
  bf16* ckv   = (bf16*)alloc(T * 1536 * 2);
  bf16* cvtT  = (bf16*)alloc((size_t)48 * 64 * 1024 * 2);
  bf16* biasA = (bf16*)alloc((size_t)4 * 12 * 1024 * 1024 * 2);  // 100.7 MB
  bf16* ca    = (bf16*)alloc(T * 768 * 2);
  float* x2   = (float*)alloc(T * 768 * 4);
  bf16* xn3   = (bf16*)alloc(T * 768 * 2);
  bf16* hbuf  = (bf16*)alloc(T * 3072 * 2);
  int* mshift = (int*)alloc(256);

  detect_mask_k<<<1, 256, 0, stream>>>(mask, mshift);

  { // fused weight conversion (pk,pv land adjacent in w_pkv)
    CvtArgs a;
    const float* srcs[8] = {qkvw, apw, pqw, pkw, pvw, cpw, f1w, f2w};
    bf16* dsts[8] = {w_qkv, w_ap, w_pq, w_pkv, w_pkv + 768 * 768, w_cp, w_f1, w_f2};
    const int n4s[8] = {442368, 147456, 147456, 147456, 147456, 147456, 589824, 589824};
    int cum = 0;
    for (int j = 0; j < 8; ++j) {
      a.src[j] = srcs[j]; a.dst[j] = dsts[j];
      cum += n4s[j]; a.end[j] = cum;
    }
    cvt_all_k<<<cum / 256, 256, 0, stream>>>(a);
  }

  bias_k<<<4096, 256, 0, stream>>>(sim, mask, mshift, biasA);

  // ---- self-attention ----
  ln_k<<<4096, 256, 0, stream>>>(x, ln1g, ln1b, xn);
  gemm_bt<128,128,false,false,false,true><<<dim3(18, 32), 256, 0, stream>>>(
      xn, w_qkv, nullptr, nullptr, qkvo, nullptr, 4096, 2304, 768);
  build_vt<<<dim3(48, 16), 256, 0, stream>>>(qkvo + 1536, 2304, vt);
  attn_k<0><<<3072, 512, 0, stream>>>(
      qkvo, 2304, qkvo + 768, 2304, vt, nullptr, sa);
  gemm_bt<64,128,true,false,true,false><<<dim3(6, 64), 256, 0, stream>>>(
      sa, w_ap, apb, x, nullptr, x1, 4096, 768, 768);

  // ---- cross-attention ----
  ln_k<<<4096, 256, 0, stream>>>(y, lnyg, lnyb, yln);
  ln_k<<<4096, 256, 0, stream>>>(x1, ln2g, ln2b, xn2);
  gemm_bt<64,128,false,false,false,true><<<dim3(6, 64), 256, 0, stream>>>(
      xn2, w_pq, nullptr, nullptr, cqf, nullptr, 4096, 768, 768);
  gemm_bt<128,128,false,false,false,true><<<dim3(12, 32), 256, 0, stream>>>(
      yln, w_pkv, nullptr, nullptr, ckv, nullptr, 4096, 1536, 768);
  build_vt<<<dim3(48, 16), 256, 0, stream>>>(ckv + 768, 1536, cvtT);
  attn_k<1><<<3072, 512, 0, stream>>>(
      cqf, 768, ckv, 1536, cvtT, biasA, ca);
  gemm_bt<64,128,true,false,true,false><<<dim3(6, 64), 256, 0, stream>>>(
      ca, w_cp, cpb, x1, nullptr, x2, 4096, 768, 768);

  // ---- MLP ----
  ln_k<<<4096, 256, 0, stream>>>(x2, ln3g, ln3b, xn3);
  gemm_bt<128,128,true,true,false,true><<<dim3(24, 32), 256, 0, stream>>>(
      xn3, w_f1, f1b, nullptr, hbuf, nullptr, 4096, 3072, 768);
  gemm_bt<64,128,true,false,true,false><<<dim3(6, 64), 256, 0, stream>>>(
      hbuf, w_f2, f2b, x2, nullptr, (float*)d_out, 4096, 768, 3072);

  // ---- y passthrough ----
  copy4_k<<<3072, 256, 0, stream>>>(y, (float*)d_out + 3145728, 786432);
}

// Round 6
// 416.525 us; speedup vs baseline: 1.6085x; 1.3009x over previous
//
#include <hip/hip_runtime.h>
#include <cstdint>
#include <cstddef>

// DinoDecoderBlock on MI355X (gfx950).
// B=4 NQ=NK=1024 C=768 H=12 DH=64, scale=1/8, eps=1e-5.
// R6: flash-style attention (online softmax, LDS-staged K/V via global_load_lds
//     with m201 both-sides XOR swizzle, swapped QK^T so softmax is lane-local,
//     P via per-wave padded LDS). Replaces the latency-serial gather attn.

typedef __bf16 bf16;
typedef __attribute__((ext_vector_type(8))) __bf16 bf16x8;
typedef __attribute__((ext_vector_type(4))) __bf16 bf16x4;
typedef __attribute__((ext_vector_type(4))) float f32x4;

typedef __attribute__((address_space(1))) void gvoid;
typedef __attribute__((address_space(3))) void lvoid;

#define DEVI static __device__ __forceinline__

DEVI void gload16(const void* g, void* l) {
  __builtin_amdgcn_global_load_lds((gvoid*)(uintptr_t)g, (lvoid*)(uintptr_t)l, 16, 0, 0);
}

DEVI f32x4 mfma_bf16(bf16x8 a, bf16x8 b, f32x4 c) {
  return __builtin_amdgcn_mfma_f32_16x16x32_bf16(a, b, c, 0, 0, 0);
}

// ---------------- mask dtype detection ----------------
__global__ __launch_bounds__(256)
void detect_mask_k(const unsigned char* __restrict__ mask, int* __restrict__ shift)
{
  __shared__ int acc[256];
  const int t = threadIdx.x;
  int s = 0;
  for (int i = t; i < 16384; i += 256) {
    const int base = i * 4;
    s += mask[base + 1] + mask[base + 2] + mask[base + 3];
  }
  acc[t] = s;
  __syncthreads();
  #pragma unroll
  for (int o = 128; o; o >>= 1) {
    if (t < o) acc[t] += acc[t + o];
    __syncthreads();
  }
  if (t == 0) *shift = (acc[0] == 0) ? 2 : 0;
}

// ---------------- fused bias precompute, ALL batches ----------------
__global__ __launch_bounds__(256)
void bias_k(const float* __restrict__ sim,
            const unsigned char* __restrict__ mask,
            const int* __restrict__ mshift,
            bf16* __restrict__ biasOut)
{
  const int blk = blockIdx.x;                 // 4096 = b*1024 + q
  const int b = blk >> 10, q = blk & 1023;
  const int t = threadIdx.x;
  const int k4 = t * 4;
  const int msh = *mshift;
  const float* sb = sim + (size_t)b * 12 * 1024 * 1024;
  bf16* ob = biasOut + (size_t)b * 12 * 1024 * 1024;

  f32x4 sv[12];
  f32x4 acc = {0.f, 0.f, 0.f, 0.f};
  #pragma unroll
  for (int h = 0; h < 12; ++h) {
    sv[h] = *(const f32x4*)(sb + ((size_t)h * 1024 + q) * 1024 + k4);
    acc += sv[h];
  }
  const f32x4 mean = acc * (1.0f / 12.0f);

  float mb[4];
  if (msh == 0) {
    const uchar4 mv = *(const uchar4*)(mask + (size_t)q * 1024 + k4);
    mb[0] = mv.x ? 0.f : -1e30f; mb[1] = mv.y ? 0.f : -1e30f;
    mb[2] = mv.z ? 0.f : -1e30f; mb[3] = mv.w ? 0.f : -1e30f;
  } else {
    const int4 mv = *(const int4*)((const int*)mask + (size_t)q * 1024 + k4);
    mb[0] = mv.x ? 0.f : -1e30f; mb[1] = mv.y ? 0.f : -1e30f;
    mb[2] = mv.z ? 0.f : -1e30f; mb[3] = mv.w ? 0.f : -1e30f;
  }

  #pragma unroll
  for (int h = 0; h < 12; ++h) {
    bf16x4 o;
    #pragma unroll
    for (int j = 0; j < 4; ++j)
      o[j] = (bf16)(sv[h][j] - mean[j] + mb[j]);
    *(bf16x4*)(ob + ((size_t)h * 1024 + q) * 1024 + k4) = o;
  }
}

// ---------------- fused fp32 -> bf16 convert for all 8 weights ----------------
struct CvtArgs {
  const float* src[8];
  bf16* dst[8];
  int end[8];
};
__global__ __launch_bounds__(256)
void cvt_all_k(CvtArgs a)
{
  const int i = blockIdx.x * 256 + threadIdx.x;
  int s = 0;
  #pragma unroll
  for (int j = 0; j < 7; ++j) s += (i >= a.end[j]) ? 1 : 0;
  const int base = s ? a.end[s - 1] : 0;
  const int off = i - base;
  const f32x4 v = *((const f32x4*)a.src[s] + off);
  bf16x4 o;
  o[0] = (bf16)v[0]; o[1] = (bf16)v[1]; o[2] = (bf16)v[2]; o[3] = (bf16)v[3];
  *(bf16x4*)(a.dst[s] + (size_t)off * 4) = o;
}

// ---------------- float4 copy ----------------
__global__ __launch_bounds__(256)
void copy4_k(const float* __restrict__ s, float* __restrict__ d, int n4)
{
  const int i = blockIdx.x * 256 + threadIdx.x;
  if (i < n4) ((f32x4*)d)[i] = ((const f32x4*)s)[i];
}

// ---------------- LayerNorm over 768, fp32 in -> bf16 out ----------------
__global__ __launch_bounds__(256)
void ln_k(const float* __restrict__ xin, const float* __restrict__ g,
          const float* __restrict__ be, bf16* __restrict__ out)
{
  const int row = blockIdx.x, tid = threadIdx.x;
  const int lane = tid & 63, w = tid >> 6;
  const float* xr = xin + (size_t)row * 768;
  const float v0 = xr[tid], v1 = xr[tid + 256], v2 = xr[tid + 512];
  float s = v0 + v1 + v2;
  #pragma unroll
  for (int o = 32; o; o >>= 1) s += __shfl_xor(s, o);
  __shared__ float r1[4], r2[4];
  if (lane == 0) r1[w] = s;
  __syncthreads();
  const float mean = (r1[0] + r1[1] + r1[2] + r1[3]) * (1.0f / 768.0f);
  const float d0 = v0 - mean, d1 = v1 - mean, d2 = v2 - mean;
  float q = d0 * d0 + d1 * d1 + d2 * d2;
  #pragma unroll
  for (int o = 32; o; o >>= 1) q += __shfl_xor(q, o);
  if (lane == 0) r2[w] = q;
  __syncthreads();
  const float inv = rsqrtf((r2[0] + r2[1] + r2[2] + r2[3]) * (1.0f / 768.0f) + 1e-5f);
  bf16* orow = out + (size_t)row * 768;
  orow[tid]       = (bf16)(d0 * inv * g[tid]       + be[tid]);
  orow[tid + 256] = (bf16)(d1 * inv * g[tid + 256] + be[tid + 256]);
  orow[tid + 512] = (bf16)(d2 * inv * g[tid + 512] + be[tid + 512]);
}

// ---------------- V transpose ----------------
__global__ __launch_bounds__(256)
void build_vt(const bf16* __restrict__ src, int ld, bf16* __restrict__ vt)
{
  __shared__ unsigned short t[64][72];
  const int bh = blockIdx.x, nt = blockIdx.y;
  const int b = bh / 12, hh = bh % 12;
  const int tid = threadIdx.x;
  {
    const int nl = tid >> 2, d0 = (tid & 3) * 16;
    const unsigned short* srow = (const unsigned short*)src
        + (size_t)(b * 1024 + nt * 64 + nl) * ld + hh * 64 + d0;
    #pragma unroll
    for (int j = 0; j < 4; ++j)
      *(ushort4*)(&t[nl][d0 + j * 4]) = *(const ushort4*)(srow + j * 4);
  }
  __syncthreads();
  {
    const int dl = tid >> 2, n0 = (tid & 3) * 16;
    unsigned short* drow = (unsigned short*)vt + ((size_t)bh * 64 + dl) * 1024 + nt * 64 + n0;
    #pragma unroll
    for (int j = 0; j < 4; ++j) {
      ushort4 o;
      o.x = t[n0 + j * 4 + 0][dl];
      o.y = t[n0 + j * 4 + 1][dl];
      o.z = t[n0 + j * 4 + 2][dl];
      o.w = t[n0 + j * 4 + 3][dl];
      *(ushort4*)(drow + j * 4) = o;
    }
  }
}

// ---------------- GEMM: C[M,N] = A[M,K] * Bt[N,K]^T, tile BM x BN ----------------
template<int BM, int BN, bool BIAS, bool GELU, bool RES, bool OBF>
__global__ __launch_bounds__(256)
void gemm_bt(const bf16* __restrict__ A, const bf16* __restrict__ Bt,
             const float* __restrict__ bias, const float* __restrict__ res,
             bf16* __restrict__ Cb, float* __restrict__ Cf,
             int M, int N, int K)
{
  constexpr int WM = BM / 2, WN = BN / 2;
  constexpr int FM = WM / 16, FN = WN / 16;
  __shared__ bf16 As[BM * 64];
  __shared__ bf16 Bs[BN * 64];
  const int tid = threadIdx.x;
  const int lane = tid & 63;
  const int wv = tid >> 6;
  const int wr = wv >> 1, wc = wv & 1;
  const int l15 = lane & 15, lg = lane >> 4;
  const int bm = blockIdx.y * BM, bn = blockIdx.x * BN;
  (void)M;

  f32x4 acc[FM][FN];
  const f32x4 z = {0.f, 0.f, 0.f, 0.f};
  #pragma unroll
  for (int i = 0; i < FM; ++i)
    #pragma unroll
    for (int j = 0; j < FN; ++j) acc[i][j] = z;

  for (int k0 = 0; k0 < K; k0 += 64) {
    __syncthreads();
    #pragma unroll
    for (int c = tid; c < BM * 8; c += 256) {
      const int row = c >> 3, colb = (c & 7) << 4;
      gload16((const char*)A + ((size_t)(bm + row) * K + k0) * 2 + colb,
              (char*)As + (size_t)c * 16);
    }
    #pragma unroll
    for (int c = tid; c < BN * 8; c += 256) {
      const int row = c >> 3, colb = (c & 7) << 4;
      gload16((const char*)Bt + ((size_t)(bn + row) * K + k0) * 2 + colb,
              (char*)Bs + (size_t)c * 16);
    }
    __syncthreads();
    #pragma unroll
    for (int kk = 0; kk < 64; kk += 32) {
      bf16x8 af[FM], bfr[FN];
      #pragma unroll
      for (int mi = 0; mi < FM; ++mi)
        af[mi] = *(const bf16x8*)(As + (size_t)(wr * WM + mi * 16 + l15) * 64 + kk + lg * 8);
      #pragma unroll
      for (int ni = 0; ni < FN; ++ni)
        bfr[ni] = *(const bf16x8*)(Bs + (size_t)(wc * WN + ni * 16 + l15) * 64 + kk + lg * 8);
      #pragma unroll
      for (int mi = 0; mi < FM; ++mi)
        #pragma unroll
        for (int ni = 0; ni < FN; ++ni)
          acc[mi][ni] = mfma_bf16(af[mi], bfr[ni], acc[mi][ni]);
    }
  }

  #pragma unroll
  for (int mi = 0; mi < FM; ++mi) {
    const int row0 = bm + wr * WM + mi * 16 + lg * 4;
    #pragma unroll
    for (int ni = 0; ni < FN; ++ni) {
      const int col = bn + wc * WN + ni * 16 + l15;
      #pragma unroll
      for (int r = 0; r < 4; ++r) {
        float v = acc[mi][ni][r];
        if constexpr (BIAS) v += bias[col];
        if constexpr (GELU) v = 0.5f * v * (1.0f + erff(v * 0.70710678118654752f));
        if constexpr (RES)  v += res[(size_t)(row0 + r) * N + col];
        if constexpr (OBF)  Cb[(size_t)(row0 + r) * N + col] = (bf16)v;
        else                Cf[(size_t)(row0 + r) * N + col] = v;
      }
    }
  }
}

// ---------------- flash attention: 64 q-rows/block, 4 waves, online softmax ----
// Wave w owns q-rows [qt*64+w*16, +16). Swapped QK^T (mfma(K,Q)) => lane holds
// S^T[k=ni*16+lg*4+r][q=l15]: softmax per q is lane-local + 2 shuffles.
// K/V tiles [64][64] staged via global_load_lds, XOR-swizzled both sides (m201).
// P goes through per-wave padded LDS (stride 72 bf16) to reach A-fragment layout.
// Grid: 768 linear, XCD-clustered: all 16 q-blocks of pair p=(h+12b) on one XCD.
template<int CROSS>
__global__ __launch_bounds__(256, 4)
void fattn_k(const bf16* __restrict__ Qp, int ldq,
             const bf16* __restrict__ Kp, int ldk,
             const bf16* __restrict__ Vt,
             const bf16* __restrict__ bias,   // [4][12][1024][1024] bf16, CROSS only
             bf16* __restrict__ Out)
{
  __shared__ bf16 Kl[64 * 64];        // 8 KB, [krow][c] swizzled
  __shared__ bf16 Vl[64 * 64];        // 8 KB, [d][k]   swizzled
  __shared__ bf16 Bl[4][16 * 72];     // per-wave bias tile, padded
  __shared__ bf16 Pl[4][16 * 72];     // per-wave P tile, padded

  const int f = blockIdx.x;
  const int r8 = f & 7, rest = f >> 3;
  const int c6 = rest % 6, qt = rest / 6;
  const int pp = r8 + 8 * c6;          // 0..47
  const int b = pp / 12, hh = pp % 12;
  const int tid = threadIdx.x, lane = tid & 63, wq = tid >> 6;
  const int l15 = lane & 15, lg = lane >> 4;

  // Q fragment (B-operand): lane holds Q[q=l15][kk*32 + lg*8 ..+7]
  bf16x8 qreg0, qreg1;
  {
    const bf16* qsrc = Qp + (size_t)(b * 1024 + qt * 64 + wq * 16 + l15) * ldq + hh * 64 + lg * 8;
    qreg0 = *(const bf16x8*)qsrc;
    qreg1 = *(const bf16x8*)(qsrc + 32);
  }
  const char* Kbase = (const char*)(Kp + (size_t)b * 1024 * ldk + hh * 64);
  const char* Vbase = (const char*)(Vt + (size_t)(b * 12 + hh) * 64 * 1024);
  const char* Bbase = nullptr;
  if constexpr (CROSS)
    Bbase = (const char*)(bias + (((size_t)(b * 12 + hh)) * 1024 + qt * 64 + wq * 16) * 1024);

  f32x4 oacc[4];
  const f32x4 z = {0.f, 0.f, 0.f, 0.f};
  #pragma unroll
  for (int i = 0; i < 4; ++i) oacc[i] = z;
  float m_run = -1e30f, l_run = 0.f;

  char* BlW = (char*)&Bl[wq][0];
  char* PlW = (char*)&Pl[wq][0];
  const int swz = (l15 & 7) << 4;      // read-side XOR (row&7)<<4

  for (int t = 0; t < 16; ++t) {
    const int k0 = t * 64;
    __syncthreads();   // previous tile's LDS reads complete
    // stage K,V: linear LDS dest, source pre-swizzled (rule #21 / m201)
    #pragma unroll
    for (int j = 0; j < 2; ++j) {
      const int c = j * 256 + tid;                 // 16B chunk id 0..511
      const int r = c >> 3;
      const int sw = ((c & 7) ^ (r & 7)) << 4;     // swizzled byte-col in row
      gload16(Kbase + ((size_t)(k0 + r) * ldk) * 2 + sw, (char*)Kl + (size_t)c * 16);
      gload16(Vbase + (size_t)r * 2048 + (size_t)k0 * 2 + sw, (char*)Vl + (size_t)c * 16);
    }
    if constexpr (CROSS) {  // reg-stage this wave's bias tile [16][64] -> padded LDS
      #pragma unroll
      for (int j = 0; j < 2; ++j) {
        const int c = j * 64 + lane;
        const int r = c >> 3, off = (c & 7) * 16;
        const bf16x8 v = *(const bf16x8*)(Bbase + (size_t)r * 2048 + (size_t)k0 * 2 + off);
        *(bf16x8*)(BlW + r * 144 + off) = v;
      }
    }
    __syncthreads();   // gload_lds drained; K/V valid for all waves

    // ---- S^T = K . Q^T  (A=K, B=Q) ----
    f32x4 sacc[4];
    #pragma unroll
    for (int i = 0; i < 4; ++i) sacc[i] = z;
    #pragma unroll
    for (int ni = 0; ni < 4; ++ni) {
      const int rowb = (ni * 16 + l15) * 128;
      const bf16x8 a0 = *(const bf16x8*)((char*)Kl + rowb + ((lg * 16) ^ swz));
      const bf16x8 a1 = *(const bf16x8*)((char*)Kl + rowb + ((64 + lg * 16) ^ swz));
      sacc[ni] = mfma_bf16(a0, qreg0, sacc[ni]);
      sacc[ni] = mfma_bf16(a1, qreg1, sacc[ni]);
    }

    // ---- online softmax (lane: q=l15 fixed; k = k0 + ni*16 + lg*4 + r) ----
    float sv[16];
    #pragma unroll
    for (int ni = 0; ni < 4; ++ni)
      #pragma unroll
      for (int r = 0; r < 4; ++r)
        sv[ni * 4 + r] = sacc[ni][r] * 0.125f;
    if constexpr (CROSS) {
      #pragma unroll
      for (int ni = 0; ni < 4; ++ni) {
        const bf16x4 bv = *(const bf16x4*)(BlW + l15 * 144 + ni * 32 + lg * 8);
        #pragma unroll
        for (int r = 0; r < 4; ++r)
          sv[ni * 4 + r] += (float)bv[r];
      }
    }
    float mx = sv[0];
    #pragma unroll
    for (int j = 1; j < 16; ++j) mx = fmaxf(mx, sv[j]);
    mx = fmaxf(mx, __shfl_xor(mx, 16));
    mx = fmaxf(mx, __shfl_xor(mx, 32));
    const float mnew = fmaxf(m_run, mx);
    const float corr = __expf(m_run - mnew);
    m_run = mnew;
    float ps = 0.f;
    #pragma unroll
    for (int j = 0; j < 16; ++j) { sv[j] = __expf(sv[j] - mnew); ps += sv[j]; }
    l_run = l_run * corr + ps;

    // ---- P -> per-wave LDS (fragment-layout transpose) ----
    #pragma unroll
    for (int ni = 0; ni < 4; ++ni) {
      bf16x4 pw;
      #pragma unroll
      for (int r = 0; r < 4; ++r) pw[r] = (bf16)sv[ni * 4 + r];
      *(bf16x4*)(PlW + l15 * 144 + ni * 32 + lg * 8) = pw;
    }
    // rescale O by per-row corr (broadcast from lane q=lg*4+r)
    float cr[4];
    #pragma unroll
    for (int r = 0; r < 4; ++r) cr[r] = __shfl(corr, ((lane >> 4) << 2) + r);
    #pragma unroll
    for (int nd = 0; nd < 4; ++nd)
      #pragma unroll
      for (int r = 0; r < 4; ++r) oacc[nd][r] *= cr[r];

    // ---- O += P . V  (A=P, B=V^T) ----
    const bf16x8 p0 = *(const bf16x8*)(PlW + l15 * 144 + lg * 16);
    const bf16x8 p1 = *(const bf16x8*)(PlW + l15 * 144 + 64 + lg * 16);
    #pragma unroll
    for (int nd = 0; nd < 4; ++nd) {
      const int rowb = (nd * 16 + l15) * 128;
      const bf16x8 v0 = *(const bf16x8*)((char*)Vl + rowb + ((lg * 16) ^ swz));
      const bf16x8 v1 = *(const bf16x8*)((char*)Vl + rowb + ((64 + lg * 16) ^ swz));
      oacc[nd] = mfma_bf16(p0, v0, oacc[nd]);
      oacc[nd] = mfma_bf16(p1, v1, oacc[nd]);
    }
  }

  // ---- finalize: divide by row-sum, store ----
  float ls = l_run + __shfl_xor(l_run, 16);
  ls += __shfl_xor(ls, 32);
  const float inv = 1.0f / ls;
  float ivr[4];
  #pragma unroll
  for (int r = 0; r < 4; ++r) ivr[r] = __shfl(inv, ((lane >> 4) << 2) + r);
  bf16* ob = Out + (size_t)(b * 1024 + qt * 64 + wq * 16 + lg * 4) * 768 + hh * 64 + l15;
  #pragma unroll
  for (int r = 0; r < 4; ++r)
    #pragma unroll
    for (int nd = 0; nd < 4; ++nd)
      ob[(size_t)r * 768 + nd * 16] = (bf16)(oacc[nd][r] * ivr[r]);
}

// ---------------- launcher ----------------
extern "C" void kernel_launch(void* const* d_in, const int* in_sizes, int n_in,
                              void* d_out, int out_size, void* d_ws, size_t ws_size,
                              hipStream_t stream)
{
  (void)in_sizes; (void)n_in; (void)out_size; (void)ws_size;
  const float* x    = (const float*)d_in[0];
  const float* y    = (const float*)d_in[1];
  const unsigned char* mask = (const unsigned char*)d_in[4];
  const float* sim  = (const float*)d_in[5];
  const float* ln1g = (const float*)d_in[6];
  const float* ln1b = (const float*)d_in[7];
  const float* ln2g = (const float*)d_in[8];
  const float* ln2b = (const float*)d_in[9];
  const float* ln3g = (const float*)d_in[10];
  const float* ln3b = (const float*)d_in[11];
  const float* lnyg = (const float*)d_in[12];
  const float* lnyb = (const float*)d_in[13];
  const float* qkvw = (const float*)d_in[14];
  const float* apw  = (const float*)d_in[15];
  const float* apb  = (const float*)d_in[16];
  const float* pqw  = (const float*)d_in[17];
  const float* pkw  = (const float*)d_in[18];
  const float* pvw  = (const float*)d_in[19];
  const float* cpw  = (const float*)d_in[20];
  const float* cpb  = (const float*)d_in[21];
  const float* f1w  = (const float*)d_in[22];
  const float* f1b  = (const float*)d_in[23];
  const float* f2w  = (const float*)d_in[24];
  const float* f2b  = (const float*)d_in[25];

  char* ws = (char*)d_ws;
  size_t off = 0;
  auto alloc = [&](size_t bytes) -> void* {
    off = (off + 255) & ~(size_t)255;
    void* p = ws + off;
    off += bytes;
    return p;
  };
  const size_t T = 4096;  // B*NQ
  bf16* w_qkv = (bf16*)alloc((size_t)2304 * 768 * 2);
  bf16* w_ap  = (bf16*)alloc((size_t)768 * 768 * 2);
  bf16* w_pq  = (bf16*)alloc((size_t)768 * 768 * 2);
  bf16* w_pkv = (bf16*)alloc((size_t)1536 * 768 * 2);
  bf16* w_cp  = (bf16*)alloc((size_t)768 * 768 * 2);
  bf16* w_f1  = (bf16*)alloc((size_t)3072 * 768 * 2);
  bf16* w_f2  = (bf16*)alloc((size_t)768 * 3072 * 2);
  bf16* xn    = (bf16*)alloc(T * 768 * 2);
  bf16* qkvo  = (bf16*)alloc(T * 2304 * 2);
  bf16* vt    = (bf16*)alloc((size_t)48 * 64 * 1024 * 2);
  bf16* sa    = (bf16*)alloc(T * 768 * 2);
  float* x1   = (float*)alloc(T * 768 * 4);
  bf16* yln   = (bf16*)alloc(T * 768 * 2);
  bf16* xn2   = (bf16*)alloc(T * 768 * 2);
  bf16* cqf   = (bf16*)alloc(T * 768 * 2);
  bf16* ckv   = (bf16*)alloc(T * 1536 * 2);
  bf16* cvtT  = (bf16*)alloc((size_t)48 * 64 * 1024 * 2);
  bf16* biasA = (bf16*)alloc((size_t)4 * 12 * 1024 * 1024 * 2);  // 100.7 MB
  bf16* ca    = (bf16*)alloc(T * 768 * 2);
  float* x2   = (float*)alloc(T * 768 * 4);
  bf16* xn3   = (bf16*)alloc(T * 768 * 2);
  bf16* hbuf  = (bf16*)alloc(T * 3072 * 2);
  int* mshift = (int*)alloc(256);

  detect_mask_k<<<1, 256, 0, stream>>>(mask, mshift);

  { // fused weight conversion (pk,pv land adjacent in w_pkv)
    CvtArgs a;
    const float* srcs[8] = {qkvw, apw, pqw, pkw, pvw, cpw, f1w, f2w};
    bf16* dsts[8] = {w_qkv, w_ap, w_pq, w_pkv, w_pkv + 768 * 768, w_cp, w_f1, w_f2};
    const int n4s[8] = {442368, 147456, 147456, 147456, 147456, 147456, 589824, 589824};
    int cum = 0;
    for (int j = 0; j < 8; ++j) {
      a.src[j] = srcs[j]; a.dst[j] = dsts[j];
      cum += n4s[j]; a.end[j] = cum;
    }
    cvt_all_k<<<cum / 256, 256, 0, stream>>>(a);
  }

  bias_k<<<4096, 256, 0, stream>>>(sim, mask, mshift, biasA);

  // ---- self-attention ----
  ln_k<<<4096, 256, 0, stream>>>(x, ln1g, ln1b, xn);
  gemm_bt<128,128,false,false,false,true><<<dim3(18, 32), 256, 0, stream>>>(
      xn, w_qkv, nullptr, nullptr, qkvo, nullptr, 4096, 2304, 768);
  build_vt<<<dim3(48, 16), 256, 0, stream>>>(qkvo + 1536, 2304, vt);
  fattn_k<0><<<768, 256, 0, stream>>>(
      qkvo, 2304, qkvo + 768, 2304, vt, nullptr, sa);
  gemm_bt<64,128,true,false,true,false><<<dim3(6, 64), 256, 0, stream>>>(
      sa, w_ap, apb, x, nullptr, x1, 4096, 768, 768);

  // ---- cross-attention ----
  ln_k<<<4096, 256, 0, stream>>>(y, lnyg, lnyb, yln);
  ln_k<<<4096, 256, 0, stream>>>(x1, ln2g, ln2b, xn2);
  gemm_bt<64,128,false,false,false,true><<<dim3(6, 64), 256, 0, stream>>>(
      xn2, w_pq, nullptr, nullptr, cqf, nullptr, 4096, 768, 768);
  gemm_bt<128,128,false,false,false,true><<<dim3(12, 32), 256, 0, stream>>>(
      yln, w_pkv, nullptr, nullptr, ckv, nullptr, 4096, 1536, 768);
  build_vt<<<dim3(48, 16), 256, 0, stream>>>(ckv + 768, 1536, cvtT);
  fattn_k<1><<<768, 256, 0, stream>>>(
      cqf, 768, ckv, 1536, cvtT, biasA, ca);
  gemm_bt<64,128,true,false,true,false><<<dim3(6, 64), 256, 0, stream>>>(
      ca, w_cp, cpb, x1, nullptr, x2, 4096, 768, 768);

  // ---- MLP ----
  ln_k<<<4096, 256, 0, stream>>>(x2, ln3g, ln3b, xn3);
  gemm_bt<128,128,true,true,false,true><<<dim3(24, 32), 256, 0, stream>>>(
      xn3, w_f1, f1b, nullptr, hbuf, nullptr, 4096, 3072, 768);
  gemm_bt<64,128,true,false,true,false><<<dim3(6, 64), 256, 0, stream>>>(
      hbuf, w_f2, f2b, x2, nullptr, (float*)d_out, 4096, 768, 3072);

  // ---- y passthrough ----
  copy4_k<<<3072, 256, 0, stream>>>(y, (float*)d_out + 3145728, 786432);
}

// Round 7
// 412.908 us; speedup vs baseline: 1.6226x; 1.0088x over previous
//
#include <hip/hip_runtime.h>
#include <cstdint>
#include <cstddef>

// DinoDecoderBlock on MI355X (gfx950).
// B=4 NQ=NK=1024 C=768 H=12 DH=64, scale=1/8, eps=1e-5.
// R7: XCD-clustered 1D GEMM grid (A-panel locality per XCD),
//     double-buffered flash-attn (1 barrier/tile, bias via direct reg loads,
//     41 KB LDS -> 3 blocks/CU), merged ln(x)+ln(y) dispatch.

typedef __bf16 bf16;
typedef __attribute__((ext_vector_type(8))) __bf16 bf16x8;
typedef __attribute__((ext_vector_type(4))) __bf16 bf16x4;
typedef __attribute__((ext_vector_type(4))) float f32x4;

typedef __attribute__((address_space(1))) void gvoid;
typedef __attribute__((address_space(3))) void lvoid;

#define DEVI static __device__ __forceinline__

DEVI void gload16(const void* g, void* l) {
  __builtin_amdgcn_global_load_lds((gvoid*)(uintptr_t)g, (lvoid*)(uintptr_t)l, 16, 0, 0);
}

DEVI f32x4 mfma_bf16(bf16x8 a, bf16x8 b, f32x4 c) {
  return __builtin_amdgcn_mfma_f32_16x16x32_bf16(a, b, c, 0, 0, 0);
}

// ---------------- mask dtype detection ----------------
__global__ __launch_bounds__(256)
void detect_mask_k(const unsigned char* __restrict__ mask, int* __restrict__ shift)
{
  __shared__ int acc[256];
  const int t = threadIdx.x;
  int s = 0;
  for (int i = t; i < 16384; i += 256) {
    const int base = i * 4;
    s += mask[base + 1] + mask[base + 2] + mask[base + 3];
  }
  acc[t] = s;
  __syncthreads();
  #pragma unroll
  for (int o = 128; o; o >>= 1) {
    if (t < o) acc[t] += acc[t + o];
    __syncthreads();
  }
  if (t == 0) *shift = (acc[0] == 0) ? 2 : 0;
}

// ---------------- fused bias precompute, ALL batches ----------------
__global__ __launch_bounds__(256)
void bias_k(const float* __restrict__ sim,
            const unsigned char* __restrict__ mask,
            const int* __restrict__ mshift,
            bf16* __restrict__ biasOut)
{
  const int blk = blockIdx.x;                 // 4096 = b*1024 + q
  const int b = blk >> 10, q = blk & 1023;
  const int t = threadIdx.x;
  const int k4 = t * 4;
  const int msh = *mshift;
  const float* sb = sim + (size_t)b * 12 * 1024 * 1024;
  bf16* ob = biasOut + (size_t)b * 12 * 1024 * 1024;

  f32x4 sv[12];
  f32x4 acc = {0.f, 0.f, 0.f, 0.f};
  #pragma unroll
  for (int h = 0; h < 12; ++h) {
    sv[h] = *(const f32x4*)(sb + ((size_t)h * 1024 + q) * 1024 + k4);
    acc += sv[h];
  }
  const f32x4 mean = acc * (1.0f / 12.0f);

  float mb[4];
  if (msh == 0) {
    const uchar4 mv = *(const uchar4*)(mask + (size_t)q * 1024 + k4);
    mb[0] = mv.x ? 0.f : -1e30f; mb[1] = mv.y ? 0.f : -1e30f;
    mb[2] = mv.z ? 0.f : -1e30f; mb[3] = mv.w ? 0.f : -1e30f;
  } else {
    const int4 mv = *(const int4*)((const int*)mask + (size_t)q * 1024 + k4);
    mb[0] = mv.x ? 0.f : -1e30f; mb[1] = mv.y ? 0.f : -1e30f;
    mb[2] = mv.z ? 0.f : -1e30f; mb[3] = mv.w ? 0.f : -1e30f;
  }

  #pragma unroll
  for (int h = 0; h < 12; ++h) {
    bf16x4 o;
    #pragma unroll
    for (int j = 0; j < 4; ++j)
      o[j] = (bf16)(sv[h][j] - mean[j] + mb[j]);
    *(bf16x4*)(ob + ((size_t)h * 1024 + q) * 1024 + k4) = o;
  }
}

// ---------------- fused fp32 -> bf16 convert for all 8 weights ----------------
struct CvtArgs {
  const float* src[8];
  bf16* dst[8];
  int end[8];
};
__global__ __launch_bounds__(256)
void cvt_all_k(CvtArgs a)
{
  const int i = blockIdx.x * 256 + threadIdx.x;
  int s = 0;
  #pragma unroll
  for (int j = 0; j < 7; ++j) s += (i >= a.end[j]) ? 1 : 0;
  const int base = s ? a.end[s - 1] : 0;
  const int off = i - base;
  const f32x4 v = *((const f32x4*)a.src[s] + off);
  bf16x4 o;
  o[0] = (bf16)v[0]; o[1] = (bf16)v[1]; o[2] = (bf16)v[2]; o[3] = (bf16)v[3];
  *(bf16x4*)(a.dst[s] + (size_t)off * 4) = o;
}

// ---------------- float4 copy ----------------
__global__ __launch_bounds__(256)
void copy4_k(const float* __restrict__ s, float* __restrict__ d, int n4)
{
  const int i = blockIdx.x * 256 + threadIdx.x;
  if (i < n4) ((f32x4*)d)[i] = ((const f32x4*)s)[i];
}

// ---------------- LayerNorm over 768, fp32 in -> bf16 out ----------------
// DUAL: blocks [0,4096) process inA (gA/bA -> outA), [4096,8192) inB.
template<bool DUAL>
__global__ __launch_bounds__(256)
void ln_k(const float* __restrict__ inA, const float* __restrict__ gA,
          const float* __restrict__ bA, bf16* __restrict__ outA,
          const float* __restrict__ inB, const float* __restrict__ gB,
          const float* __restrict__ bB, bf16* __restrict__ outB)
{
  int row = blockIdx.x;
  const float* xin = inA; const float* g = gA; const float* be = bA; bf16* out = outA;
  if constexpr (DUAL) {
    if (row >= 4096) {
      row -= 4096; xin = inB; g = gB; be = bB; out = outB;
    }
  }
  const int tid = threadIdx.x;
  const int lane = tid & 63, w = tid >> 6;
  const float* xr = xin + (size_t)row * 768;
  const float v0 = xr[tid], v1 = xr[tid + 256], v2 = xr[tid + 512];
  float s = v0 + v1 + v2;
  #pragma unroll
  for (int o = 32; o; o >>= 1) s += __shfl_xor(s, o);
  __shared__ float r1[4], r2[4];
  if (lane == 0) r1[w] = s;
  __syncthreads();
  const float mean = (r1[0] + r1[1] + r1[2] + r1[3]) * (1.0f / 768.0f);
  const float d0 = v0 - mean, d1 = v1 - mean, d2 = v2 - mean;
  float q = d0 * d0 + d1 * d1 + d2 * d2;
  #pragma unroll
  for (int o = 32; o; o >>= 1) q += __shfl_xor(q, o);
  if (lane == 0) r2[w] = q;
  __syncthreads();
  const float inv = rsqrtf((r2[0] + r2[1] + r2[2] + r2[3]) * (1.0f / 768.0f) + 1e-5f);
  bf16* orow = out + (size_t)row * 768;
  orow[tid]       = (bf16)(d0 * inv * g[tid]       + be[tid]);
  orow[tid + 256] = (bf16)(d1 * inv * g[tid + 256] + be[tid + 256]);
  orow[tid + 512] = (bf16)(d2 * inv * g[tid + 512] + be[tid + 512]);
}

// ---------------- V transpose ----------------
__global__ __launch_bounds__(256)
void build_vt(const bf16* __restrict__ src, int ld, bf16* __restrict__ vt)
{
  __shared__ unsigned short t[64][72];
  const int bh = blockIdx.x, nt = blockIdx.y;
  const int b = bh / 12, hh = bh % 12;
  const int tid = threadIdx.x;
  {
    const int nl = tid >> 2, d0 = (tid & 3) * 16;
    const unsigned short* srow = (const unsigned short*)src
        + (size_t)(b * 1024 + nt * 64 + nl) * ld + hh * 64 + d0;
    #pragma unroll
    for (int j = 0; j < 4; ++j)
      *(ushort4*)(&t[nl][d0 + j * 4]) = *(const ushort4*)(srow + j * 4);
  }
  __syncthreads();
  {
    const int dl = tid >> 2, n0 = (tid & 3) * 16;
    unsigned short* drow = (unsigned short*)vt + ((size_t)bh * 64 + dl) * 1024 + nt * 64 + n0;
    #pragma unroll
    for (int j = 0; j < 4; ++j) {
      ushort4 o;
      o.x = t[n0 + j * 4 + 0][dl];
      o.y = t[n0 + j * 4 + 1][dl];
      o.z = t[n0 + j * 4 + 2][dl];
      o.w = t[n0 + j * 4 + 3][dl];
      *(ushort4*)(drow + j * 4) = o;
    }
  }
}

// ---------------- GEMM: C[M,N] = A[M,K] * Bt[N,K]^T, tile BM x BN ----------------
// 1D grid, XCD-clustered decode: xcd = f&7; all bx of a given by land on one XCD
// (A-panel cached in that XCD's L2; B shared through L3). nyPerXcd = ny/8.
template<int BM, int BN, bool BIAS, bool GELU, bool RES, bool OBF>
__global__ __launch_bounds__(256)
void gemm_bt(const bf16* __restrict__ A, const bf16* __restrict__ Bt,
             const float* __restrict__ bias, const float* __restrict__ res,
             bf16* __restrict__ Cb, float* __restrict__ Cf,
             int nyPerXcd, int N, int K)
{
  constexpr int WM = BM / 2, WN = BN / 2;
  constexpr int FM = WM / 16, FN = WN / 16;
  __shared__ bf16 As[BM * 64];
  __shared__ bf16 Bs[BN * 64];
  const int f = blockIdx.x;
  const int xcd = f & 7, j = f >> 3;
  const int by = xcd + 8 * (j % nyPerXcd);
  const int bx = j / nyPerXcd;
  const int tid = threadIdx.x;
  const int lane = tid & 63;
  const int wv = tid >> 6;
  const int wr = wv >> 1, wc = wv & 1;
  const int l15 = lane & 15, lg = lane >> 4;
  const int bm = by * BM, bn = bx * BN;

  f32x4 acc[FM][FN];
  const f32x4 z = {0.f, 0.f, 0.f, 0.f};
  #pragma unroll
  for (int i = 0; i < FM; ++i)
    #pragma unroll
    for (int jj = 0; jj < FN; ++jj) acc[i][jj] = z;

  for (int k0 = 0; k0 < K; k0 += 64) {
    __syncthreads();
    #pragma unroll
    for (int c = tid; c < BM * 8; c += 256) {
      const int row = c >> 3, colb = (c & 7) << 4;
      gload16((const char*)A + ((size_t)(bm + row) * K + k0) * 2 + colb,
              (char*)As + (size_t)c * 16);
    }
    #pragma unroll
    for (int c = tid; c < BN * 8; c += 256) {
      const int row = c >> 3, colb = (c & 7) << 4;
      gload16((const char*)Bt + ((size_t)(bn + row) * K + k0) * 2 + colb,
              (char*)Bs + (size_t)c * 16);
    }
    __syncthreads();
    #pragma unroll
    for (int kk = 0; kk < 64; kk += 32) {
      bf16x8 af[FM], bfr[FN];
      #pragma unroll
      for (int mi = 0; mi < FM; ++mi)
        af[mi] = *(const bf16x8*)(As + (size_t)(wr * WM + mi * 16 + l15) * 64 + kk + lg * 8);
      #pragma unroll
      for (int ni = 0; ni < FN; ++ni)
        bfr[ni] = *(const bf16x8*)(Bs + (size_t)(wc * WN + ni * 16 + l15) * 64 + kk + lg * 8);
      #pragma unroll
      for (int mi = 0; mi < FM; ++mi)
        #pragma unroll
        for (int ni = 0; ni < FN; ++ni)
          acc[mi][ni] = mfma_bf16(af[mi], bfr[ni], acc[mi][ni]);
    }
  }

  #pragma unroll
  for (int mi = 0; mi < FM; ++mi) {
    const int row0 = bm + wr * WM + mi * 16 + lg * 4;
    #pragma unroll
    for (int ni = 0; ni < FN; ++ni) {
      const int col = bn + wc * WN + ni * 16 + l15;
      #pragma unroll
      for (int r = 0; r < 4; ++r) {
        float v = acc[mi][ni][r];
        if constexpr (BIAS) v += bias[col];
        if constexpr (GELU) v = 0.5f * v * (1.0f + erff(v * 0.70710678118654752f));
        if constexpr (RES)  v += res[(size_t)(row0 + r) * N + col];
        if constexpr (OBF)  Cb[(size_t)(row0 + r) * N + col] = (bf16)v;
        else                Cf[(size_t)(row0 + r) * N + col] = v;
      }
    }
  }
}

// ---------------- flash attention: 64 q-rows/block, 4 waves, online softmax ----
// Double-buffered K/V (one barrier per tile; stage t+1 issued before compute t).
// Swapped QK^T (mfma(K,Q)) => lane holds S^T[k][q=l15]; softmax lane-local + 2 shuffles.
// Bias consumed via direct per-lane 8B global loads (matches S^T fragment layout).
// 41 KB LDS -> 3 blocks/CU. Grid 768 XCD-clustered by pair p=(h+12b).
template<int CROSS>
__global__ __launch_bounds__(256, 3)
void fattn_k(const bf16* __restrict__ Qp, int ldq,
             const bf16* __restrict__ Kp, int ldk,
             const bf16* __restrict__ Vt,
             const bf16* __restrict__ bias,   // [4][12][1024][1024] bf16, CROSS only
             bf16* __restrict__ Out)
{
  __shared__ bf16 Kl[2][64 * 64];     // 16 KB, [krow][c] swizzled
  __shared__ bf16 Vl[2][64 * 64];     // 16 KB, [d][k]   swizzled
  __shared__ bf16 Pl[4][16 * 72];     // per-wave P tile, padded

  const int f = blockIdx.x;
  const int r8 = f & 7, rest = f >> 3;
  const int c6 = rest % 6, qt = rest / 6;
  const int pp = r8 + 8 * c6;          // 0..47
  const int b = pp / 12, hh = pp % 12;
  const int tid = threadIdx.x, lane = tid & 63, wq = tid >> 6;
  const int l15 = lane & 15, lg = lane >> 4;

  // Q fragment (B-operand): lane holds Q[q=l15][kk*32 + lg*8 ..+7]
  bf16x8 qreg0, qreg1;
  {
    const bf16* qsrc = Qp + (size_t)(b * 1024 + qt * 64 + wq * 16 + l15) * ldq + hh * 64 + lg * 8;
    qreg0 = *(const bf16x8*)qsrc;
    qreg1 = *(const bf16x8*)(qsrc + 32);
  }
  const char* Kbase = (const char*)(Kp + (size_t)b * 1024 * ldk + hh * 64);
  const char* Vbase = (const char*)(Vt + (size_t)(b * 12 + hh) * 64 * 1024);
  const bf16* biasRow = nullptr;
  if constexpr (CROSS)
    biasRow = bias + (((size_t)(b * 12 + hh)) * 1024 + qt * 64 + wq * 16 + l15) * 1024;

  f32x4 oacc[4];
  const f32x4 z = {0.f, 0.f, 0.f, 0.f};
  #pragma unroll
  for (int i = 0; i < 4; ++i) oacc[i] = z;
  float m_run = -1e30f, l_run = 0.f;

  char* PlW = (char*)&Pl[wq][0];
  const int swz = (l15 & 7) << 4;      // read-side XOR (row&7)<<4

  auto stage = [&](int buf, int t) {
    const int k0 = t * 64;
    #pragma unroll
    for (int jj = 0; jj < 2; ++jj) {
      const int c = jj * 256 + tid;                // 16B chunk id 0..511
      const int r = c >> 3;
      const int sw = ((c & 7) ^ (r & 7)) << 4;     // swizzled byte-col in row
      gload16(Kbase + ((size_t)(k0 + r) * ldk) * 2 + sw, (char*)&Kl[buf][0] + (size_t)c * 16);
      gload16(Vbase + (size_t)r * 2048 + (size_t)k0 * 2 + sw, (char*)&Vl[buf][0] + (size_t)c * 16);
    }
  };

  stage(0, 0);
  __syncthreads();   // prologue staging drained

  for (int t = 0; t < 16; ++t) {
    const int cur = t & 1;
    const int k0 = t * 64;
    if (t < 15) stage(cur ^ 1, t + 1);   // async prefetch; drained at loop-end barrier

    bf16x4 bv[4];
    if constexpr (CROSS) {
      const bf16* bp = biasRow + k0 + lg * 4;
      #pragma unroll
      for (int ni = 0; ni < 4; ++ni) bv[ni] = *(const bf16x4*)(bp + ni * 16);
    }

    // ---- S^T = K . Q^T  (A=K, B=Q) ----
    f32x4 sacc[4];
    #pragma unroll
    for (int i = 0; i < 4; ++i) sacc[i] = z;
    #pragma unroll
    for (int ni = 0; ni < 4; ++ni) {
      const int rowb = (ni * 16 + l15) * 128;
      const bf16x8 a0 = *(const bf16x8*)((char*)&Kl[cur][0] + rowb + ((lg * 16) ^ swz));
      const bf16x8 a1 = *(const bf16x8*)((char*)&Kl[cur][0] + rowb + ((64 + lg * 16) ^ swz));
      sacc[ni] = mfma_bf16(a0, qreg0, sacc[ni]);
      sacc[ni] = mfma_bf16(a1, qreg1, sacc[ni]);
    }

    // ---- online softmax (lane: q=l15 fixed; k = k0 + ni*16 + lg*4 + r) ----
    float sv[16];
    #pragma unroll
    for (int ni = 0; ni < 4; ++ni)
      #pragma unroll
      for (int r = 0; r < 4; ++r)
        sv[ni * 4 + r] = sacc[ni][r] * 0.125f;
    if constexpr (CROSS) {
      #pragma unroll
      for (int ni = 0; ni < 4; ++ni)
        #pragma unroll
        for (int r = 0; r < 4; ++r)
          sv[ni * 4 + r] += (float)bv[ni][r];
    }
    float mx = sv[0];
    #pragma unroll
    for (int jj = 1; jj < 16; ++jj) mx = fmaxf(mx, sv[jj]);
    mx = fmaxf(mx, __shfl_xor(mx, 16));
    mx = fmaxf(mx, __shfl_xor(mx, 32));
    const float mnew = fmaxf(m_run, mx);
    const float corr = __expf(m_run - mnew);
    m_run = mnew;
    float ps = 0.f;
    #pragma unroll
    for (int jj = 0; jj < 16; ++jj) { sv[jj] = __expf(sv[jj] - mnew); ps += sv[jj]; }
    l_run = l_run * corr + ps;

    // ---- P -> per-wave LDS (fragment-layout transpose) ----
    #pragma unroll
    for (int ni = 0; ni < 4; ++ni) {
      bf16x4 pw;
      #pragma unroll
      for (int r = 0; r < 4; ++r) pw[r] = (bf16)sv[ni * 4 + r];
      *(bf16x4*)(PlW + l15 * 144 + ni * 32 + lg * 8) = pw;
    }
    // rescale O by per-row corr (broadcast from lane q=lg*4+r)
    float cr[4];
    #pragma unroll
    for (int r = 0; r < 4; ++r) cr[r] = __shfl(corr, ((lane >> 4) << 2) + r);
    #pragma unroll
    for (int nd = 0; nd < 4; ++nd)
      #pragma unroll
      for (int r = 0; r < 4; ++r) oacc[nd][r] *= cr[r];

    // ---- O += P . V  (A=P, B=V^T) ----
    const bf16x8 p0 = *(const bf16x8*)(PlW + l15 * 144 + lg * 16);
    const bf16x8 p1 = *(const bf16x8*)(PlW + l15 * 144 + 64 + lg * 16);
    #pragma unroll
    for (int nd = 0; nd < 4; ++nd) {
      const int rowb = (nd * 16 + l15) * 128;
      const bf16x8 v0 = *(const bf16x8*)((char*)&Vl[cur][0] + rowb + ((lg * 16) ^ swz));
      const bf16x8 v1 = *(const bf16x8*)((char*)&Vl[cur][0] + rowb + ((64 + lg * 16) ^ swz));
      oacc[nd] = mfma_bf16(p0, v0, oacc[nd]);
      oacc[nd] = mfma_bf16(p1, v1, oacc[nd]);
    }
    __syncthreads();   // staging t+1 complete; all waves done with buf cur
  }

  // ---- finalize: divide by row-sum, store ----
  float ls = l_run + __shfl_xor(l_run, 16);
  ls += __shfl_xor(ls, 32);
  const float inv = 1.0f / ls;
  float ivr[4];
  #pragma unroll
  for (int r = 0; r < 4; ++r) ivr[r] = __shfl(inv, ((lane >> 4) << 2) + r);
  bf16* ob = Out + (size_t)(b * 1024 + qt * 64 + wq * 16 + lg * 4) * 768 + hh * 64 + l15;
  #pragma unroll
  for (int r = 0; r < 4; ++r)
    #pragma unroll
    for (int nd = 0; nd < 4; ++nd)
      ob[(size_t)r * 768 + nd * 16] = (bf16)(oacc[nd][r] * ivr[r]);
}

// ---------------- launcher ----------------
extern "C" void kernel_launch(void* const* d_in, const int* in_sizes, int n_in,
                              void* d_out, int out_size, void* d_ws, size_t ws_size,
                              hipStream_t stream)
{
  (void)in_sizes; (void)n_in; (void)out_size; (void)ws_size;
  const float* x    = (const float*)d_in[0];
  const float* y    = (const float*)d_in[1];
  const unsigned char* mask = (const unsigned char*)d_in[4];
  const float* sim  = (const float*)d_in[5];
  const float* ln1g = (const float*)d_in[6];
  const float* ln1b = (const float*)d_in[7];
  const float* ln2g = (const float*)d_in[8];
  const float* ln2b = (const float*)d_in[9];
  const float* ln3g = (const float*)d_in[10];
  const float* ln3b = (const float*)d_in[11];
  const float* lnyg = (const float*)d_in[12];
  const float* lnyb = (const float*)d_in[13];
  const float* qkvw = (const float*)d_in[14];
  const float* apw  = (const float*)d_in[15];
  const float* apb  = (const float*)d_in[16];
  const float* pqw  = (const float*)d_in[17];
  const float* pkw  = (const float*)d_in[18];
  const float* pvw  = (const float*)d_in[19];
  const float* cpw  = (const float*)d_in[20];
  const float* cpb  = (const float*)d_in[21];
  const float* f1w  = (const float*)d_in[22];
  const float* f1b  = (const float*)d_in[23];
  const float* f2w  = (const float*)d_in[24];
  const float* f2b  = (const float*)d_in[25];

  char* ws = (char*)d_ws;
  size_t off = 0;
  auto alloc = [&](size_t bytes) -> void* {
    off = (off + 255) & ~(size_t)255;
    void* p = ws + off;
    off += bytes;
    return p;
  };
  const size_t T = 4096;  // B*NQ
  bf16* w_qkv = (bf16*)alloc((size_t)2304 * 768 * 2);
  bf16* w_ap  = (bf16*)alloc((size_t)768 * 768 * 2);
  bf16* w_pq  = (bf16*)alloc((size_t)768 * 768 * 2);
  bf16* w_pkv = (bf16*)alloc((size_t)1536 * 768 * 2);
  bf16* w_cp  = (bf16*)alloc((size_t)768 * 768 * 2);
  bf16* w_f1  = (bf16*)alloc((size_t)3072 * 768 * 2);
  bf16* w_f2  = (bf16*)alloc((size_t)768 * 3072 * 2);
  bf16* xn    = (bf16*)alloc(T * 768 * 2);
  bf16* qkvo  = (bf16*)alloc(T * 2304 * 2);
  bf16* vt    = (bf16*)alloc((size_t)48 * 64 * 1024 * 2);
  bf16* sa    = (bf16*)alloc(T * 768 * 2);
  float* x1   = (float*)alloc(T * 768 * 4);
  bf16* yln   = (bf16*)alloc(T * 768 * 2);
  bf16* xn2   = (bf16*)alloc(T * 768 * 2);
  bf16* cqf   = (bf16*)alloc(T * 768 * 2);
  bf16* ckv   = (bf16*)alloc(T * 1536 * 2);
  bf16* cvtT  = (bf16*)alloc((size_t)48 * 64 * 1024 * 2);
  bf16* biasA = (bf16*)alloc((size_t)4 * 12 * 1024 * 1024 * 2);  // 100.7 MB
  bf16* ca    = (bf16*)alloc(T * 768 * 2);
  float* x2   = (float*)alloc(T * 768 * 4);
  bf16* xn3   = (bf16*)alloc(T * 768 * 2);
  bf16* hbuf  = (bf16*)alloc(T * 3072 * 2);
  int* mshift = (int*)alloc(256);

  detect_mask_k<<<1, 256, 0, stream>>>(mask, mshift);

  { // fused weight conversion (pk,pv land adjacent in w_pkv)
    CvtArgs a;
    const float* srcs[8] = {qkvw, apw, pqw, pkw, pvw, cpw, f1w, f2w};
    bf16* dsts[8] = {w_qkv, w_ap, w_pq, w_pkv, w_pkv + 768 * 768, w_cp, w_f1, w_f2};
    const int n4s[8] = {442368, 147456, 147456, 147456, 147456, 147456, 589824, 589824};
    int cum = 0;
    for (int j = 0; j < 8; ++j) {
      a.src[j] = srcs[j]; a.dst[j] = dsts[j];
      cum += n4s[j]; a.end[j] = cum;
    }
    cvt_all_k<<<cum / 256, 256, 0, stream>>>(a);
  }

  bias_k<<<4096, 256, 0, stream>>>(sim, mask, mshift, biasA);

  // ---- self-attention ----
  ln_k<true><<<8192, 256, 0, stream>>>(x, ln1g, ln1b, xn, y, lnyg, lnyb, yln);
  gemm_bt<128,128,false,false,false,true><<<576, 256, 0, stream>>>(
      xn, w_qkv, nullptr, nullptr, qkvo, nullptr, 4, 2304, 768);
  build_vt<<<dim3(48, 16), 256, 0, stream>>>(qkvo + 1536, 2304, vt);
  fattn_k<0><<<768, 256, 0, stream>>>(
      qkvo, 2304, qkvo + 768, 2304, vt, nullptr, sa);
  gemm_bt<64,128,true,false,true,false><<<384, 256, 0, stream>>>(
      sa, w_ap, apb, x, nullptr, x1, 8, 768, 768);

  // ---- cross-attention ----
  ln_k<false><<<4096, 256, 0, stream>>>(x1, ln2g, ln2b, xn2,
                                        nullptr, nullptr, nullptr, nullptr);
  gemm_bt<64,128,false,false,false,true><<<384, 256, 0, stream>>>(
      xn2, w_pq, nullptr, nullptr, cqf, nullptr, 8, 768, 768);
  gemm_bt<128,128,false,false,false,true><<<384, 256, 0, stream>>>(
      yln, w_pkv, nullptr, nullptr, ckv, nullptr, 4, 1536, 768);
  build_vt<<<dim3(48, 16), 256, 0, stream>>>(ckv + 768, 1536, cvtT);
  fattn_k<1><<<768, 256, 0, stream>>>(
      cqf, 768, ckv, 1536, cvtT, biasA, ca);
  gemm_bt<64,128,true,false,true,false><<<384, 256, 0, stream>>>(
      ca, w_cp, cpb, x1, nullptr, x2, 8, 768, 768);

  // ---- MLP ----
  ln_k<false><<<4096, 256, 0, stream>>>(x2, ln3g, ln3b, xn3,
                                        nullptr, nullptr, nullptr, nullptr);
  gemm_bt<128,128,true,true,false,true><<<768, 256, 0, stream>>>(
      xn3, w_f1, f1b, nullptr, hbuf, nullptr, 4, 3072, 768);
  gemm_bt<64,128,true,false,true,false><<<384, 256, 0, stream>>>(
      hbuf, w_f2, f2b, x2, nullptr, (float*)d_out, 8, 768, 3072);

  // ---- y passthrough ----
  copy4_k<<<3072, 256, 0, stream>>>(y, (float*)d_out + 3145728, 786432);
}

// Round 8
// 388.566 us; speedup vs baseline: 1.7242x; 1.0626x over previous
//
#include <hip/hip_runtime.h>
#include <cstdint>
#include <cstddef>

// DinoDecoderBlock on MI355X (gfx950).
// B=4 NQ=NK=1024 C=768 H=12 DH=64, scale=1/8, eps=1e-5.
// R8: V-transpose fused into qkv/pkv GEMM epilogues (build_vt deleted),
//     mask-dtype detection inlined into bias_k (detect_mask deleted).

typedef __bf16 bf16;
typedef __attribute__((ext_vector_type(8))) __bf16 bf16x8;
typedef __attribute__((ext_vector_type(4))) __bf16 bf16x4;
typedef __attribute__((ext_vector_type(4))) float f32x4;

typedef __attribute__((address_space(1))) void gvoid;
typedef __attribute__((address_space(3))) void lvoid;

#define DEVI static __device__ __forceinline__

DEVI void gload16(const void* g, void* l) {
  __builtin_amdgcn_global_load_lds((gvoid*)(uintptr_t)g, (lvoid*)(uintptr_t)l, 16, 0, 0);
}

DEVI f32x4 mfma_bf16(bf16x8 a, bf16x8 b, f32x4 c) {
  return __builtin_amdgcn_mfma_f32_16x16x32_bf16(a, b, c, 0, 0, 0);
}

// ---------------- fused bias precompute, ALL batches ----------------
// biasOut[b][h][q][k] = sim[b,h,q,k] - mean_h + (mask[q,k]?0:-1e30)
// Mask dtype (byte-bool vs int32) detected per-block from a 3KB window.
__global__ __launch_bounds__(256)
void bias_k(const float* __restrict__ sim,
            const unsigned char* __restrict__ mask,
            bf16* __restrict__ biasOut)
{
  __shared__ int red[4];
  const int blk = blockIdx.x;                 // 4096 = b*1024 + q
  const int b = blk >> 10, q = blk & 1023;
  const int t = threadIdx.x;
  const int k4 = t * 4;

  // inline mask dtype detection: for int32 0/1 data, bytes at idx%4!=0 are 0
  int ds = mask[t * 4 + 1] + mask[t * 4 + 2] + mask[t * 4 + 3];
  #pragma unroll
  for (int o = 32; o; o >>= 1) ds += __shfl_xor(ds, o);
  if ((t & 63) == 0) red[t >> 6] = ds;
  __syncthreads();
  const int msh = ((red[0] + red[1] + red[2] + red[3]) == 0) ? 2 : 0;

  const float* sb = sim + (size_t)b * 12 * 1024 * 1024;
  bf16* ob = biasOut + (size_t)b * 12 * 1024 * 1024;

  f32x4 sv[12];
  f32x4 acc = {0.f, 0.f, 0.f, 0.f};
  #pragma unroll
  for (int h = 0; h < 12; ++h) {
    sv[h] = *(const f32x4*)(sb + ((size_t)h * 1024 + q) * 1024 + k4);
    acc += sv[h];
  }
  const f32x4 mean = acc * (1.0f / 12.0f);

  float mb[4];
  if (msh == 0) {
    const uchar4 mv = *(const uchar4*)(mask + (size_t)q * 1024 + k4);
    mb[0] = mv.x ? 0.f : -1e30f; mb[1] = mv.y ? 0.f : -1e30f;
    mb[2] = mv.z ? 0.f : -1e30f; mb[3] = mv.w ? 0.f : -1e30f;
  } else {
    const int4 mv = *(const int4*)((const int*)mask + (size_t)q * 1024 + k4);
    mb[0] = mv.x ? 0.f : -1e30f; mb[1] = mv.y ? 0.f : -1e30f;
    mb[2] = mv.z ? 0.f : -1e30f; mb[3] = mv.w ? 0.f : -1e30f;
  }

  #pragma unroll
  for (int h = 0; h < 12; ++h) {
    bf16x4 o;
    #pragma unroll
    for (int j = 0; j < 4; ++j)
      o[j] = (bf16)(sv[h][j] - mean[j] + mb[j]);
    *(bf16x4*)(ob + ((size_t)h * 1024 + q) * 1024 + k4) = o;
  }
}

// ---------------- fused fp32 -> bf16 convert for all 8 weights ----------------
struct CvtArgs {
  const float* src[8];
  bf16* dst[8];
  int end[8];
};
__global__ __launch_bounds__(256)
void cvt_all_k(CvtArgs a)
{
  const int i = blockIdx.x * 256 + threadIdx.x;
  int s = 0;
  #pragma unroll
  for (int j = 0; j < 7; ++j) s += (i >= a.end[j]) ? 1 : 0;
  const int base = s ? a.end[s - 1] : 0;
  const int off = i - base;
  const f32x4 v = *((const f32x4*)a.src[s] + off);
  bf16x4 o;
  o[0] = (bf16)v[0]; o[1] = (bf16)v[1]; o[2] = (bf16)v[2]; o[3] = (bf16)v[3];
  *(bf16x4*)(a.dst[s] + (size_t)off * 4) = o;
}

// ---------------- float4 copy ----------------
__global__ __launch_bounds__(256)
void copy4_k(const float* __restrict__ s, float* __restrict__ d, int n4)
{
  const int i = blockIdx.x * 256 + threadIdx.x;
  if (i < n4) ((f32x4*)d)[i] = ((const f32x4*)s)[i];
}

// ---------------- LayerNorm over 768, fp32 in -> bf16 out ----------------
template<bool DUAL>
__global__ __launch_bounds__(256)
void ln_k(const float* __restrict__ inA, const float* __restrict__ gA,
          const float* __restrict__ bA, bf16* __restrict__ outA,
          const float* __restrict__ inB, const float* __restrict__ gB,
          const float* __restrict__ bB, bf16* __restrict__ outB)
{
  int row = blockIdx.x;
  const float* xin = inA; const float* g = gA; const float* be = bA; bf16* out = outA;
  if constexpr (DUAL) {
    if (row >= 4096) {
      row -= 4096; xin = inB; g = gB; be = bB; out = outB;
    }
  }
  const int tid = threadIdx.x;
  const int lane = tid & 63, w = tid >> 6;
  const float* xr = xin + (size_t)row * 768;
  const float v0 = xr[tid], v1 = xr[tid + 256], v2 = xr[tid + 512];
  float s = v0 + v1 + v2;
  #pragma unroll
  for (int o = 32; o; o >>= 1) s += __shfl_xor(s, o);
  __shared__ float r1[4], r2[4];
  if (lane == 0) r1[w] = s;
  __syncthreads();
  const float mean = (r1[0] + r1[1] + r1[2] + r1[3]) * (1.0f / 768.0f);
  const float d0 = v0 - mean, d1 = v1 - mean, d2 = v2 - mean;
  float q = d0 * d0 + d1 * d1 + d2 * d2;
  #pragma unroll
  for (int o = 32; o; o >>= 1) q += __shfl_xor(q, o);
  if (lane == 0) r2[w] = q;
  __syncthreads();
  const float inv = rsqrtf((r2[0] + r2[1] + r2[2] + r2[3]) * (1.0f / 768.0f) + 1e-5f);
  bf16* orow = out + (size_t)row * 768;
  orow[tid]       = (bf16)(d0 * inv * g[tid]       + be[tid]);
  orow[tid + 256] = (bf16)(d1 * inv * g[tid + 256] + be[tid + 256]);
  orow[tid + 512] = (bf16)(d2 * inv * g[tid + 512] + be[tid + 512]);
}

// ---------------- GEMM: C[M,N] = A[M,K] * Bt[N,K]^T, tile BM x BN ----------------
// 1D grid, XCD-clustered decode (nyPerXcd = ny/8).
// VT: cols >= vtBase are attention-V channels, written transposed to
//     vtOut[(b*768 + (col-vtBase))*1024 + n] (4 consecutive n -> 8B stores).
template<int BM, int BN, bool BIAS, bool GELU, bool RES, bool OBF, bool VT>
__global__ __launch_bounds__(256)
void gemm_bt(const bf16* __restrict__ A, const bf16* __restrict__ Bt,
             const float* __restrict__ bias, const float* __restrict__ res,
             bf16* __restrict__ Cb, float* __restrict__ Cf,
             bf16* __restrict__ vtOut, int vtBase,
             int nyPerXcd, int N, int K)
{
  constexpr int WM = BM / 2, WN = BN / 2;
  constexpr int FM = WM / 16, FN = WN / 16;
  __shared__ bf16 As[BM * 64];
  __shared__ bf16 Bs[BN * 64];
  const int f = blockIdx.x;
  const int xcd = f & 7, j = f >> 3;
  const int by = xcd + 8 * (j % nyPerXcd);
  const int bx = j / nyPerXcd;
  const int tid = threadIdx.x;
  const int lane = tid & 63;
  const int wv = tid >> 6;
  const int wr = wv >> 1, wc = wv & 1;
  const int l15 = lane & 15, lg = lane >> 4;
  const int bm = by * BM, bn = bx * BN;

  f32x4 acc[FM][FN];
  const f32x4 z = {0.f, 0.f, 0.f, 0.f};
  #pragma unroll
  for (int i = 0; i < FM; ++i)
    #pragma unroll
    for (int jj = 0; jj < FN; ++jj) acc[i][jj] = z;

  for (int k0 = 0; k0 < K; k0 += 64) {
    __syncthreads();
    #pragma unroll
    for (int c = tid; c < BM * 8; c += 256) {
      const int row = c >> 3, colb = (c & 7) << 4;
      gload16((const char*)A + ((size_t)(bm + row) * K + k0) * 2 + colb,
              (char*)As + (size_t)c * 16);
    }
    #pragma unroll
    for (int c = tid; c < BN * 8; c += 256) {
      const int row = c >> 3, colb = (c & 7) << 4;
      gload16((const char*)Bt + ((size_t)(bn + row) * K + k0) * 2 + colb,
              (char*)Bs + (size_t)c * 16);
    }
    __syncthreads();
    #pragma unroll
    for (int kk = 0; kk < 64; kk += 32) {
      bf16x8 af[FM], bfr[FN];
      #pragma unroll
      for (int mi = 0; mi < FM; ++mi)
        af[mi] = *(const bf16x8*)(As + (size_t)(wr * WM + mi * 16 + l15) * 64 + kk + lg * 8);
      #pragma unroll
      for (int ni = 0; ni < FN; ++ni)
        bfr[ni] = *(const bf16x8*)(Bs + (size_t)(wc * WN + ni * 16 + l15) * 64 + kk + lg * 8);
      #pragma unroll
      for (int mi = 0; mi < FM; ++mi)
        #pragma unroll
        for (int ni = 0; ni < FN; ++ni)
          acc[mi][ni] = mfma_bf16(af[mi], bfr[ni], acc[mi][ni]);
    }
  }

  #pragma unroll
  for (int mi = 0; mi < FM; ++mi) {
    const int row0 = bm + wr * WM + mi * 16 + lg * 4;
    #pragma unroll
    for (int ni = 0; ni < FN; ++ni) {
      const int col = bn + wc * WN + ni * 16 + l15;
      if constexpr (VT) {
        if (col >= vtBase) {   // V channel: store transposed, 4 consecutive n
          const int hd = col - vtBase;            // h*64+d
          const int bb = row0 >> 10, n0 = row0 & 1023;
          bf16x4 ov;
          #pragma unroll
          for (int r = 0; r < 4; ++r) ov[r] = (bf16)acc[mi][ni][r];
          *(bf16x4*)(vtOut + ((size_t)(bb * 768 + hd)) * 1024 + n0) = ov;
          continue;
        }
      }
      #pragma unroll
      for (int r = 0; r < 4; ++r) {
        float v = acc[mi][ni][r];
        if constexpr (BIAS) v += bias[col];
        if constexpr (GELU) v = 0.5f * v * (1.0f + erff(v * 0.70710678118654752f));
        if constexpr (RES)  v += res[(size_t)(row0 + r) * N + col];
        if constexpr (OBF)  Cb[(size_t)(row0 + r) * N + col] = (bf16)v;
        else                Cf[(size_t)(row0 + r) * N + col] = v;
      }
    }
  }
}

// ---------------- flash attention: 64 q-rows/block, 4 waves, online softmax ----
template<int CROSS>
__global__ __launch_bounds__(256, 3)
void fattn_k(const bf16* __restrict__ Qp, int ldq,
             const bf16* __restrict__ Kp, int ldk,
             const bf16* __restrict__ Vt,
             const bf16* __restrict__ bias,   // [4][12][1024][1024] bf16, CROSS only
             bf16* __restrict__ Out)
{
  __shared__ bf16 Kl[2][64 * 64];     // 16 KB, [krow][c] swizzled
  __shared__ bf16 Vl[2][64 * 64];     // 16 KB, [d][k]   swizzled
  __shared__ bf16 Pl[4][16 * 72];     // per-wave P tile, padded

  const int f = blockIdx.x;
  const int r8 = f & 7, rest = f >> 3;
  const int c6 = rest % 6, qt = rest / 6;
  const int pp = r8 + 8 * c6;          // 0..47
  const int b = pp / 12, hh = pp % 12;
  const int tid = threadIdx.x, lane = tid & 63, wq = tid >> 6;
  const int l15 = lane & 15, lg = lane >> 4;

  bf16x8 qreg0, qreg1;
  {
    const bf16* qsrc = Qp + (size_t)(b * 1024 + qt * 64 + wq * 16 + l15) * ldq + hh * 64 + lg * 8;
    qreg0 = *(const bf16x8*)qsrc;
    qreg1 = *(const bf16x8*)(qsrc + 32);
  }
  const char* Kbase = (const char*)(Kp + (size_t)b * 1024 * ldk + hh * 64);
  const char* Vbase = (const char*)(Vt + (size_t)(b * 12 + hh) * 64 * 1024);
  const bf16* biasRow = nullptr;
  if constexpr (CROSS)
    biasRow = bias + (((size_t)(b * 12 + hh)) * 1024 + qt * 64 + wq * 16 + l15) * 1024;

  f32x4 oacc[4];
  const f32x4 z = {0.f, 0.f, 0.f, 0.f};
  #pragma unroll
  for (int i = 0; i < 4; ++i) oacc[i] = z;
  float m_run = -1e30f, l_run = 0.f;

  char* PlW = (char*)&Pl[wq][0];
  const int swz = (l15 & 7) << 4;      // read-side XOR (row&7)<<4

  auto stage = [&](int buf, int t) {
    const int k0 = t * 64;
    #pragma unroll
    for (int jj = 0; jj < 2; ++jj) {
      const int c = jj * 256 + tid;                // 16B chunk id 0..511
      const int r = c >> 3;
      const int sw = ((c & 7) ^ (r & 7)) << 4;     // swizzled byte-col in row
      gload16(Kbase + ((size_t)(k0 + r) * ldk) * 2 + sw, (char*)&Kl[buf][0] + (size_t)c * 16);
      gload16(Vbase + (size_t)r * 2048 + (size_t)k0 * 2 + sw, (char*)&Vl[buf][0] + (size_t)c * 16);
    }
  };

  stage(0, 0);
  __syncthreads();   // prologue staging drained

  for (int t = 0; t < 16; ++t) {
    const int cur = t & 1;
    const int k0 = t * 64;
    if (t < 15) stage(cur ^ 1, t + 1);   // async prefetch; drained at loop-end barrier

    bf16x4 bv[4];
    if constexpr (CROSS) {
      const bf16* bp = biasRow + k0 + lg * 4;
      #pragma unroll
      for (int ni = 0; ni < 4; ++ni) bv[ni] = *(const bf16x4*)(bp + ni * 16);
    }

    // ---- S^T = K . Q^T ----
    f32x4 sacc[4];
    #pragma unroll
    for (int i = 0; i < 4; ++i) sacc[i] = z;
    #pragma unroll
    for (int ni = 0; ni < 4; ++ni) {
      const int rowb = (ni * 16 + l15) * 128;
      const bf16x8 a0 = *(const bf16x8*)((char*)&Kl[cur][0] + rowb + ((lg * 16) ^ swz));
      const bf16x8 a1 = *(const bf16x8*)((char*)&Kl[cur][0] + rowb + ((64 + lg * 16) ^ swz));
      sacc[ni] = mfma_bf16(a0, qreg0, sacc[ni]);
      sacc[ni] = mfma_bf16(a1, qreg1, sacc[ni]);
    }

    // ---- online softmax ----
    float sv[16];
    #pragma unroll
    for (int ni = 0; ni < 4; ++ni)
      #pragma unroll
      for (int r = 0; r < 4; ++r)
        sv[ni * 4 + r] = sacc[ni][r] * 0.125f;
    if constexpr (CROSS) {
      #pragma unroll
      for (int ni = 0; ni < 4; ++ni)
        #pragma unroll
        for (int r = 0; r < 4; ++r)
          sv[ni * 4 + r] += (float)bv[ni][r];
    }
    float mx = sv[0];
    #pragma unroll
    for (int jj = 1; jj < 16; ++jj) mx = fmaxf(mx, sv[jj]);
    mx = fmaxf(mx, __shfl_xor(mx, 16));
    mx = fmaxf(mx, __shfl_xor(mx, 32));
    const float mnew = fmaxf(m_run, mx);
    const float corr = __expf(m_run - mnew);
    m_run = mnew;
    float ps = 0.f;
    #pragma unroll
    for (int jj = 0; jj < 16; ++jj) { sv[jj] = __expf(sv[jj] - mnew); ps += sv[jj]; }
    l_run = l_run * corr + ps;

    // ---- P -> per-wave LDS (fragment-layout transpose) ----
    #pragma unroll
    for (int ni = 0; ni < 4; ++ni) {
      bf16x4 pw;
      #pragma unroll
      for (int r = 0; r < 4; ++r) pw[r] = (bf16)sv[ni * 4 + r];
      *(bf16x4*)(PlW + l15 * 144 + ni * 32 + lg * 8) = pw;
    }
    float cr[4];
    #pragma unroll
    for (int r = 0; r < 4; ++r) cr[r] = __shfl(corr, ((lane >> 4) << 2) + r);
    #pragma unroll
    for (int nd = 0; nd < 4; ++nd)
      #pragma unroll
      for (int r = 0; r < 4; ++r) oacc[nd][r] *= cr[r];

    // ---- O += P . V ----
    const bf16x8 p0 = *(const bf16x8*)(PlW + l15 * 144 + lg * 16);
    const bf16x8 p1 = *(const bf16x8*)(PlW + l15 * 144 + 64 + lg * 16);
    #pragma unroll
    for (int nd = 0; nd < 4; ++nd) {
      const int rowb = (nd * 16 + l15) * 128;
      const bf16x8 v0 = *(const bf16x8*)((char*)&Vl[cur][0] + rowb + ((lg * 16) ^ swz));
      const bf16x8 v1 = *(const bf16x8*)((char*)&Vl[cur][0] + rowb + ((64 + lg * 16) ^ swz));
      oacc[nd] = mfma_bf16(p0, v0, oacc[nd]);
      oacc[nd] = mfma_bf16(p1, v1, oacc[nd]);
    }
    __syncthreads();   // staging t+1 complete; all waves done with buf cur
  }

  // ---- finalize ----
  float ls = l_run + __shfl_xor(l_run, 16);
  ls += __shfl_xor(ls, 32);
  const float inv = 1.0f / ls;
  float ivr[4];
  #pragma unroll
  for (int r = 0; r < 4; ++r) ivr[r] = __shfl(inv, ((lane >> 4) << 2) + r);
  bf16* ob = Out + (size_t)(b * 1024 + qt * 64 + wq * 16 + lg * 4) * 768 + hh * 64 + l15;
  #pragma unroll
  for (int r = 0; r < 4; ++r)
    #pragma unroll
    for (int nd = 0; nd < 4; ++nd)
      ob[(size_t)r * 768 + nd * 16] = (bf16)(oacc[nd][r] * ivr[r]);
}

// ---------------- launcher ----------------
extern "C" void kernel_launch(void* const* d_in, const int* in_sizes, int n_in,
                              void* d_out, int out_size, void* d_ws, size_t ws_size,
                              hipStream_t stream)
{
  (void)in_sizes; (void)n_in; (void)out_size; (void)ws_size;
  const float* x    = (const float*)d_in[0];
  const float* y    = (const float*)d_in[1];
  const unsigned char* mask = (const unsigned char*)d_in[4];
  const float* sim  = (const float*)d_in[5];
  const float* ln1g = (const float*)d_in[6];
  const float* ln1b = (const float*)d_in[7];
  const float* ln2g = (const float*)d_in[8];
  const float* ln2b = (const float*)d_in[9];
  const float* ln3g = (const float*)d_in[10];
  const float* ln3b = (const float*)d_in[11];
  const float* lnyg = (const float*)d_in[12];
  const float* lnyb = (const float*)d_in[13];
  const float* qkvw = (const float*)d_in[14];
  const float* apw  = (const float*)d_in[15];
  const float* apb  = (const float*)d_in[16];
  const float* pqw  = (const float*)d_in[17];
  const float* pkw  = (const float*)d_in[18];
  const float* pvw  = (const float*)d_in[19];
  const float* cpw  = (const float*)d_in[20];
  const float* cpb  = (const float*)d_in[21];
  const float* f1w  = (const float*)d_in[22];
  const float* f1b  = (const float*)d_in[23];
  const float* f2w  = (const float*)d_in[24];
  const float* f2b  = (const float*)d_in[25];

  char* ws = (char*)d_ws;
  size_t off = 0;
  auto alloc = [&](size_t bytes) -> void* {
    off = (off + 255) & ~(size_t)255;
    void* p = ws + off;
    off += bytes;
    return p;
  };
  const size_t T = 4096;  // B*NQ
  bf16* w_qkv = (bf16*)alloc((size_t)2304 * 768 * 2);
  bf16* w_ap  = (bf16*)alloc((size_t)768 * 768 * 2);
  bf16* w_pq  = (bf16*)alloc((size_t)768 * 768 * 2);
  bf16* w_pkv = (bf16*)alloc((size_t)1536 * 768 * 2);
  bf16* w_cp  = (bf16*)alloc((size_t)768 * 768 * 2);
  bf16* w_f1  = (bf16*)alloc((size_t)3072 * 768 * 2);
  bf16* w_f2  = (bf16*)alloc((size_t)768 * 3072 * 2);
  bf16* xn    = (bf16*)alloc(T * 768 * 2);
  bf16* qkvo  = (bf16*)alloc(T * 2304 * 2);
  bf16* vt    = (bf16*)alloc((size_t)48 * 64 * 1024 * 2);
  bf16* sa    = (bf16*)alloc(T * 768 * 2);
  float* x1   = (float*)alloc(T * 768 * 4);
  bf16* yln   = (bf16*)alloc(T * 768 * 2);
  bf16* xn2   = (bf16*)alloc(T * 768 * 2);
  bf16* cqf   = (bf16*)alloc(T * 768 * 2);
  bf16* ckv   = (bf16*)alloc(T * 1536 * 2);
  bf16* cvtT  = (bf16*)alloc((size_t)48 * 64 * 1024 * 2);
  bf16* biasA = (bf16*)alloc((size_t)4 * 12 * 1024 * 1024 * 2);  // 100.7 MB
  bf16* ca    = (bf16*)alloc(T * 768 * 2);
  float* x2   = (float*)alloc(T * 768 * 4);
  bf16* xn3   = (bf16*)alloc(T * 768 * 2);
  bf16* hbuf  = (bf16*)alloc(T * 3072 * 2);

  { // fused weight conversion (pk,pv land adjacent in w_pkv)
    CvtArgs a;
    const float* srcs[8] = {qkvw, apw, pqw, pkw, pvw, cpw, f1w, f2w};
    bf16* dsts[8] = {w_qkv, w_ap, w_pq, w_pkv, w_pkv + 768 * 768, w_cp, w_f1, w_f2};
    const int n4s[8] = {442368, 147456, 147456, 147456, 147456, 147456, 589824, 589824};
    int cum = 0;
    for (int j = 0; j < 8; ++j) {
      a.src[j] = srcs[j]; a.dst[j] = dsts[j];
      cum += n4s[j]; a.end[j] = cum;
    }
    cvt_all_k<<<cum / 256, 256, 0, stream>>>(a);
  }

  bias_k<<<4096, 256, 0, stream>>>(sim, mask, biasA);

  // ---- self-attention ----
  ln_k<true><<<8192, 256, 0, stream>>>(x, ln1g, ln1b, xn, y, lnyg, lnyb, yln);
  gemm_bt<128,128,false,false,false,true,true><<<576, 256, 0, stream>>>(
      xn, w_qkv, nullptr, nullptr, qkvo, nullptr, vt, 1536, 4, 2304, 768);
  fattn_k<0><<<768, 256, 0, stream>>>(
      qkvo, 2304, qkvo + 768, 2304, vt, nullptr, sa);
  gemm_bt<64,128,true,false,true,false,false><<<384, 256, 0, stream>>>(
      sa, w_ap, apb, x, nullptr, x1, nullptr, 0, 8, 768, 768);

  // ---- cross-attention ----
  ln_k<false><<<4096, 256, 0, stream>>>(x1, ln2g, ln2b, xn2,
                                        nullptr, nullptr, nullptr, nullptr);
  gemm_bt<64,128,false,false,false,true,false><<<384, 256, 0, stream>>>(
      xn2, w_pq, nullptr, nullptr, cqf, nullptr, nullptr, 0, 8, 768, 768);
  gemm_bt<128,128,false,false,false,true,true><<<384, 256, 0, stream>>>(
      yln, w_pkv, nullptr, nullptr, ckv, nullptr, cvtT, 768, 4, 1536, 768);
  fattn_k<1><<<768, 256, 0, stream>>>(
      cqf, 768, ckv, 1536, cvtT, biasA, ca);
  gemm_bt<64,128,true,false,true,false,false><<<384, 256, 0, stream>>>(
      ca, w_cp, cpb, x1, nullptr, x2, nullptr, 0, 8, 768, 768);

  // ---- MLP ----
  ln_k<false><<<4096, 256, 0, stream>>>(x2, ln3g, ln3b, xn3,
                                        nullptr, nullptr, nullptr, nullptr);
  gemm_bt<128,128,true,true,false,true,false><<<768, 256, 0, stream>>>(
      xn3, w_f1, f1b, nullptr, hbuf, nullptr, nullptr, 0, 4, 3072, 768);
  gemm_bt<64,128,true,false,true,false,false><<<384, 256, 0, stream>>>(
      hbuf, w_f2, f2b, x2, nullptr, (float*)d_out, nullptr, 0, 8, 768, 3072);

  // ---- y passthrough ----
  copy4_k<<<3072, 256, 0, stream>>>(y, (float*)d_out + 3145728, 786432);
}

// Round 9
// 380.683 us; speedup vs baseline: 1.7599x; 1.0207x over previous
//
#include <hip/hip_runtime.h>
#include <cstdint>
#include <cstddef>

// DinoDecoderBlock on MI355X (gfx950).
// B=4 NQ=NK=1024 C=768 H=12 DH=64, scale=1/8, eps=1e-5.
// R9: co-dispatch independent work in single grids (one stream => overlap via
//     blockIdx partitioning): [cvt+ln(x)+ln(y)], [qkv GEMM + bias precompute],
//     [aproj+pkv], [fc2 + y-copy]. 15 -> 11 dispatches; bias HBM hides under MFMA.

typedef __bf16 bf16;
typedef __attribute__((ext_vector_type(8))) __bf16 bf16x8;
typedef __attribute__((ext_vector_type(4))) __bf16 bf16x4;
typedef __attribute__((ext_vector_type(4))) float f32x4;

typedef __attribute__((address_space(1))) void gvoid;
typedef __attribute__((address_space(3))) void lvoid;

#define DEVI static __device__ __forceinline__

DEVI void gload16(const void* g, void* l) {
  __builtin_amdgcn_global_load_lds((gvoid*)(uintptr_t)g, (lvoid*)(uintptr_t)l, 16, 0, 0);
}

DEVI f32x4 mfma_bf16(bf16x8 a, bf16x8 b, f32x4 c) {
  return __builtin_amdgcn_mfma_f32_16x16x32_bf16(a, b, c, 0, 0, 0);
}

// ================= device bodies =================

// ---- GEMM tile body: C[M,N] = A[M,K]*Bt[N,K]^T; As/Bs are kernel-scope LDS ----
template<int BM, int BN, bool BIAS, bool GELU, bool RES, bool OBF, bool VT>
DEVI void gemm_dev(bf16* As, bf16* Bs, int by, int bx,
                   const bf16* __restrict__ A, const bf16* __restrict__ Bt,
                   const float* __restrict__ bias, const float* __restrict__ res,
                   bf16* __restrict__ Cb, float* __restrict__ Cf,
                   bf16* __restrict__ vtOut, int vtBase, int N, int K)
{
  constexpr int WM = BM / 2, WN = BN / 2;
  constexpr int FM = WM / 16, FN = WN / 16;
  const int tid = threadIdx.x;
  const int lane = tid & 63;
  const int wv = tid >> 6;
  const int wr = wv >> 1, wc = wv & 1;
  const int l15 = lane & 15, lg = lane >> 4;
  const int bm = by * BM, bn = bx * BN;

  f32x4 acc[FM][FN];
  const f32x4 z = {0.f, 0.f, 0.f, 0.f};
  #pragma unroll
  for (int i = 0; i < FM; ++i)
    #pragma unroll
    for (int jj = 0; jj < FN; ++jj) acc[i][jj] = z;

  for (int k0 = 0; k0 < K; k0 += 64) {
    __syncthreads();
    #pragma unroll
    for (int c = tid; c < BM * 8; c += 256) {
      const int row = c >> 3, colb = (c & 7) << 4;
      gload16((const char*)A + ((size_t)(bm + row) * K + k0) * 2 + colb,
              (char*)As + (size_t)c * 16);
    }
    #pragma unroll
    for (int c = tid; c < BN * 8; c += 256) {
      const int row = c >> 3, colb = (c & 7) << 4;
      gload16((const char*)Bt + ((size_t)(bn + row) * K + k0) * 2 + colb,
              (char*)Bs + (size_t)c * 16);
    }
    __syncthreads();
    #pragma unroll
    for (int kk = 0; kk < 64; kk += 32) {
      bf16x8 af[FM], bfr[FN];
      #pragma unroll
      for (int mi = 0; mi < FM; ++mi)
        af[mi] = *(const bf16x8*)(As + (size_t)(wr * WM + mi * 16 + l15) * 64 + kk + lg * 8);
      #pragma unroll
      for (int ni = 0; ni < FN; ++ni)
        bfr[ni] = *(const bf16x8*)(Bs + (size_t)(wc * WN + ni * 16 + l15) * 64 + kk + lg * 8);
      #pragma unroll
      for (int mi = 0; mi < FM; ++mi)
        #pragma unroll
        for (int ni = 0; ni < FN; ++ni)
          acc[mi][ni] = mfma_bf16(af[mi], bfr[ni], acc[mi][ni]);
    }
  }

  #pragma unroll
  for (int mi = 0; mi < FM; ++mi) {
    const int row0 = bm + wr * WM + mi * 16 + lg * 4;
    #pragma unroll
    for (int ni = 0; ni < FN; ++ni) {
      const int col = bn + wc * WN + ni * 16 + l15;
      if constexpr (VT) {
        if (col >= vtBase) {   // V channel: store transposed, 4 consecutive n
          const int hd = col - vtBase;            // h*64+d
          const int bb = row0 >> 10, n0 = row0 & 1023;
          bf16x4 ov;
          #pragma unroll
          for (int r = 0; r < 4; ++r) ov[r] = (bf16)acc[mi][ni][r];
          *(bf16x4*)(vtOut + ((size_t)(bb * 768 + hd)) * 1024 + n0) = ov;
          continue;
        }
      }
      #pragma unroll
      for (int r = 0; r < 4; ++r) {
        float v = acc[mi][ni][r];
        if constexpr (BIAS) v += bias[col];
        if constexpr (GELU) v = 0.5f * v * (1.0f + erff(v * 0.70710678118654752f));
        if constexpr (RES)  v += res[(size_t)(row0 + r) * N + col];
        if constexpr (OBF)  Cb[(size_t)(row0 + r) * N + col] = (bf16)v;
        else                Cf[(size_t)(row0 + r) * N + col] = v;
      }
    }
  }
}

// ---- bias body: biasOut[b][h][q][k] = sim - mean_h + (mask?0:-1e30) ----
DEVI void bias_dev(int blk, int* red,
                   const float* __restrict__ sim,
                   const unsigned char* __restrict__ mask,
                   bf16* __restrict__ biasOut)
{
  const int b = blk >> 10, q = blk & 1023;
  const int t = threadIdx.x;
  const int k4 = t * 4;

  // inline mask dtype detection: for int32 0/1 data, bytes at idx%4!=0 are 0
  int ds = mask[t * 4 + 1] + mask[t * 4 + 2] + mask[t * 4 + 3];
  #pragma unroll
  for (int o = 32; o; o >>= 1) ds += __shfl_xor(ds, o);
  if ((t & 63) == 0) red[t >> 6] = ds;
  __syncthreads();
  const int msh = ((red[0] + red[1] + red[2] + red[3]) == 0) ? 2 : 0;

  const float* sb = sim + (size_t)b * 12 * 1024 * 1024;
  bf16* ob = biasOut + (size_t)b * 12 * 1024 * 1024;

  f32x4 sv[12];
  f32x4 acc = {0.f, 0.f, 0.f, 0.f};
  #pragma unroll
  for (int h = 0; h < 12; ++h) {
    sv[h] = *(const f32x4*)(sb + ((size_t)h * 1024 + q) * 1024 + k4);
    acc += sv[h];
  }
  const f32x4 mean = acc * (1.0f / 12.0f);

  float mb[4];
  if (msh == 0) {
    const uchar4 mv = *(const uchar4*)(mask + (size_t)q * 1024 + k4);
    mb[0] = mv.x ? 0.f : -1e30f; mb[1] = mv.y ? 0.f : -1e30f;
    mb[2] = mv.z ? 0.f : -1e30f; mb[3] = mv.w ? 0.f : -1e30f;
  } else {
    const int4 mv = *(const int4*)((const int*)mask + (size_t)q * 1024 + k4);
    mb[0] = mv.x ? 0.f : -1e30f; mb[1] = mv.y ? 0.f : -1e30f;
    mb[2] = mv.z ? 0.f : -1e30f; mb[3] = mv.w ? 0.f : -1e30f;
  }

  #pragma unroll
  for (int h = 0; h < 12; ++h) {
    bf16x4 o;
    #pragma unroll
    for (int j = 0; j < 4; ++j)
      o[j] = (bf16)(sv[h][j] - mean[j] + mb[j]);
    *(bf16x4*)(ob + ((size_t)h * 1024 + q) * 1024 + k4) = o;
  }
}

// ---- LayerNorm row body (768) ----
DEVI void ln_dev(int row, float* r1, float* r2,
                 const float* __restrict__ xin, const float* __restrict__ g,
                 const float* __restrict__ be, bf16* __restrict__ out)
{
  const int tid = threadIdx.x;
  const int lane = tid & 63, w = tid >> 6;
  const float* xr = xin + (size_t)row * 768;
  const float v0 = xr[tid], v1 = xr[tid + 256], v2 = xr[tid + 512];
  float s = v0 + v1 + v2;
  #pragma unroll
  for (int o = 32; o; o >>= 1) s += __shfl_xor(s, o);
  if (lane == 0) r1[w] = s;
  __syncthreads();
  const float mean = (r1[0] + r1[1] + r1[2] + r1[3]) * (1.0f / 768.0f);
  const float d0 = v0 - mean, d1 = v1 - mean, d2 = v2 - mean;
  float q = d0 * d0 + d1 * d1 + d2 * d2;
  #pragma unroll
  for (int o = 32; o; o >>= 1) q += __shfl_xor(q, o);
  if (lane == 0) r2[w] = q;
  __syncthreads();
  const float inv = rsqrtf((r2[0] + r2[1] + r2[2] + r2[3]) * (1.0f / 768.0f) + 1e-5f);
  bf16* orow = out + (size_t)row * 768;
  orow[tid]       = (bf16)(d0 * inv * g[tid]       + be[tid]);
  orow[tid + 256] = (bf16)(d1 * inv * g[tid + 256] + be[tid + 256]);
  orow[tid + 512] = (bf16)(d2 * inv * g[tid + 512] + be[tid + 512]);
}

// ================= kernels =================

struct CvtArgs {
  const float* src[8];
  bf16* dst[8];
  int end[8];
};

// D1: weight cvt (blocks [0,9216)) + ln(x) (9216..13312) + ln(y) (13312..17408)
__global__ __launch_bounds__(256)
void prep_k(CvtArgs a,
            const float* __restrict__ x, const float* __restrict__ g1,
            const float* __restrict__ b1, bf16* __restrict__ xn,
            const float* __restrict__ y, const float* __restrict__ gy,
            const float* __restrict__ by_, bf16* __restrict__ yln)
{
  __shared__ float r1[4], r2[4];
  const int f = blockIdx.x;
  if (f < 9216) {
    const int i = f * 256 + threadIdx.x;
    int s = 0;
    #pragma unroll
    for (int j = 0; j < 7; ++j) s += (i >= a.end[j]) ? 1 : 0;
    const int base = s ? a.end[s - 1] : 0;
    const int off = i - base;
    const f32x4 v = *((const f32x4*)a.src[s] + off);
    bf16x4 o;
    o[0] = (bf16)v[0]; o[1] = (bf16)v[1]; o[2] = (bf16)v[2]; o[3] = (bf16)v[3];
    *(bf16x4*)(a.dst[s] + (size_t)off * 4) = o;
  } else if (f < 13312) {
    ln_dev(f - 9216, r1, r2, x, g1, b1, xn);
  } else {
    ln_dev(f - 13312, r1, r2, y, gy, by_, yln);
  }
}

// D2: qkv GEMM (576 blocks) + bias precompute (4096 blocks) co-dispatch
__global__ __launch_bounds__(256)
void qkvbias_k(const bf16* __restrict__ xn, const bf16* __restrict__ w_qkv,
               bf16* __restrict__ qkvo, bf16* __restrict__ vt,
               const float* __restrict__ sim, const unsigned char* __restrict__ mask,
               bf16* __restrict__ biasA)
{
  __shared__ bf16 As[128 * 64];
  __shared__ bf16 Bs[128 * 64];
  const int f = blockIdx.x;
  if (f < 576) {
    const int xcd = f & 7, j = f >> 3;
    const int by = xcd + 8 * (j % 4);
    const int bx = j / 4;
    gemm_dev<128,128,false,false,false,true,true>(As, Bs, by, bx,
        xn, w_qkv, nullptr, nullptr, qkvo, nullptr, vt, 1536, 2304, 768);
  } else {
    bias_dev(f - 576, (int*)As, sim, mask, biasA);
  }
}

// D4: aproj (384) + pkv (384) co-dispatch
__global__ __launch_bounds__(256)
void apkv_k(const bf16* __restrict__ sa, const bf16* __restrict__ w_ap,
            const float* __restrict__ apb, const float* __restrict__ x,
            float* __restrict__ x1,
            const bf16* __restrict__ yln, const bf16* __restrict__ w_pkv,
            bf16* __restrict__ ckv, bf16* __restrict__ cvtT)
{
  __shared__ bf16 As[128 * 64];
  __shared__ bf16 Bs[128 * 64];
  const int f = blockIdx.x;
  if (f < 384) {
    const int xcd = f & 7, j = f >> 3;
    const int by = xcd + 8 * (j % 8);
    const int bx = j / 8;
    gemm_dev<64,128,true,false,true,false,false>(As, Bs, by, bx,
        sa, w_ap, apb, x, nullptr, x1, nullptr, 0, 768, 768);
  } else {
    const int g = f - 384;
    const int xcd = g & 7, j = g >> 3;
    const int by = xcd + 8 * (j % 4);
    const int bx = j / 4;
    gemm_dev<128,128,false,false,false,true,true>(As, Bs, by, bx,
        yln, w_pkv, nullptr, nullptr, ckv, nullptr, cvtT, 768, 1536, 768);
  }
}

// D11: fc2 (384) + y-copy (512, grid-stride) co-dispatch
__global__ __launch_bounds__(256)
void fc2copy_k(const bf16* __restrict__ hbuf, const bf16* __restrict__ w_f2,
               const float* __restrict__ f2b, const float* __restrict__ x2,
               float* __restrict__ outp,
               const float* __restrict__ y, float* __restrict__ ycopy)
{
  __shared__ bf16 As[128 * 64];
  __shared__ bf16 Bs[128 * 64];
  const int f = blockIdx.x;
  if (f < 384) {
    const int xcd = f & 7, j = f >> 3;
    const int by = xcd + 8 * (j % 8);
    const int bx = j / 8;
    gemm_dev<64,128,true,false,true,false,false>(As, Bs, by, bx,
        hbuf, w_f2, f2b, x2, nullptr, outp, nullptr, 0, 768, 3072);
  } else {
    for (int i = (f - 384) * 256 + threadIdx.x; i < 786432; i += 512 * 256)
      ((f32x4*)ycopy)[i] = ((const f32x4*)y)[i];
  }
}

// standalone GEMM wrapper (pq / cproj / fc1)
template<int BM, int BN, bool BIAS, bool GELU, bool RES, bool OBF>
__global__ __launch_bounds__(256)
void gemm_bt(const bf16* __restrict__ A, const bf16* __restrict__ Bt,
             const float* __restrict__ bias, const float* __restrict__ res,
             bf16* __restrict__ Cb, float* __restrict__ Cf,
             int nyPerXcd, int N, int K)
{
  __shared__ bf16 As[BM * 64];
  __shared__ bf16 Bs[BN * 64];
  const int f = blockIdx.x;
  const int xcd = f & 7, j = f >> 3;
  const int by = xcd + 8 * (j % nyPerXcd);
  const int bx = j / nyPerXcd;
  gemm_dev<BM,BN,BIAS,GELU,RES,OBF,false>(As, Bs, by, bx,
      A, Bt, bias, res, Cb, Cf, nullptr, 0, N, K);
}

// standalone LayerNorm (ln2 / ln3)
__global__ __launch_bounds__(256)
void ln_k(const float* __restrict__ xin, const float* __restrict__ g,
          const float* __restrict__ be, bf16* __restrict__ out)
{
  __shared__ float r1[4], r2[4];
  ln_dev(blockIdx.x, r1, r2, xin, g, be, out);
}

// ---------------- flash attention: 64 q-rows/block, 4 waves, online softmax ----
template<int CROSS>
__global__ __launch_bounds__(256, 3)
void fattn_k(const bf16* __restrict__ Qp, int ldq,
             const bf16* __restrict__ Kp, int ldk,
             const bf16* __restrict__ Vt,
             const bf16* __restrict__ bias,   // [4][12][1024][1024] bf16, CROSS only
             bf16* __restrict__ Out)
{
  __shared__ bf16 Kl[2][64 * 64];     // 16 KB, [krow][c] swizzled
  __shared__ bf16 Vl[2][64 * 64];     // 16 KB, [d][k]   swizzled
  __shared__ bf16 Pl[4][16 * 72];     // per-wave P tile, padded

  const int f = blockIdx.x;
  const int r8 = f & 7, rest = f >> 3;
  const int c6 = rest % 6, qt = rest / 6;
  const int pp = r8 + 8 * c6;          // 0..47
  const int b = pp / 12, hh = pp % 12;
  const int tid = threadIdx.x, lane = tid & 63, wq = tid >> 6;
  const int l15 = lane & 15, lg = lane >> 4;

  bf16x8 qreg0, qreg1;
  {
    const bf16* qsrc = Qp + (size_t)(b * 1024 + qt * 64 + wq * 16 + l15) * ldq + hh * 64 + lg * 8;
    qreg0 = *(const bf16x8*)qsrc;
    qreg1 = *(const bf16x8*)(qsrc + 32);
  }
  const char* Kbase = (const char*)(Kp + (size_t)b * 1024 * ldk + hh * 64);
  const char* Vbase = (const char*)(Vt + (size_t)(b * 12 + hh) * 64 * 1024);
  const bf16* biasRow = nullptr;
  if constexpr (CROSS)
    biasRow = bias + (((size_t)(b * 12 + hh)) * 1024 + qt * 64 + wq * 16 + l15) * 1024;

  f32x4 oacc[4];
  const f32x4 z = {0.f, 0.f, 0.f, 0.f};
  #pragma unroll
  for (int i = 0; i < 4; ++i) oacc[i] = z;
  float m_run = -1e30f, l_run = 0.f;

  char* PlW = (char*)&Pl[wq][0];
  const int swz = (l15 & 7) << 4;      // read-side XOR (row&7)<<4

  auto stage = [&](int buf, int t) {
    const int k0 = t * 64;
    #pragma unroll
    for (int jj = 0; jj < 2; ++jj) {
      const int c = jj * 256 + tid;                // 16B chunk id 0..511
      const int r = c >> 3;
      const int sw = ((c & 7) ^ (r & 7)) << 4;     // swizzled byte-col in row
      gload16(Kbase + ((size_t)(k0 + r) * ldk) * 2 + sw, (char*)&Kl[buf][0] + (size_t)c * 16);
      gload16(Vbase + (size_t)r * 2048 + (size_t)k0 * 2 + sw, (char*)&Vl[buf][0] + (size_t)c * 16);
    }
  };

  stage(0, 0);
  __syncthreads();   // prologue staging drained

  for (int t = 0; t < 16; ++t) {
    const int cur = t & 1;
    const int k0 = t * 64;
    if (t < 15) stage(cur ^ 1, t + 1);   // async prefetch; drained at loop-end barrier

    bf16x4 bv[4];
    if constexpr (CROSS) {
      const bf16* bp = biasRow + k0 + lg * 4;
      #pragma unroll
      for (int ni = 0; ni < 4; ++ni) bv[ni] = *(const bf16x4*)(bp + ni * 16);
    }

    // ---- S^T = K . Q^T ----
    f32x4 sacc[4];
    #pragma unroll
    for (int i = 0; i < 4; ++i) sacc[i] = z;
    #pragma unroll
    for (int ni = 0; ni < 4; ++ni) {
      const int rowb = (ni * 16 + l15) * 128;
      const bf16x8 a0 = *(const bf16x8*)((char*)&Kl[cur][0] + rowb + ((lg * 16) ^ swz));
      const bf16x8 a1 = *(const bf16x8*)((char*)&Kl[cur][0] + rowb + ((64 + lg * 16) ^ swz));
      sacc[ni] = mfma_bf16(a0, qreg0, sacc[ni]);
      sacc[ni] = mfma_bf16(a1, qreg1, sacc[ni]);
    }

    // ---- online softmax ----
    float sv[16];
    #pragma unroll
    for (int ni = 0; ni < 4; ++ni)
      #pragma unroll
      for (int r = 0; r < 4; ++r)
        sv[ni * 4 + r] = sacc[ni][r] * 0.125f;
    if constexpr (CROSS) {
      #pragma unroll
      for (int ni = 0; ni < 4; ++ni)
        #pragma unroll
        for (int r = 0; r < 4; ++r)
          sv[ni * 4 + r] += (float)bv[ni][r];
    }
    float mx = sv[0];
    #pragma unroll
    for (int jj = 1; jj < 16; ++jj) mx = fmaxf(mx, sv[jj]);
    mx = fmaxf(mx, __shfl_xor(mx, 16));
    mx = fmaxf(mx, __shfl_xor(mx, 32));
    const float mnew = fmaxf(m_run, mx);
    const float corr = __expf(m_run - mnew);
    m_run = mnew;
    float ps = 0.f;
    #pragma unroll
    for (int jj = 0; jj < 16; ++jj) { sv[jj] = __expf(sv[jj] - mnew); ps += sv[jj]; }
    l_run = l_run * corr + ps;

    // ---- P -> per-wave LDS (fragment-layout transpose) ----
    #pragma unroll
    for (int ni = 0; ni < 4; ++ni) {
      bf16x4 pw;
      #pragma unroll
      for (int r = 0; r < 4; ++r) pw[r] = (bf16)sv[ni * 4 + r];
      *(bf16x4*)(PlW + l15 * 144 + ni * 32 + lg * 8) = pw;
    }
    float cr[4];
    #pragma unroll
    for (int r = 0; r < 4; ++r) cr[r] = __shfl(corr, ((lane >> 4) << 2) + r);
    #pragma unroll
    for (int nd = 0; nd < 4; ++nd)
      #pragma unroll
      for (int r = 0; r < 4; ++r) oacc[nd][r] *= cr[r];

    // ---- O += P . V ----
    const bf16x8 p0 = *(const bf16x8*)(PlW + l15 * 144 + lg * 16);
    const bf16x8 p1 = *(const bf16x8*)(PlW + l15 * 144 + 64 + lg * 16);
    #pragma unroll
    for (int nd = 0; nd < 4; ++nd) {
      const int rowb = (nd * 16 + l15) * 128;
      const bf16x8 v0 = *(const bf16x8*)((char*)&Vl[cur][0] + rowb + ((lg * 16) ^ swz));
      const bf16x8 v1 = *(const bf16x8*)((char*)&Vl[cur][0] + rowb + ((64 + lg * 16) ^ swz));
      oacc[nd] = mfma_bf16(p0, v0, oacc[nd]);
      oacc[nd] = mfma_bf16(p1, v1, oacc[nd]);
    }
    __syncthreads();   // staging t+1 complete; all waves done with buf cur
  }

  // ---- finalize ----
  float ls = l_run + __shfl_xor(l_run, 16);
  ls += __shfl_xor(ls, 32);
  const float inv = 1.0f / ls;
  float ivr[4];
  #pragma unroll
  for (int r = 0; r < 4; ++r) ivr[r] = __shfl(inv, ((lane >> 4) << 2) + r);
  bf16* ob = Out + (size_t)(b * 1024 + qt * 64 + wq * 16 + lg * 4) * 768 + hh * 64 + l15;
  #pragma unroll
  for (int r = 0; r < 4; ++r)
    #pragma unroll
    for (int nd = 0; nd < 4; ++nd)
      ob[(size_t)r * 768 + nd * 16] = (bf16)(oacc[nd][r] * ivr[r]);
}

// ---------------- launcher ----------------
extern "C" void kernel_launch(void* const* d_in, const int* in_sizes, int n_in,
                              void* d_out, int out_size, void* d_ws, size_t ws_size,
                              hipStream_t stream)
{
  (void)in_sizes; (void)n_in; (void)out_size; (void)ws_size;
  const float* x    = (const float*)d_in[0];
  const float* y    = (const float*)d_in[1];
  const unsigned char* mask = (const unsigned char*)d_in[4];
  const float* sim  = (const float*)d_in[5];
  const float* ln1g = (const float*)d_in[6];
  const float* ln1b = (const float*)d_in[7];
  const float* ln2g = (const float*)d_in[8];
  const float* ln2b = (const float*)d_in[9];
  const float* ln3g = (const float*)d_in[10];
  const float* ln3b = (const float*)d_in[11];
  const float* lnyg = (const float*)d_in[12];
  const float* lnyb = (const float*)d_in[13];
  const float* qkvw = (const float*)d_in[14];
  const float* apw  = (const float*)d_in[15];
  const float* apb  = (const float*)d_in[16];
  const float* pqw  = (const float*)d_in[17];
  const float* pkw  = (const float*)d_in[18];
  const float* pvw  = (const float*)d_in[19];
  const float* cpw  = (const float*)d_in[20];
  const float* cpb  = (const float*)d_in[21];
  const float* f1w  = (const float*)d_in[22];
  const float* f1b  = (const float*)d_in[23];
  const float* f2w  = (const float*)d_in[24];
  const float* f2b  = (const float*)d_in[25];

  char* ws = (char*)d_ws;
  size_t off = 0;
  auto alloc = [&](size_t bytes) -> void* {
    off = (off + 255) & ~(size_t)255;
    void* p = ws + off;
    off += bytes;
    return p;
  };
  const size_t T = 4096;  // B*NQ
  bf16* w_qkv = (bf16*)alloc((size_t)2304 * 768 * 2);
  bf16* w_ap  = (bf16*)alloc((size_t)768 * 768 * 2);
  bf16* w_pq  = (bf16*)alloc((size_t)768 * 768 * 2);
  bf16* w_pkv = (bf16*)alloc((size_t)1536 * 768 * 2);
  bf16* w_cp  = (bf16*)alloc((size_t)768 * 768 * 2);
  bf16* w_f1  = (bf16*)alloc((size_t)3072 * 768 * 2);
  bf16* w_f2  = (bf16*)alloc((size_t)768 * 3072 * 2);
  bf16* xn    = (bf16*)alloc(T * 768 * 2);
  bf16* qkvo  = (bf16*)alloc(T * 2304 * 2);
  bf16* vt    = (bf16*)alloc((size_t)48 * 64 * 1024 * 2);
  bf16* sa    = (bf16*)alloc(T * 768 * 2);
  float* x1   = (float*)alloc(T * 768 * 4);
  bf16* yln   = (bf16*)alloc(T * 768 * 2);
  bf16* xn2   = (bf16*)alloc(T * 768 * 2);
  bf16* cqf   = (bf16*)alloc(T * 768 * 2);
  bf16* ckv   = (bf16*)alloc(T * 1536 * 2);
  bf16* cvtT  = (bf16*)alloc((size_t)48 * 64 * 1024 * 2);
  bf16* biasA = (bf16*)alloc((size_t)4 * 12 * 1024 * 1024 * 2);  // 100.7 MB
  bf16* ca    = (bf16*)alloc(T * 768 * 2);
  float* x2   = (float*)alloc(T * 768 * 4);
  bf16* xn3   = (bf16*)alloc(T * 768 * 2);
  bf16* hbuf  = (bf16*)alloc(T * 3072 * 2);

  CvtArgs a;
  {
    const float* srcs[8] = {qkvw, apw, pqw, pkw, pvw, cpw, f1w, f2w};
    bf16* dsts[8] = {w_qkv, w_ap, w_pq, w_pkv, w_pkv + 768 * 768, w_cp, w_f1, w_f2};
    const int n4s[8] = {442368, 147456, 147456, 147456, 147456, 147456, 589824, 589824};
    int cum = 0;
    for (int j = 0; j < 8; ++j) {
      a.src[j] = srcs[j]; a.dst[j] = dsts[j];
      cum += n4s[j]; a.end[j] = cum;
    }
  }

  // D1: cvt + ln(x) + ln(y)
  prep_k<<<17408, 256, 0, stream>>>(a, x, ln1g, ln1b, xn, y, lnyg, lnyb, yln);

  // D2: qkv GEMM + bias precompute (overlapped)
  qkvbias_k<<<4672, 256, 0, stream>>>(xn, w_qkv, qkvo, vt, sim, mask, biasA);

  // D3: self-attention
  fattn_k<0><<<768, 256, 0, stream>>>(
      qkvo, 2304, qkvo + 768, 2304, vt, nullptr, sa);

  // D4: aproj + pkv (both independent GEMMs)
  apkv_k<<<768, 256, 0, stream>>>(sa, w_ap, apb, x, x1, yln, w_pkv, ckv, cvtT);

  // D5: ln2
  ln_k<<<4096, 256, 0, stream>>>(x1, ln2g, ln2b, xn2);

  // D6: pq
  gemm_bt<64,128,false,false,false,true><<<384, 256, 0, stream>>>(
      xn2, w_pq, nullptr, nullptr, cqf, nullptr, 8, 768, 768);

  // D7: cross-attention
  fattn_k<1><<<768, 256, 0, stream>>>(
      cqf, 768, ckv, 1536, cvtT, biasA, ca);

  // D8: cproj
  gemm_bt<64,128,true,false,true,false><<<384, 256, 0, stream>>>(
      ca, w_cp, cpb, x1, nullptr, x2, 8, 768, 768);

  // D9: ln3
  ln_k<<<4096, 256, 0, stream>>>(x2, ln3g, ln3b, xn3);

  // D10: fc1
  gemm_bt<128,128,true,true,false,true><<<768, 256, 0, stream>>>(
      xn3, w_f1, f1b, nullptr, hbuf, nullptr, 4, 3072, 768);

  // D11: fc2 + y passthrough copy
  fc2copy_k<<<896, 256, 0, stream>>>(
      hbuf, w_f2, f2b, x2, (float*)d_out, y, (float*)d_out + 3145728);
}

// Round 10
// 380.567 us; speedup vs baseline: 1.7605x; 1.0003x over previous
//
#include <hip/hip_runtime.h>
#include <cstdint>
#include <cstddef>

// DinoDecoderBlock on MI355X (gfx950).
// B=4 NQ=NK=1024 C=768 H=12 DH=64, scale=1/8, eps=1e-5.
// R10: bias precompute co-dispatched with prep (streaming-with-streaming);
//      qkv GEMM standalone again (R9's GEMM+streaming mix starved both:
//      long-lived GEMM blocks held CU slots -> 19% occupancy, 2 TB/s).

typedef __bf16 bf16;
typedef __attribute__((ext_vector_type(8))) __bf16 bf16x8;
typedef __attribute__((ext_vector_type(4))) __bf16 bf16x4;
typedef __attribute__((ext_vector_type(4))) float f32x4;

typedef __attribute__((address_space(1))) void gvoid;
typedef __attribute__((address_space(3))) void lvoid;

#define DEVI static __device__ __forceinline__

DEVI void gload16(const void* g, void* l) {
  __builtin_amdgcn_global_load_lds((gvoid*)(uintptr_t)g, (lvoid*)(uintptr_t)l, 16, 0, 0);
}

DEVI f32x4 mfma_bf16(bf16x8 a, bf16x8 b, f32x4 c) {
  return __builtin_amdgcn_mfma_f32_16x16x32_bf16(a, b, c, 0, 0, 0);
}

// ================= device bodies =================

// ---- GEMM tile body: C[M,N] = A[M,K]*Bt[N,K]^T; As/Bs are kernel-scope LDS ----
template<int BM, int BN, bool BIAS, bool GELU, bool RES, bool OBF, bool VT>
DEVI void gemm_dev(bf16* As, bf16* Bs, int by, int bx,
                   const bf16* __restrict__ A, const bf16* __restrict__ Bt,
                   const float* __restrict__ bias, const float* __restrict__ res,
                   bf16* __restrict__ Cb, float* __restrict__ Cf,
                   bf16* __restrict__ vtOut, int vtBase, int N, int K)
{
  constexpr int WM = BM / 2, WN = BN / 2;
  constexpr int FM = WM / 16, FN = WN / 16;
  const int tid = threadIdx.x;
  const int lane = tid & 63;
  const int wv = tid >> 6;
  const int wr = wv >> 1, wc = wv & 1;
  const int l15 = lane & 15, lg = lane >> 4;
  const int bm = by * BM, bn = bx * BN;

  f32x4 acc[FM][FN];
  const f32x4 z = {0.f, 0.f, 0.f, 0.f};
  #pragma unroll
  for (int i = 0; i < FM; ++i)
    #pragma unroll
    for (int jj = 0; jj < FN; ++jj) acc[i][jj] = z;

  for (int k0 = 0; k0 < K; k0 += 64) {
    __syncthreads();
    #pragma unroll
    for (int c = tid; c < BM * 8; c += 256) {
      const int row = c >> 3, colb = (c & 7) << 4;
      gload16((const char*)A + ((size_t)(bm + row) * K + k0) * 2 + colb,
              (char*)As + (size_t)c * 16);
    }
    #pragma unroll
    for (int c = tid; c < BN * 8; c += 256) {
      const int row = c >> 3, colb = (c & 7) << 4;
      gload16((const char*)Bt + ((size_t)(bn + row) * K + k0) * 2 + colb,
              (char*)Bs + (size_t)c * 16);
    }
    __syncthreads();
    #pragma unroll
    for (int kk = 0; kk < 64; kk += 32) {
      bf16x8 af[FM], bfr[FN];
      #pragma unroll
      for (int mi = 0; mi < FM; ++mi)
        af[mi] = *(const bf16x8*)(As + (size_t)(wr * WM + mi * 16 + l15) * 64 + kk + lg * 8);
      #pragma unroll
      for (int ni = 0; ni < FN; ++ni)
        bfr[ni] = *(const bf16x8*)(Bs + (size_t)(wc * WN + ni * 16 + l15) * 64 + kk + lg * 8);
      #pragma unroll
      for (int mi = 0; mi < FM; ++mi)
        #pragma unroll
        for (int ni = 0; ni < FN; ++ni)
          acc[mi][ni] = mfma_bf16(af[mi], bfr[ni], acc[mi][ni]);
    }
  }

  #pragma unroll
  for (int mi = 0; mi < FM; ++mi) {
    const int row0 = bm + wr * WM + mi * 16 + lg * 4;
    #pragma unroll
    for (int ni = 0; ni < FN; ++ni) {
      const int col = bn + wc * WN + ni * 16 + l15;
      if constexpr (VT) {
        if (col >= vtBase) {   // V channel: store transposed, 4 consecutive n
          const int hd = col - vtBase;            // h*64+d
          const int bb = row0 >> 10, n0 = row0 & 1023;
          bf16x4 ov;
          #pragma unroll
          for (int r = 0; r < 4; ++r) ov[r] = (bf16)acc[mi][ni][r];
          *(bf16x4*)(vtOut + ((size_t)(bb * 768 + hd)) * 1024 + n0) = ov;
          continue;
        }
      }
      #pragma unroll
      for (int r = 0; r < 4; ++r) {
        float v = acc[mi][ni][r];
        if constexpr (BIAS) v += bias[col];
        if constexpr (GELU) v = 0.5f * v * (1.0f + erff(v * 0.70710678118654752f));
        if constexpr (RES)  v += res[(size_t)(row0 + r) * N + col];
        if constexpr (OBF)  Cb[(size_t)(row0 + r) * N + col] = (bf16)v;
        else                Cf[(size_t)(row0 + r) * N + col] = v;
      }
    }
  }
}

// ---- bias body: biasOut[b][h][q][k] = sim - mean_h + (mask?0:-1e30) ----
DEVI void bias_dev(int blk, int* red,
                   const float* __restrict__ sim,
                   const unsigned char* __restrict__ mask,
                   bf16* __restrict__ biasOut)
{
  const int b = blk >> 10, q = blk & 1023;
  const int t = threadIdx.x;
  const int k4 = t * 4;

  // inline mask dtype detection: for int32 0/1 data, bytes at idx%4!=0 are 0
  int ds = mask[t * 4 + 1] + mask[t * 4 + 2] + mask[t * 4 + 3];
  #pragma unroll
  for (int o = 32; o; o >>= 1) ds += __shfl_xor(ds, o);
  if ((t & 63) == 0) red[t >> 6] = ds;
  __syncthreads();
  const int msh = ((red[0] + red[1] + red[2] + red[3]) == 0) ? 2 : 0;

  const float* sb = sim + (size_t)b * 12 * 1024 * 1024;
  bf16* ob = biasOut + (size_t)b * 12 * 1024 * 1024;

  f32x4 sv[12];
  f32x4 acc = {0.f, 0.f, 0.f, 0.f};
  #pragma unroll
  for (int h = 0; h < 12; ++h) {
    sv[h] = *(const f32x4*)(sb + ((size_t)h * 1024 + q) * 1024 + k4);
    acc += sv[h];
  }
  const f32x4 mean = acc * (1.0f / 12.0f);

  float mb[4];
  if (msh == 0) {
    const uchar4 mv = *(const uchar4*)(mask + (size_t)q * 1024 + k4);
    mb[0] = mv.x ? 0.f : -1e30f; mb[1] = mv.y ? 0.f : -1e30f;
    mb[2] = mv.z ? 0.f : -1e30f; mb[3] = mv.w ? 0.f : -1e30f;
  } else {
    const int4 mv = *(const int4*)((const int*)mask + (size_t)q * 1024 + k4);
    mb[0] = mv.x ? 0.f : -1e30f; mb[1] = mv.y ? 0.f : -1e30f;
    mb[2] = mv.z ? 0.f : -1e30f; mb[3] = mv.w ? 0.f : -1e30f;
  }

  #pragma unroll
  for (int h = 0; h < 12; ++h) {
    bf16x4 o;
    #pragma unroll
    for (int j = 0; j < 4; ++j)
      o[j] = (bf16)(sv[h][j] - mean[j] + mb[j]);
    *(bf16x4*)(ob + ((size_t)h * 1024 + q) * 1024 + k4) = o;
  }
}

// ---- LayerNorm row body (768) ----
DEVI void ln_dev(int row, float* r1, float* r2,
                 const float* __restrict__ xin, const float* __restrict__ g,
                 const float* __restrict__ be, bf16* __restrict__ out)
{
  const int tid = threadIdx.x;
  const int lane = tid & 63, w = tid >> 6;
  const float* xr = xin + (size_t)row * 768;
  const float v0 = xr[tid], v1 = xr[tid + 256], v2 = xr[tid + 512];
  float s = v0 + v1 + v2;
  #pragma unroll
  for (int o = 32; o; o >>= 1) s += __shfl_xor(s, o);
  if (lane == 0) r1[w] = s;
  __syncthreads();
  const float mean = (r1[0] + r1[1] + r1[2] + r1[3]) * (1.0f / 768.0f);
  const float d0 = v0 - mean, d1 = v1 - mean, d2 = v2 - mean;
  float q = d0 * d0 + d1 * d1 + d2 * d2;
  #pragma unroll
  for (int o = 32; o; o >>= 1) q += __shfl_xor(q, o);
  if (lane == 0) r2[w] = q;
  __syncthreads();
  const float inv = rsqrtf((r2[0] + r2[1] + r2[2] + r2[3]) * (1.0f / 768.0f) + 1e-5f);
  bf16* orow = out + (size_t)row * 768;
  orow[tid]       = (bf16)(d0 * inv * g[tid]       + be[tid]);
  orow[tid + 256] = (bf16)(d1 * inv * g[tid + 256] + be[tid + 256]);
  orow[tid + 512] = (bf16)(d2 * inv * g[tid + 512] + be[tid + 512]);
}

// ================= kernels =================

struct CvtArgs {
  const float* src[8];
  bf16* dst[8];
  int end[8];
};

// D1 (all streaming): weight cvt [0,9216) + ln(x) [9216,13312) + ln(y)
// [13312,17408) + bias precompute [17408,21504)
__global__ __launch_bounds__(256)
void prep_k(CvtArgs a,
            const float* __restrict__ x, const float* __restrict__ g1,
            const float* __restrict__ b1, bf16* __restrict__ xn,
            const float* __restrict__ y, const float* __restrict__ gy,
            const float* __restrict__ by_, bf16* __restrict__ yln,
            const float* __restrict__ sim, const unsigned char* __restrict__ mask,
            bf16* __restrict__ biasA)
{
  __shared__ float r1[4], r2[4];
  const int f = blockIdx.x;
  if (f < 9216) {
    const int i = f * 256 + threadIdx.x;
    int s = 0;
    #pragma unroll
    for (int j = 0; j < 7; ++j) s += (i >= a.end[j]) ? 1 : 0;
    const int base = s ? a.end[s - 1] : 0;
    const int off = i - base;
    const f32x4 v = *((const f32x4*)a.src[s] + off);
    bf16x4 o;
    o[0] = (bf16)v[0]; o[1] = (bf16)v[1]; o[2] = (bf16)v[2]; o[3] = (bf16)v[3];
    *(bf16x4*)(a.dst[s] + (size_t)off * 4) = o;
  } else if (f < 13312) {
    ln_dev(f - 9216, r1, r2, x, g1, b1, xn);
  } else if (f < 17408) {
    ln_dev(f - 13312, r1, r2, y, gy, by_, yln);
  } else {
    bias_dev(f - 17408, (int*)r1, sim, mask, biasA);
  }
}

// D4: aproj (384) + pkv (384) co-dispatch (both compute-bound GEMMs)
__global__ __launch_bounds__(256)
void apkv_k(const bf16* __restrict__ sa, const bf16* __restrict__ w_ap,
            const float* __restrict__ apb, const float* __restrict__ x,
            float* __restrict__ x1,
            const bf16* __restrict__ yln, const bf16* __restrict__ w_pkv,
            bf16* __restrict__ ckv, bf16* __restrict__ cvtT)
{
  __shared__ bf16 As[128 * 64];
  __shared__ bf16 Bs[128 * 64];
  const int f = blockIdx.x;
  if (f < 384) {
    const int xcd = f & 7, j = f >> 3;
    const int by = xcd + 8 * (j % 8);
    const int bx = j / 8;
    gemm_dev<64,128,true,false,true,false,false>(As, Bs, by, bx,
        sa, w_ap, apb, x, nullptr, x1, nullptr, 0, 768, 768);
  } else {
    const int g = f - 384;
    const int xcd = g & 7, j = g >> 3;
    const int by = xcd + 8 * (j % 4);
    const int bx = j / 4;
    gemm_dev<128,128,false,false,false,true,true>(As, Bs, by, bx,
        yln, w_pkv, nullptr, nullptr, ckv, nullptr, cvtT, 768, 1536, 768);
  }
}

// D11: fc2 (384) + y-copy (512, grid-stride) co-dispatch
__global__ __launch_bounds__(256)
void fc2copy_k(const bf16* __restrict__ hbuf, const bf16* __restrict__ w_f2,
               const float* __restrict__ f2b, const float* __restrict__ x2,
               float* __restrict__ outp,
               const float* __restrict__ y, float* __restrict__ ycopy)
{
  __shared__ bf16 As[128 * 64];
  __shared__ bf16 Bs[128 * 64];
  const int f = blockIdx.x;
  if (f < 384) {
    const int xcd = f & 7, j = f >> 3;
    const int by = xcd + 8 * (j % 8);
    const int bx = j / 8;
    gemm_dev<64,128,true,false,true,false,false>(As, Bs, by, bx,
        hbuf, w_f2, f2b, x2, nullptr, outp, nullptr, 0, 768, 3072);
  } else {
    for (int i = (f - 384) * 256 + threadIdx.x; i < 786432; i += 512 * 256)
      ((f32x4*)ycopy)[i] = ((const f32x4*)y)[i];
  }
}

// standalone GEMM wrapper (qkv / pq / cproj / fc1)
template<int BM, int BN, bool BIAS, bool GELU, bool RES, bool OBF, bool VT>
__global__ __launch_bounds__(256)
void gemm_bt(const bf16* __restrict__ A, const bf16* __restrict__ Bt,
             const float* __restrict__ bias, const float* __restrict__ res,
             bf16* __restrict__ Cb, float* __restrict__ Cf,
             bf16* __restrict__ vtOut, int vtBase,
             int nyPerXcd, int N, int K)
{
  __shared__ bf16 As[BM * 64];
  __shared__ bf16 Bs[BN * 64];
  const int f = blockIdx.x;
  const int xcd = f & 7, j = f >> 3;
  const int by = xcd + 8 * (j % nyPerXcd);
  const int bx = j / nyPerXcd;
  gemm_dev<BM,BN,BIAS,GELU,RES,OBF,VT>(As, Bs, by, bx,
      A, Bt, bias, res, Cb, Cf, vtOut, vtBase, N, K);
}

// standalone LayerNorm (ln2 / ln3)
__global__ __launch_bounds__(256)
void ln_k(const float* __restrict__ xin, const float* __restrict__ g,
          const float* __restrict__ be, bf16* __restrict__ out)
{
  __shared__ float r1[4], r2[4];
  ln_dev(blockIdx.x, r1, r2, xin, g, be, out);
}

// ---------------- flash attention: 64 q-rows/block, 4 waves, online softmax ----
template<int CROSS>
__global__ __launch_bounds__(256, 3)
void fattn_k(const bf16* __restrict__ Qp, int ldq,
             const bf16* __restrict__ Kp, int ldk,
             const bf16* __restrict__ Vt,
             const bf16* __restrict__ bias,   // [4][12][1024][1024] bf16, CROSS only
             bf16* __restrict__ Out)
{
  __shared__ bf16 Kl[2][64 * 64];     // 16 KB, [krow][c] swizzled
  __shared__ bf16 Vl[2][64 * 64];     // 16 KB, [d][k]   swizzled
  __shared__ bf16 Pl[4][16 * 72];     // per-wave P tile, padded

  const int f = blockIdx.x;
  const int r8 = f & 7, rest = f >> 3;
  const int c6 = rest % 6, qt = rest / 6;
  const int pp = r8 + 8 * c6;          // 0..47
  const int b = pp / 12, hh = pp % 12;
  const int tid = threadIdx.x, lane = tid & 63, wq = tid >> 6;
  const int l15 = lane & 15, lg = lane >> 4;

  bf16x8 qreg0, qreg1;
  {
    const bf16* qsrc = Qp + (size_t)(b * 1024 + qt * 64 + wq * 16 + l15) * ldq + hh * 64 + lg * 8;
    qreg0 = *(const bf16x8*)qsrc;
    qreg1 = *(const bf16x8*)(qsrc + 32);
  }
  const char* Kbase = (const char*)(Kp + (size_t)b * 1024 * ldk + hh * 64);
  const char* Vbase = (const char*)(Vt + (size_t)(b * 12 + hh) * 64 * 1024);
  const bf16* biasRow = nullptr;
  if constexpr (CROSS)
    biasRow = bias + (((size_t)(b * 12 + hh)) * 1024 + qt * 64 + wq * 16 + l15) * 1024;

  f32x4 oacc[4];
  const f32x4 z = {0.f, 0.f, 0.f, 0.f};
  #pragma unroll
  for (int i = 0; i < 4; ++i) oacc[i] = z;
  float m_run = -1e30f, l_run = 0.f;

  char* PlW = (char*)&Pl[wq][0];
  const int swz = (l15 & 7) << 4;      // read-side XOR (row&7)<<4

  auto stage = [&](int buf, int t) {
    const int k0 = t * 64;
    #pragma unroll
    for (int jj = 0; jj < 2; ++jj) {
      const int c = jj * 256 + tid;                // 16B chunk id 0..511
      const int r = c >> 3;
      const int sw = ((c & 7) ^ (r & 7)) << 4;     // swizzled byte-col in row
      gload16(Kbase + ((size_t)(k0 + r) * ldk) * 2 + sw, (char*)&Kl[buf][0] + (size_t)c * 16);
      gload16(Vbase + (size_t)r * 2048 + (size_t)k0 * 2 + sw, (char*)&Vl[buf][0] + (size_t)c * 16);
    }
  };

  stage(0, 0);
  __syncthreads();   // prologue staging drained

  for (int t = 0; t < 16; ++t) {
    const int cur = t & 1;
    const int k0 = t * 64;
    if (t < 15) stage(cur ^ 1, t + 1);   // async prefetch; drained at loop-end barrier

    bf16x4 bv[4];
    if constexpr (CROSS) {
      const bf16* bp = biasRow + k0 + lg * 4;
      #pragma unroll
      for (int ni = 0; ni < 4; ++ni) bv[ni] = *(const bf16x4*)(bp + ni * 16);
    }

    // ---- S^T = K . Q^T ----
    f32x4 sacc[4];
    #pragma unroll
    for (int i = 0; i < 4; ++i) sacc[i] = z;
    #pragma unroll
    for (int ni = 0; ni < 4; ++ni) {
      const int rowb = (ni * 16 + l15) * 128;
      const bf16x8 a0 = *(const bf16x8*)((char*)&Kl[cur][0] + rowb + ((lg * 16) ^ swz));
      const bf16x8 a1 = *(const bf16x8*)((char*)&Kl[cur][0] + rowb + ((64 + lg * 16) ^ swz));
      sacc[ni] = mfma_bf16(a0, qreg0, sacc[ni]);
      sacc[ni] = mfma_bf16(a1, qreg1, sacc[ni]);
    }

    // ---- online softmax ----
    float sv[16];
    #pragma unroll
    for (int ni = 0; ni < 4; ++ni)
      #pragma unroll
      for (int r = 0; r < 4; ++r)
        sv[ni * 4 + r] = sacc[ni][r] * 0.125f;
    if constexpr (CROSS) {
      #pragma unroll
      for (int ni = 0; ni < 4; ++ni)
        #pragma unroll
        for (int r = 0; r < 4; ++r)
          sv[ni * 4 + r] += (float)bv[ni][r];
    }
    float mx = sv[0];
    #pragma unroll
    for (int jj = 1; jj < 16; ++jj) mx = fmaxf(mx, sv[jj]);
    mx = fmaxf(mx, __shfl_xor(mx, 16));
    mx = fmaxf(mx, __shfl_xor(mx, 32));
    const float mnew = fmaxf(m_run, mx);
    const float corr = __expf(m_run - mnew);
    m_run = mnew;
    float ps = 0.f;
    #pragma unroll
    for (int jj = 0; jj < 16; ++jj) { sv[jj] = __expf(sv[jj] - mnew); ps += sv[jj]; }
    l_run = l_run * corr + ps;

    // ---- P -> per-wave LDS (fragment-layout transpose) ----
    #pragma unroll
    for (int ni = 0; ni < 4; ++ni) {
      bf16x4 pw;
      #pragma unroll
      for (int r = 0; r < 4; ++r) pw[r] = (bf16)sv[ni * 4 + r];
      *(bf16x4*)(PlW + l15 * 144 + ni * 32 + lg * 8) = pw;
    }
    float cr[4];
    #pragma unroll
    for (int r = 0; r < 4; ++r) cr[r] = __shfl(corr, ((lane >> 4) << 2) + r);
    #pragma unroll
    for (int nd = 0; nd < 4; ++nd)
      #pragma unroll
      for (int r = 0; r < 4; ++r) oacc[nd][r] *= cr[r];

    // ---- O += P . V ----
    const bf16x8 p0 = *(const bf16x8*)(PlW + l15 * 144 + lg * 16);
    const bf16x8 p1 = *(const bf16x8*)(PlW + l15 * 144 + 64 + lg * 16);
    #pragma unroll
    for (int nd = 0; nd < 4; ++nd) {
      const int rowb = (nd * 16 + l15) * 128;
      const bf16x8 v0 = *(const bf16x8*)((char*)&Vl[cur][0] + rowb + ((lg * 16) ^ swz));
      const bf16x8 v1 = *(const bf16x8*)((char*)&Vl[cur][0] + rowb + ((64 + lg * 16) ^ swz));
      oacc[nd] = mfma_bf16(p0, v0, oacc[nd]);
      oacc[nd] = mfma_bf16(p1, v1, oacc[nd]);
    }
    __syncthreads();   // staging t+1 complete; all waves done with buf cur
  }

  // ---- finalize ----
  float ls = l_run + __shfl_xor(l_run, 16);
  ls += __shfl_xor(ls, 32);
  const float inv = 1.0f / ls;
  float ivr[4];
  #pragma unroll
  for (int r = 0; r < 4; ++r) ivr[r] = __shfl(inv, ((lane >> 4) << 2) + r);
  bf16* ob = Out + (size_t)(b * 1024 + qt * 64 + wq * 16 + lg * 4) * 768 + hh * 64 + l15;
  #pragma unroll
  for (int r = 0; r < 4; ++r)
    #pragma unroll
    for (int nd = 0; nd < 4; ++nd)
      ob[(size_t)r * 768 + nd * 16] = (bf16)(oacc[nd][r] * ivr[r]);
}

// ---------------- launcher ----------------
extern "C" void kernel_launch(void* const* d_in, const int* in_sizes, int n_in,
                              void* d_out, int out_size, void* d_ws, size_t ws_size,
                              hipStream_t stream)
{
  (void)in_sizes; (void)n_in; (void)out_size; (void)ws_size;
  const float* x    = (const float*)d_in[0];
  const float* y    = (const float*)d_in[1];
  const unsigned char* mask = (const unsigned char*)d_in[4];
  const float* sim  = (const float*)d_in[5];
  const float* ln1g = (const float*)d_in[6];
  const float* ln1b = (const float*)d_in[7];
  const float* ln2g = (const float*)d_in[8];
  const float* ln2b = (const float*)d_in[9];
  const float* ln3g = (const float*)d_in[10];
  const float* ln3b = (const float*)d_in[11];
  const float* lnyg = (const float*)d_in[12];
  const float* lnyb = (const float*)d_in[13];
  const float* qkvw = (const float*)d_in[14];
  const float* apw  = (const float*)d_in[15];
  const float* apb  = (const float*)d_in[16];
  const float* pqw  = (const float*)d_in[17];
  const float* pkw  = (const float*)d_in[18];
  const float* pvw  = (const float*)d_in[19];
  const float* cpw  = (const float*)d_in[20];
  const float* cpb  = (const float*)d_in[21];
  const float* f1w  = (const float*)d_in[22];
  const float* f1b  = (const float*)d_in[23];
  const float* f2w  = (const float*)d_in[24];
  const float* f2b  = (const float*)d_in[25];

  char* ws = (char*)d_ws;
  size_t off = 0;
  auto alloc = [&](size_t bytes) -> void* {
    off = (off + 255) & ~(size_t)255;
    void* p = ws + off;
    off += bytes;
    return p;
  };
  const size_t T = 4096;  // B*NQ
  bf16* w_qkv = (bf16*)alloc((size_t)2304 * 768 * 2);
  bf16* w_ap  = (bf16*)alloc((size_t)768 * 768 * 2);
  bf16* w_pq  = (bf16*)alloc((size_t)768 * 768 * 2);
  bf16* w_pkv = (bf16*)alloc((size_t)1536 * 768 * 2);
  bf16* w_cp  = (bf16*)alloc((size_t)768 * 768 * 2);
  bf16* w_f1  = (bf16*)alloc((size_t)3072 * 768 * 2);
  bf16* w_f2  = (bf16*)alloc((size_t)768 * 3072 * 2);
  bf16* xn    = (bf16*)alloc(T * 768 * 2);
  bf16* qkvo  = (bf16*)alloc(T * 2304 * 2);
  bf16* vt    = (bf16*)alloc((size_t)48 * 64 * 1024 * 2);
  bf16* sa    = (bf16*)alloc(T * 768 * 2);
  float* x1   = (float*)alloc(T * 768 * 4);
  bf16* yln   = (bf16*)alloc(T * 768 * 2);
  bf16* xn2   = (bf16*)alloc(T * 768 * 2);
  bf16* cqf   = (bf16*)alloc(T * 768 * 2);
  bf16* ckv   = (bf16*)alloc(T * 1536 * 2);
  bf16* cvtT  = (bf16*)alloc((size_t)48 * 64 * 1024 * 2);
  bf16* biasA = (bf16*)alloc((size_t)4 * 12 * 1024 * 1024 * 2);  // 100.7 MB
  bf16* ca    = (bf16*)alloc(T * 768 * 2);
  float* x2   = (float*)alloc(T * 768 * 4);
  bf16* xn3   = (bf16*)alloc(T * 768 * 2);
  bf16* hbuf  = (bf16*)alloc(T * 3072 * 2);

  CvtArgs a;
  {
    const float* srcs[8] = {qkvw, apw, pqw, pkw, pvw, cpw, f1w, f2w};
    bf16* dsts[8] = {w_qkv, w_ap, w_pq, w_pkv, w_pkv + 768 * 768, w_cp, w_f1, w_f2};
    const int n4s[8] = {442368, 147456, 147456, 147456, 147456, 147456, 589824, 589824};
    int cum = 0;
    for (int j = 0; j < 8; ++j) {
      a.src[j] = srcs[j]; a.dst[j] = dsts[j];
      cum += n4s[j]; a.end[j] = cum;
    }
  }

  // D1: cvt + ln(x) + ln(y) + bias precompute (all streaming)
  prep_k<<<21504, 256, 0, stream>>>(a, x, ln1g, ln1b, xn, y, lnyg, lnyb, yln,
                                    sim, mask, biasA);

  // D2: qkv GEMM (+ fused V transpose)
  gemm_bt<128,128,false,false,false,true,true><<<576, 256, 0, stream>>>(
      xn, w_qkv, nullptr, nullptr, qkvo, nullptr, vt, 1536, 4, 2304, 768);

  // D3: self-attention
  fattn_k<0><<<768, 256, 0, stream>>>(
      qkvo, 2304, qkvo + 768, 2304, vt, nullptr, sa);

  // D4: aproj + pkv (both compute-bound GEMMs)
  apkv_k<<<768, 256, 0, stream>>>(sa, w_ap, apb, x, x1, yln, w_pkv, ckv, cvtT);

  // D5: ln2
  ln_k<<<4096, 256, 0, stream>>>(x1, ln2g, ln2b, xn2);

  // D6: pq
  gemm_bt<64,128,false,false,false,true,false><<<384, 256, 0, stream>>>(
      xn2, w_pq, nullptr, nullptr, cqf, nullptr, nullptr, 0, 8, 768, 768);

  // D7: cross-attention
  fattn_k<1><<<768, 256, 0, stream>>>(
      cqf, 768, ckv, 1536, cvtT, biasA, ca);

  // D8: cproj
  gemm_bt<64,128,true,false,true,false,false><<<384, 256, 0, stream>>>(
      ca, w_cp, cpb, x1, nullptr, x2, nullptr, 0, 8, 768, 768);

  // D9: ln3
  ln_k<<<4096, 256, 0, stream>>>(x2, ln3g, ln3b, xn3);

  // D10: fc1
  gemm_bt<128,128,true,true,false,true,false><<<768, 256, 0, stream>>>(
      xn3, w_f1, f1b, nullptr, hbuf, nullptr, nullptr, 0, 4, 3072, 768);

  // D11: fc2 + y passthrough copy
  fc2copy_k<<<896, 256, 0, stream>>>(
      hbuf, w_f2, f2b, x2, (float*)d_out, y, (float*)d_out + 3145728);
}

// Round 11
// 380.186 us; speedup vs baseline: 1.7622x; 1.0010x over previous
//
#include <hip/hip_runtime.h>
#include <cstdint>
#include <cstddef>

// DinoDecoderBlock on MI355X (gfx950).
// B=4 NQ=NK=1024 C=768 H=12 DH=64, scale=1/8, eps=1e-5.
// R11: prep_k rebuilt for HBM BW: cvt ILP-4 (2304 blks), barrier-free per-wave
//      LayerNorm (2048 blks), bias 2-q/block ILP-24 (2048 blks). Standalone LNs
//      also wave-parallel. (R10 profile: prep_k 120us @ 2.3 TB/s, latency-bound.)

typedef __bf16 bf16;
typedef __attribute__((ext_vector_type(8))) __bf16 bf16x8;
typedef __attribute__((ext_vector_type(4))) __bf16 bf16x4;
typedef __attribute__((ext_vector_type(4))) float f32x4;

typedef __attribute__((address_space(1))) void gvoid;
typedef __attribute__((address_space(3))) void lvoid;

#define DEVI static __device__ __forceinline__

DEVI void gload16(const void* g, void* l) {
  __builtin_amdgcn_global_load_lds((gvoid*)(uintptr_t)g, (lvoid*)(uintptr_t)l, 16, 0, 0);
}

DEVI f32x4 mfma_bf16(bf16x8 a, bf16x8 b, f32x4 c) {
  return __builtin_amdgcn_mfma_f32_16x16x32_bf16(a, b, c, 0, 0, 0);
}

// ================= device bodies =================

// ---- GEMM tile body ----
template<int BM, int BN, bool BIAS, bool GELU, bool RES, bool OBF, bool VT>
DEVI void gemm_dev(bf16* As, bf16* Bs, int by, int bx,
                   const bf16* __restrict__ A, const bf16* __restrict__ Bt,
                   const float* __restrict__ bias, const float* __restrict__ res,
                   bf16* __restrict__ Cb, float* __restrict__ Cf,
                   bf16* __restrict__ vtOut, int vtBase, int N, int K)
{
  constexpr int WM = BM / 2, WN = BN / 2;
  constexpr int FM = WM / 16, FN = WN / 16;
  const int tid = threadIdx.x;
  const int lane = tid & 63;
  const int wv = tid >> 6;
  const int wr = wv >> 1, wc = wv & 1;
  const int l15 = lane & 15, lg = lane >> 4;
  const int bm = by * BM, bn = bx * BN;

  f32x4 acc[FM][FN];
  const f32x4 z = {0.f, 0.f, 0.f, 0.f};
  #pragma unroll
  for (int i = 0; i < FM; ++i)
    #pragma unroll
    for (int jj = 0; jj < FN; ++jj) acc[i][jj] = z;

  for (int k0 = 0; k0 < K; k0 += 64) {
    __syncthreads();
    #pragma unroll
    for (int c = tid; c < BM * 8; c += 256) {
      const int row = c >> 3, colb = (c & 7) << 4;
      gload16((const char*)A + ((size_t)(bm + row) * K + k0) * 2 + colb,
              (char*)As + (size_t)c * 16);
    }
    #pragma unroll
    for (int c = tid; c < BN * 8; c += 256) {
      const int row = c >> 3, colb = (c & 7) << 4;
      gload16((const char*)Bt + ((size_t)(bn + row) * K + k0) * 2 + colb,
              (char*)Bs + (size_t)c * 16);
    }
    __syncthreads();
    #pragma unroll
    for (int kk = 0; kk < 64; kk += 32) {
      bf16x8 af[FM], bfr[FN];
      #pragma unroll
      for (int mi = 0; mi < FM; ++mi)
        af[mi] = *(const bf16x8*)(As + (size_t)(wr * WM + mi * 16 + l15) * 64 + kk + lg * 8);
      #pragma unroll
      for (int ni = 0; ni < FN; ++ni)
        bfr[ni] = *(const bf16x8*)(Bs + (size_t)(wc * WN + ni * 16 + l15) * 64 + kk + lg * 8);
      #pragma unroll
      for (int mi = 0; mi < FM; ++mi)
        #pragma unroll
        for (int ni = 0; ni < FN; ++ni)
          acc[mi][ni] = mfma_bf16(af[mi], bfr[ni], acc[mi][ni]);
    }
  }

  #pragma unroll
  for (int mi = 0; mi < FM; ++mi) {
    const int row0 = bm + wr * WM + mi * 16 + lg * 4;
    #pragma unroll
    for (int ni = 0; ni < FN; ++ni) {
      const int col = bn + wc * WN + ni * 16 + l15;
      if constexpr (VT) {
        if (col >= vtBase) {   // V channel: store transposed, 4 consecutive n
          const int hd = col - vtBase;            // h*64+d
          const int bb = row0 >> 10, n0 = row0 & 1023;
          bf16x4 ov;
          #pragma unroll
          for (int r = 0; r < 4; ++r) ov[r] = (bf16)acc[mi][ni][r];
          *(bf16x4*)(vtOut + ((size_t)(bb * 768 + hd)) * 1024 + n0) = ov;
          continue;
        }
      }
      #pragma unroll
      for (int r = 0; r < 4; ++r) {
        float v = acc[mi][ni][r];
        if constexpr (BIAS) v += bias[col];
        if constexpr (GELU) v = 0.5f * v * (1.0f + erff(v * 0.70710678118654752f));
        if constexpr (RES)  v += res[(size_t)(row0 + r) * N + col];
        if constexpr (OBF)  Cb[(size_t)(row0 + r) * N + col] = (bf16)v;
        else                Cf[(size_t)(row0 + r) * N + col] = v;
      }
    }
  }
}

// ---- wave-parallel LayerNorm: one wave = one row of 768, no barriers ----
DEVI void lnw_dev(int row,
                  const float* __restrict__ xin, const float* __restrict__ g,
                  const float* __restrict__ be, bf16* __restrict__ out)
{
  const int lane = threadIdx.x & 63;
  const f32x4* xr = (const f32x4*)(xin + (size_t)row * 768);
  f32x4 v[3];
  #pragma unroll
  for (int j = 0; j < 3; ++j) v[j] = xr[lane + 64 * j];
  float s = 0.f;
  #pragma unroll
  for (int j = 0; j < 3; ++j) s += v[j][0] + v[j][1] + v[j][2] + v[j][3];
  #pragma unroll
  for (int o = 32; o; o >>= 1) s += __shfl_xor(s, o);
  const float mean = s * (1.0f / 768.0f);
  float q = 0.f;
  #pragma unroll
  for (int j = 0; j < 3; ++j)
    #pragma unroll
    for (int e = 0; e < 4; ++e) { const float d = v[j][e] - mean; q += d * d; }
  #pragma unroll
  for (int o = 32; o; o >>= 1) q += __shfl_xor(q, o);
  const float inv = rsqrtf(q * (1.0f / 768.0f) + 1e-5f);
  #pragma unroll
  for (int j = 0; j < 3; ++j) {
    const int c = lane + 64 * j;
    const f32x4 gv = ((const f32x4*)g)[c];
    const f32x4 bv = ((const f32x4*)be)[c];
    bf16x4 o4;
    #pragma unroll
    for (int e = 0; e < 4; ++e)
      o4[e] = (bf16)((v[j][e] - mean) * inv * gv[e] + bv[e]);
    *((bf16x4*)out + (size_t)row * 192 + c) = o4;
  }
}

// ---- bias body, 2 q-rows per block (ILP-24 loads) ----
DEVI void bias2_dev(int blk, int* red,
                    const float* __restrict__ sim,
                    const unsigned char* __restrict__ mask,
                    bf16* __restrict__ biasOut)
{
  const int b = blk >> 9;
  const int q0 = (blk & 511) * 2;
  const int t = threadIdx.x;
  const int k4 = t * 4;

  // mask dtype detect (3KB window; int32 0/1 data has zero bytes at idx%4!=0)
  int ds = mask[t * 4 + 1] + mask[t * 4 + 2] + mask[t * 4 + 3];
  #pragma unroll
  for (int o = 32; o; o >>= 1) ds += __shfl_xor(ds, o);
  if ((t & 63) == 0) red[t >> 6] = ds;
  __syncthreads();
  const int msh = ((red[0] + red[1] + red[2] + red[3]) == 0) ? 2 : 0;

  const float* sb = sim + (size_t)b * 12 * 1024 * 1024;
  bf16* ob = biasOut + (size_t)b * 12 * 1024 * 1024;

  #pragma unroll
  for (int p = 0; p < 2; ++p) {
    const int q = q0 + p;
    f32x4 sv[12];
    f32x4 acc = {0.f, 0.f, 0.f, 0.f};
    #pragma unroll
    for (int h = 0; h < 12; ++h) {
      sv[h] = *(const f32x4*)(sb + ((size_t)h * 1024 + q) * 1024 + k4);
      acc += sv[h];
    }
    const f32x4 mean = acc * (1.0f / 12.0f);

    float mb[4];
    if (msh == 0) {
      const uchar4 mv = *(const uchar4*)(mask + (size_t)q * 1024 + k4);
      mb[0] = mv.x ? 0.f : -1e30f; mb[1] = mv.y ? 0.f : -1e30f;
      mb[2] = mv.z ? 0.f : -1e30f; mb[3] = mv.w ? 0.f : -1e30f;
    } else {
      const int4 mv = *(const int4*)((const int*)mask + (size_t)q * 1024 + k4);
      mb[0] = mv.x ? 0.f : -1e30f; mb[1] = mv.y ? 0.f : -1e30f;
      mb[2] = mv.z ? 0.f : -1e30f; mb[3] = mv.w ? 0.f : -1e30f;
    }

    #pragma unroll
    for (int h = 0; h < 12; ++h) {
      bf16x4 o;
      #pragma unroll
      for (int j = 0; j < 4; ++j)
        o[j] = (bf16)(sv[h][j] - mean[j] + mb[j]);
      *(bf16x4*)(ob + ((size_t)h * 1024 + q) * 1024 + k4) = o;
    }
  }
}

// ================= kernels =================

struct CvtArgs {
  const float* src[8];
  bf16* dst[8];
  int end[8];
};

// D1 (all streaming, high-ILP):
//   cvt [0,2304): 4 f32x4 chunks/thread
//   LN  [2304,4352): 4 waves x 1 row each; rows 0..4095=x, 4096..8191=y
//   bias[4352,6400): 2 q-rows/block
__global__ __launch_bounds__(256)
void prep_k(CvtArgs a,
            const float* __restrict__ x, const float* __restrict__ g1,
            const float* __restrict__ b1, bf16* __restrict__ xn,
            const float* __restrict__ y, const float* __restrict__ gy,
            const float* __restrict__ by_, bf16* __restrict__ yln,
            const float* __restrict__ sim, const unsigned char* __restrict__ mask,
            bf16* __restrict__ biasA)
{
  __shared__ int red[4];
  const int f = blockIdx.x;
  const int t = threadIdx.x;
  if (f < 2304) {
    #pragma unroll
    for (int j = 0; j < 4; ++j) {
      const int i = f * 1024 + j * 256 + t;
      int s = 0;
      #pragma unroll
      for (int k = 0; k < 7; ++k) s += (i >= a.end[k]) ? 1 : 0;
      const int base = s ? a.end[s - 1] : 0;
      const int off = i - base;
      const f32x4 v = *((const f32x4*)a.src[s] + off);
      bf16x4 o;
      o[0] = (bf16)v[0]; o[1] = (bf16)v[1]; o[2] = (bf16)v[2]; o[3] = (bf16)v[3];
      *(bf16x4*)(a.dst[s] + (size_t)off * 4) = o;
    }
  } else if (f < 4352) {
    const int row = (f - 2304) * 4 + (t >> 6);
    if (row < 4096) lnw_dev(row, x, g1, b1, xn);
    else            lnw_dev(row - 4096, y, gy, by_, yln);
  } else {
    bias2_dev(f - 4352, red, sim, mask, biasA);
  }
}

// D4: aproj (384) + pkv (384) co-dispatch (both compute-bound GEMMs)
__global__ __launch_bounds__(256)
void apkv_k(const bf16* __restrict__ sa, const bf16* __restrict__ w_ap,
            const float* __restrict__ apb, const float* __restrict__ x,
            float* __restrict__ x1,
            const bf16* __restrict__ yln, const bf16* __restrict__ w_pkv,
            bf16* __restrict__ ckv, bf16* __restrict__ cvtT)
{
  __shared__ bf16 As[128 * 64];
  __shared__ bf16 Bs[128 * 64];
  const int f = blockIdx.x;
  if (f < 384) {
    const int xcd = f & 7, j = f >> 3;
    const int by = xcd + 8 * (j % 8);
    const int bx = j / 8;
    gemm_dev<64,128,true,false,true,false,false>(As, Bs, by, bx,
        sa, w_ap, apb, x, nullptr, x1, nullptr, 0, 768, 768);
  } else {
    const int g = f - 384;
    const int xcd = g & 7, j = g >> 3;
    const int by = xcd + 8 * (j % 4);
    const int bx = j / 4;
    gemm_dev<128,128,false,false,false,true,true>(As, Bs, by, bx,
        yln, w_pkv, nullptr, nullptr, ckv, nullptr, cvtT, 768, 1536, 768);
  }
}

// D11: fc2 (384) + y-copy (512, grid-stride) co-dispatch
__global__ __launch_bounds__(256)
void fc2copy_k(const bf16* __restrict__ hbuf, const bf16* __restrict__ w_f2,
               const float* __restrict__ f2b, const float* __restrict__ x2,
               float* __restrict__ outp,
               const float* __restrict__ y, float* __restrict__ ycopy)
{
  __shared__ bf16 As[128 * 64];
  __shared__ bf16 Bs[128 * 64];
  const int f = blockIdx.x;
  if (f < 384) {
    const int xcd = f & 7, j = f >> 3;
    const int by = xcd + 8 * (j % 8);
    const int bx = j / 8;
    gemm_dev<64,128,true,false,true,false,false>(As, Bs, by, bx,
        hbuf, w_f2, f2b, x2, nullptr, outp, nullptr, 0, 768, 3072);
  } else {
    for (int i = (f - 384) * 256 + threadIdx.x; i < 786432; i += 512 * 256)
      ((f32x4*)ycopy)[i] = ((const f32x4*)y)[i];
  }
}

// standalone GEMM wrapper (qkv / pq / cproj / fc1)
template<int BM, int BN, bool BIAS, bool GELU, bool RES, bool OBF, bool VT>
__global__ __launch_bounds__(256)
void gemm_bt(const bf16* __restrict__ A, const bf16* __restrict__ Bt,
             const float* __restrict__ bias, const float* __restrict__ res,
             bf16* __restrict__ Cb, float* __restrict__ Cf,
             bf16* __restrict__ vtOut, int vtBase,
             int nyPerXcd, int N, int K)
{
  __shared__ bf16 As[BM * 64];
  __shared__ bf16 Bs[BN * 64];
  const int f = blockIdx.x;
  const int xcd = f & 7, j = f >> 3;
  const int by = xcd + 8 * (j % nyPerXcd);
  const int bx = j / nyPerXcd;
  gemm_dev<BM,BN,BIAS,GELU,RES,OBF,VT>(As, Bs, by, bx,
      A, Bt, bias, res, Cb, Cf, vtOut, vtBase, N, K);
}

// standalone LayerNorm (ln2 / ln3): 4 rows/block, wave-parallel
__global__ __launch_bounds__(256)
void ln_k(const float* __restrict__ xin, const float* __restrict__ g,
          const float* __restrict__ be, bf16* __restrict__ out)
{
  lnw_dev(blockIdx.x * 4 + (threadIdx.x >> 6), xin, g, be, out);
}

// ---------------- flash attention: 64 q-rows/block, 4 waves, online softmax ----
template<int CROSS>
__global__ __launch_bounds__(256, 3)
void fattn_k(const bf16* __restrict__ Qp, int ldq,
             const bf16* __restrict__ Kp, int ldk,
             const bf16* __restrict__ Vt,
             const bf16* __restrict__ bias,   // [4][12][1024][1024] bf16, CROSS only
             bf16* __restrict__ Out)
{
  __shared__ bf16 Kl[2][64 * 64];     // 16 KB, [krow][c] swizzled
  __shared__ bf16 Vl[2][64 * 64];     // 16 KB, [d][k]   swizzled
  __shared__ bf16 Pl[4][16 * 72];     // per-wave P tile, padded

  const int f = blockIdx.x;
  const int r8 = f & 7, rest = f >> 3;
  const int c6 = rest % 6, qt = rest / 6;
  const int pp = r8 + 8 * c6;          // 0..47
  const int b = pp / 12, hh = pp % 12;
  const int tid = threadIdx.x, lane = tid & 63, wq = tid >> 6;
  const int l15 = lane & 15, lg = lane >> 4;

  bf16x8 qreg0, qreg1;
  {
    const bf16* qsrc = Qp + (size_t)(b * 1024 + qt * 64 + wq * 16 + l15) * ldq + hh * 64 + lg * 8;
    qreg0 = *(const bf16x8*)qsrc;
    qreg1 = *(const bf16x8*)(qsrc + 32);
  }
  const char* Kbase = (const char*)(Kp + (size_t)b * 1024 * ldk + hh * 64);
  const char* Vbase = (const char*)(Vt + (size_t)(b * 12 + hh) * 64 * 1024);
  const bf16* biasRow = nullptr;
  if constexpr (CROSS)
    biasRow = bias + (((size_t)(b * 12 + hh)) * 1024 + qt * 64 + wq * 16 + l15) * 1024;

  f32x4 oacc[4];
  const f32x4 z = {0.f, 0.f, 0.f, 0.f};
  #pragma unroll
  for (int i = 0; i < 4; ++i) oacc[i] = z;
  float m_run = -1e30f, l_run = 0.f;

  char* PlW = (char*)&Pl[wq][0];
  const int swz = (l15 & 7) << 4;      // read-side XOR (row&7)<<4

  auto stage = [&](int buf, int t) {
    const int k0 = t * 64;
    #pragma unroll
    for (int jj = 0; jj < 2; ++jj) {
      const int c = jj * 256 + tid;                // 16B chunk id 0..511
      const int r = c >> 3;
      const int sw = ((c & 7) ^ (r & 7)) << 4;     // swizzled byte-col in row
      gload16(Kbase + ((size_t)(k0 + r) * ldk) * 2 + sw, (char*)&Kl[buf][0] + (size_t)c * 16);
      gload16(Vbase + (size_t)r * 2048 + (size_t)k0 * 2 + sw, (char*)&Vl[buf][0] + (size_t)c * 16);
    }
  };

  stage(0, 0);
  __syncthreads();   // prologue staging drained

  for (int t = 0; t < 16; ++t) {
    const int cur = t & 1;
    const int k0 = t * 64;
    if (t < 15) stage(cur ^ 1, t + 1);   // async prefetch; drained at loop-end barrier

    bf16x4 bv[4];
    if constexpr (CROSS) {
      const bf16* bp = biasRow + k0 + lg * 4;
      #pragma unroll
      for (int ni = 0; ni < 4; ++ni) bv[ni] = *(const bf16x4*)(bp + ni * 16);
    }

    // ---- S^T = K . Q^T ----
    f32x4 sacc[4];
    #pragma unroll
    for (int i = 0; i < 4; ++i) sacc[i] = z;
    #pragma unroll
    for (int ni = 0; ni < 4; ++ni) {
      const int rowb = (ni * 16 + l15) * 128;
      const bf16x8 a0 = *(const bf16x8*)((char*)&Kl[cur][0] + rowb + ((lg * 16) ^ swz));
      const bf16x8 a1 = *(const bf16x8*)((char*)&Kl[cur][0] + rowb + ((64 + lg * 16) ^ swz));
      sacc[ni] = mfma_bf16(a0, qreg0, sacc[ni]);
      sacc[ni] = mfma_bf16(a1, qreg1, sacc[ni]);
    }

    // ---- online softmax ----
    float sv[16];
    #pragma unroll
    for (int ni = 0; ni < 4; ++ni)
      #pragma unroll
      for (int r = 0; r < 4; ++r)
        sv[ni * 4 + r] = sacc[ni][r] * 0.125f;
    if constexpr (CROSS) {
      #pragma unroll
      for (int ni = 0; ni < 4; ++ni)
        #pragma unroll
        for (int r = 0; r < 4; ++r)
          sv[ni * 4 + r] += (float)bv[ni][r];
    }
    float mx = sv[0];
    #pragma unroll
    for (int jj = 1; jj < 16; ++jj) mx = fmaxf(mx, sv[jj]);
    mx = fmaxf(mx, __shfl_xor(mx, 16));
    mx = fmaxf(mx, __shfl_xor(mx, 32));
    const float mnew = fmaxf(m_run, mx);
    const float corr = __expf(m_run - mnew);
    m_run = mnew;
    float ps = 0.f;
    #pragma unroll
    for (int jj = 0; jj < 16; ++jj) { sv[jj] = __expf(sv[jj] - mnew); ps += sv[jj]; }
    l_run = l_run * corr + ps;

    // ---- P -> per-wave LDS (fragment-layout transpose) ----
    #pragma unroll
    for (int ni = 0; ni < 4; ++ni) {
      bf16x4 pw;
      #pragma unroll
      for (int r = 0; r < 4; ++r) pw[r] = (bf16)sv[ni * 4 + r];
      *(bf16x4*)(PlW + l15 * 144 + ni * 32 + lg * 8) = pw;
    }
    float cr[4];
    #pragma unroll
    for (int r = 0; r < 4; ++r) cr[r] = __shfl(corr, ((lane >> 4) << 2) + r);
    #pragma unroll
    for (int nd = 0; nd < 4; ++nd)
      #pragma unroll
      for (int r = 0; r < 4; ++r) oacc[nd][r] *= cr[r];

    // ---- O += P . V ----
    const bf16x8 p0 = *(const bf16x8*)(PlW + l15 * 144 + lg * 16);
    const bf16x8 p1 = *(const bf16x8*)(PlW + l15 * 144 + 64 + lg * 16);
    #pragma unroll
    for (int nd = 0; nd < 4; ++nd) {
      const int rowb = (nd * 16 + l15) * 128;
      const bf16x8 v0 = *(const bf16x8*)((char*)&Vl[cur][0] + rowb + ((lg * 16) ^ swz));
      const bf16x8 v1 = *(const bf16x8*)((char*)&Vl[cur][0] + rowb + ((64 + lg * 16) ^ swz));
      oacc[nd] = mfma_bf16(p0, v0, oacc[nd]);
      oacc[nd] = mfma_bf16(p1, v1, oacc[nd]);
    }
    __syncthreads();   // staging t+1 complete; all waves done with buf cur
  }

  // ---- finalize ----
  float ls = l_run + __shfl_xor(l_run, 16);
  ls += __shfl_xor(ls, 32);
  const float inv = 1.0f / ls;
  float ivr[4];
  #pragma unroll
  for (int r = 0; r < 4; ++r) ivr[r] = __shfl(inv, ((lane >> 4) << 2) + r);
  bf16* ob = Out + (size_t)(b * 1024 + qt * 64 + wq * 16 + lg * 4) * 768 + hh * 64 + l15;
  #pragma unroll
  for (int r = 0; r < 4; ++r)
    #pragma unroll
    for (int nd = 0; nd < 4; ++nd)
      ob[(size_t)r * 768 + nd * 16] = (bf16)(oacc[nd][r] * ivr[r]);
}

// ---------------- launcher ----------------
extern "C" void kernel_launch(void* const* d_in, const int* in_sizes, int n_in,
                              void* d_out, int out_size, void* d_ws, size_t ws_size,
                              hipStream_t stream)
{
  (void)in_sizes; (void)n_in; (void)out_size; (void)ws_size;
  const float* x    = (const float*)d_in[0];
  const float* y    = (const float*)d_in[1];
  const unsigned char* mask = (const unsigned char*)d_in[4];
  const float* sim  = (const float*)d_in[5];
  const float* ln1g = (const float*)d_in[6];
  const float* ln1b = (const float*)d_in[7];
  const float* ln2g = (const float*)d_in[8];
  const float* ln2b = (const float*)d_in[9];
  const float* ln3g = (const float*)d_in[10];
  const float* ln3b = (const float*)d_in[11];
  const float* lnyg = (const float*)d_in[12];
  const float* lnyb = (const float*)d_in[13];
  const float* qkvw = (const float*)d_in[14];
  const float* apw  = (const float*)d_in[15];
  const float* apb  = (const float*)d_in[16];
  const float* pqw  = (const float*)d_in[17];
  const float* pkw  = (const float*)d_in[18];
  const float* pvw  = (const float*)d_in[19];
  const float* cpw  = (const float*)d_in[20];
  const float* cpb  = (const float*)d_in[21];
  const float* f1w  = (const float*)d_in[22];
  const float* f1b  = (const float*)d_in[23];
  const float* f2w  = (const float*)d_in[24];
  const float* f2b  = (const float*)d_in[25];

  char* ws = (char*)d_ws;
  size_t off = 0;
  auto alloc = [&](size_t bytes) -> void* {
    off = (off + 255) & ~(size_t)255;
    void* p = ws + off;
    off += bytes;
    return p;
  };
  const size_t T = 4096;  // B*NQ
  bf16* w_qkv = (bf16*)alloc((size_t)2304 * 768 * 2);
  bf16* w_ap  = (bf16*)alloc((size_t)768 * 768 * 2);
  bf16* w_pq  = (bf16*)alloc((size_t)768 * 768 * 2);
  bf16* w_pkv = (bf16*)alloc((size_t)1536 * 768 * 2);
  bf16* w_cp  = (bf16*)alloc((size_t)768 * 768 * 2);
  bf16* w_f1  = (bf16*)alloc((size_t)3072 * 768 * 2);
  bf16* w_f2  = (bf16*)alloc((size_t)768 * 3072 * 2);
  bf16* xn    = (bf16*)alloc(T * 768 * 2);
  bf16* qkvo  = (bf16*)alloc(T * 2304 * 2);
  bf16* vt    = (bf16*)alloc((size_t)48 * 64 * 1024 * 2);
  bf16* sa    = (bf16*)alloc(T * 768 * 2);
  float* x1   = (float*)alloc(T * 768 * 4);
  bf16* yln   = (bf16*)alloc(T * 768 * 2);
  bf16* xn2   = (bf16*)alloc(T * 768 * 2);
  bf16* cqf   = (bf16*)alloc(T * 768 * 2);
  bf16* ckv   = (bf16*)alloc(T * 1536 * 2);
  bf16* cvtT  = (bf16*)alloc((size_t)48 * 64 * 1024 * 2);
  bf16* biasA = (bf16*)alloc((size_t)4 * 12 * 1024 * 1024 * 2);  // 100.7 MB
  bf16* ca    = (bf16*)alloc(T * 768 * 2);
  float* x2   = (float*)alloc(T * 768 * 4);
  bf16* xn3   = (bf16*)alloc(T * 768 * 2);
  bf16* hbuf  = (bf16*)alloc(T * 3072 * 2);

  CvtArgs a;
  {
    const float* srcs[8] = {qkvw, apw, pqw, pkw, pvw, cpw, f1w, f2w};
    bf16* dsts[8] = {w_qkv, w_ap, w_pq, w_pkv, w_pkv + 768 * 768, w_cp, w_f1, w_f2};
    const int n4s[8] = {442368, 147456, 147456, 147456, 147456, 147456, 589824, 589824};
    int cum = 0;
    for (int j = 0; j < 8; ++j) {
      a.src[j] = srcs[j]; a.dst[j] = dsts[j];
      cum += n4s[j]; a.end[j] = cum;
    }
  }

  // D1: cvt + ln(x) + ln(y) + bias precompute (all streaming, high-ILP)
  prep_k<<<6400, 256, 0, stream>>>(a, x, ln1g, ln1b, xn, y, lnyg, lnyb, yln,
                                   sim, mask, biasA);

  // D2: qkv GEMM (+ fused V transpose)
  gemm_bt<128,128,false,false,false,true,true><<<576, 256, 0, stream>>>(
      xn, w_qkv, nullptr, nullptr, qkvo, nullptr, vt, 1536, 4, 2304, 768);

  // D3: self-attention
  fattn_k<0><<<768, 256, 0, stream>>>(
      qkvo, 2304, qkvo + 768, 2304, vt, nullptr, sa);

  // D4: aproj + pkv (both compute-bound GEMMs)
  apkv_k<<<768, 256, 0, stream>>>(sa, w_ap, apb, x, x1, yln, w_pkv, ckv, cvtT);

  // D5: ln2
  ln_k<<<1024, 256, 0, stream>>>(x1, ln2g, ln2b, xn2);

  // D6: pq
  gemm_bt<64,128,false,false,false,true,false><<<384, 256, 0, stream>>>(
      xn2, w_pq, nullptr, nullptr, cqf, nullptr, nullptr, 0, 8, 768, 768);

  // D7: cross-attention
  fattn_k<1><<<768, 256, 0, stream>>>(
      cqf, 768, ckv, 1536, cvtT, biasA, ca);

  // D8: cproj
  gemm_bt<64,128,true,false,true,false,false><<<384, 256, 0, stream>>>(
      ca, w_cp, cpb, x1, nullptr, x2, nullptr, 0, 8, 768, 768);

  // D9: ln3
  ln_k<<<1024, 256, 0, stream>>>(x2, ln3g, ln3b, xn3);

  // D10: fc1
  gemm_bt<128,128,true,true,false,true,false><<<768, 256, 0, stream>>>(
      xn3, w_f1, f1b, nullptr, hbuf, nullptr, nullptr, 0, 4, 3072, 768);

  // D11: fc2 + y passthrough copy
  fc2copy_k<<<896, 256, 0, stream>>>(
      hbuf, w_f2, f2b, x2, (float*)d_out, y, (float*)d_out + 3145728);
}